// Round 2
// baseline (379.256 us; speedup 1.0000x reference)
//
#include <hip/hip_runtime.h>
#include <hip/hip_fp16.h>
#include <stdint.h>

#define N_PRO 60000
#define N_WAT 40000
#define NN    100000
#define NNP   100032            // padded to a multiple of 64 for tiles
#define NE    1000000
#define IN_DIM 21
#define HID    32
#define HEADS  4
#define HC     128
#define EDGE_K 32
#define LUTN   2048             // distance-LUT bins, bin = dist*256 (range [0,8))
#define NH0B  ((NNP * 32) / 256)       // h0 blocks
#define NBUCK 196                      // coarse buckets of 512 nodes (node>>9)
#define EPT   8                        // edges per thread in bcnt/scat
#define SCATB ((NE / EPT + 255) / 256) // 489 blocks
#define FCAP  6144                     // per-bucket LDS staging capacity (edges)

typedef _Float16 half8 __attribute__((ext_vector_type(8)));
typedef float    f32x4 __attribute__((ext_vector_type(4)));

// ---------------------------------------------------------------------------
// K1: tiny fused weights (ONE block). smallw floats: [0..127]=U1,
// [128..131]=aeb1, [132..259]=U2, [260..263]=aeb2, [264..295]=h0w,
// [296..423]=va_s1, [424..551]=va_d1
// ---------------------------------------------------------------------------
__global__ __launch_bounds__(256) void k_small(
    const float* We, const float* be,
    const float* Wedge1, const float* atte1,
    const float* Wedge2, const float* atte2,
    const float* Wf, const float* bfv,
    const float* W1, const float* atts1, const float* attd1,
    float* smallw)
{
    __shared__ float V[2][128];
    int t = threadIdx.x;
    {
        int l = t >> 7, dh = t & 127, d = dh >> 2, h = dh & 3;
        const float* Wg = l ? Wedge2 : Wedge1;
        const float* ae = l ? atte2 : atte1;
        float s = 0.f;
        for (int c = 0; c < HID; c++)
            s += Wg[d * HC + h * HID + c] * ae[h * HID + c];
        V[l][dh] = s;
    }
    __syncthreads();
    {
        int l = t >> 7, kh = t & 127, k = kh >> 2, h = kh & 3;
        float s = 0.f;
        for (int d = 0; d < 32; d++)
            s += We[k * 32 + d] * V[l][d * 4 + h];
        smallw[(l ? 132 : 0) + kh] = s;
    }
    if (t < 8) {
        int l = t >> 2, h = t & 3;
        float s = 0.f;
        for (int d = 0; d < 32; d++)
            s += be[d] * V[l][d * 4 + h];
        smallw[(l ? 260 : 128) + h] = s;
    }
    if (t >= 32 && t < 64) {
        int c = t - 32;
        smallw[264 + c] = Wf[20 * 32 + c] + bfv[c];
    }
    {
        int side = t >> 7;
        int h = (t >> 5) & 3, c = t & 31;
        const float* av = side ? attd1 : atts1;
        float s = 0.f;
        for (int j = 0; j < 32; j++)
            s += W1[c * 128 + h * 32 + j] * av[h * 32 + j];
        smallw[(side ? 424 : 296) + (t & 127)] = s;
    }
}

// ---------------------------------------------------------------------------
// K1b: distance LUT. bin b corresponds to dist = b/256.
// ---------------------------------------------------------------------------
__global__ __launch_bounds__(256) void k_lut(
    const float* __restrict__ smallw, const float* __restrict__ gamma,
    float* __restrict__ lut)
{
    int e = blockIdx.x * 256 + threadIdx.x;
    if (e >= 2 * LUTN) return;
    int layer = e >> 11, bin = e & (LUTN - 1);
    const float* U = smallw + (layer ? 132 : 0);
    const float* aeb = smallw + (layer ? 260 : 128);
    float dd = bin * (1.0f / 256.0f);
    float g = gamma[0];
    float a0 = aeb[0], a1 = aeb[1], a2 = aeb[2], a3 = aeb[3];
    const float step = 5.0f / 31.0f;
    #pragma unroll
    for (int k = 0; k < EDGE_K; k++) {
        float tt = dd - (float)k * step;
        float r = __expf(-g * tt * tt);
        a0 += r * U[k * 4 + 0];
        a1 += r * U[k * 4 + 1];
        a2 += r * U[k * 4 + 2];
        a3 += r * U[k * 4 + 3];
    }
    *(float4*)&lut[(size_t)e * 4] = make_float4(a0, a1, a2, a3);
}

// ---------------------------------------------------------------------------
// K2 (pure): h0 = feats@Wf+bf (fp16) + layer-1 logits asd.
// ---------------------------------------------------------------------------
__global__ __launch_bounds__(256) void k_h0(
    const float* __restrict__ pf, const float* __restrict__ Wf,
    const float* __restrict__ bfv, const float* __restrict__ smallw,
    __half* __restrict__ h0, float* __restrict__ asd)
{
    int t = threadIdx.x;
    __shared__ float Wfs[IN_DIM * 32];
    __shared__ float bfs[32];
    __shared__ float h0w[32];
    __shared__ float vas[128], vad[128];
    for (int i = t; i < IN_DIM * 32; i += 256) Wfs[i] = Wf[i];
    if (t < 32) { bfs[t] = bfv[t]; h0w[t] = smallw[264 + t]; }
    if (t < 128) vas[t] = smallw[296 + t];
    else         vad[t - 128] = smallw[424 + (t - 128)];
    __syncthreads();
    int id = blockIdx.x * 256 + t;
    int n = id >> 5, c = id & 31;
    if (n >= NNP) return;
    float v;
    if (n < N_PRO) {
        float s = bfs[c];
        for (int k = 0; k < IN_DIM; k++)
            s += pf[n * IN_DIM + k] * Wfs[k * 32 + c];
        v = s;
    } else {
        v = h0w[c];
    }
    h0[(size_t)n * 32 + c] = __float2half(v);
    float ps[4], pd[4];
    #pragma unroll
    for (int h = 0; h < 4; h++) {
        ps[h] = v * vas[h * 32 + c];
        pd[h] = v * vad[h * 32 + c];
    }
    #pragma unroll
    for (int m = 1; m < 32; m <<= 1) {
        #pragma unroll
        for (int h = 0; h < 4; h++) {
            ps[h] += __shfl_xor(ps[h], m, 64);
            pd[h] += __shfl_xor(pd[h], m, 64);
        }
    }
    if ((t & 31) == 0) {
        *(float4*)&asd[(size_t)n * 8]     = make_float4(ps[0], ps[1], ps[2], ps[3]);
        *(float4*)&asd[(size_t)n * 8 + 4] = make_float4(pd[0], pd[1], pd[2], pd[3]);
    }
}

// ---------------------------------------------------------------------------
// CSR build, atomic-light. Coarse bucket = dst>>9 (512 nodes per bucket).
// k_bcnt: LDS histogram over 196 buckets; src indices guaranteed in-range
// (randint input), so only dst is loaded/checked (halves read traffic).
// ---------------------------------------------------------------------------
__global__ __launch_bounds__(256) void k_bcnt(
    const int* __restrict__ ei, int* __restrict__ gbh)
{
    __shared__ int lh[256];
    int t = threadIdx.x;
    lh[t] = 0;
    __syncthreads();
    int e0 = (blockIdx.x * 256 + t) * EPT;
    if (e0 < NE) {                       // NE % EPT == 0 -> full vector ok
        int4 da = *(const int4*)&ei[NE + e0];
        int4 db = *(const int4*)&ei[NE + e0 + 4];
        int ds[8] = {da.x, da.y, da.z, da.w, db.x, db.y, db.z, db.w};
        #pragma unroll
        for (int j = 0; j < EPT; j++)
            if ((unsigned)ds[j] < (unsigned)NN)
                atomicAdd(&lh[ds[j] >> 9], 1);
    }
    __syncthreads();
    if (t < NBUCK && lh[t]) atomicAdd(&gbh[t], lh[t]);
}

// scan 196 bucket counts -> global bucket offsets + cursors; off[NN]=total.
__global__ __launch_bounds__(256) void k_bscan(
    const int* __restrict__ gbh, int* __restrict__ gboff,
    int* __restrict__ gcur, int* __restrict__ offp)
{
    __shared__ int s[256];
    int t = threadIdx.x;
    int v = (t < NBUCK) ? gbh[t] : 0;
    s[t] = v;
    __syncthreads();
    #pragma unroll
    for (int o = 1; o < 256; o <<= 1) {
        int x = (t >= o) ? s[t - o] : 0;
        __syncthreads();
        s[t] += x;
        __syncthreads();
    }
    int ex = s[t] - v;
    if (t < NBUCK) { gboff[t] = ex; gcur[t] = ex; }
    if (t == NBUCK - 1) { gboff[NBUCK] = s[t]; offp[NN] = s[t]; }
}

// k_scat: rank edges within (block,bucket) via LDS atomics; one global
// atomic per (block,bucket) for the base; write (dst|code, src) records
// into bucket regions.
__global__ __launch_bounds__(256) void k_scat(
    const int* __restrict__ ei, const float* __restrict__ ppos,
    const float* __restrict__ wpos, int* __restrict__ gcur,
    uint2* __restrict__ ebuf2)
{
    __shared__ int lh[256];
    __shared__ int lbase[256];
    int t = threadIdx.x;
    lh[t] = 0;
    __syncthreads();
    int e0 = (blockIdx.x * 256 + t) * EPT;
    int bkt[EPT], rnk[EPT];
    unsigned rec0[EPT], rec1[EPT];
    #pragma unroll
    for (int j = 0; j < EPT; j++) bkt[j] = -1;
    if (e0 < NE) {
        int4 sa = *(const int4*)&ei[e0];
        int4 sb = *(const int4*)&ei[e0 + 4];
        int4 da = *(const int4*)&ei[NE + e0];
        int4 db = *(const int4*)&ei[NE + e0 + 4];
        int ss[8] = {sa.x, sa.y, sa.z, sa.w, sb.x, sb.y, sb.z, sb.w};
        int ds[8] = {da.x, da.y, da.z, da.w, db.x, db.y, db.z, db.w};
        #pragma unroll
        for (int j = 0; j < EPT; j++) {
            int s = ss[j], d = ds[j];
            if ((unsigned)d < (unsigned)NN) {
                const float* ps = (s < N_PRO) ? &ppos[s * 3] : &wpos[(s - N_PRO) * 3];
                const float* pd = (d < N_PRO) ? &ppos[d * 3] : &wpos[(d - N_PRO) * 3];
                float dx = pd[0] - ps[0];
                float dy = pd[1] - ps[1];
                float dz = pd[2] - ps[2];
                float dist = sqrtf(dx * dx + dy * dy + dz * dz);
                unsigned code = (unsigned)fminf(dist * 4096.0f, 32767.0f);
                bkt[j] = d >> 9;
                rec0[j] = ((unsigned)d << 15) | code;
                rec1[j] = (unsigned)s;
                rnk[j] = atomicAdd(&lh[bkt[j]], 1);
            }
        }
    }
    __syncthreads();
    if (t < NBUCK) lbase[t] = lh[t] ? atomicAdd(&gcur[t], lh[t]) : 0;
    __syncthreads();
    #pragma unroll
    for (int j = 0; j < EPT; j++)
        if (bkt[j] >= 0)
            ebuf2[lbase[bkt[j]] + rnk[j]] = make_uint2(rec0[j], rec1[j]);
}

// k_fine: one block per bucket. Stage bucket records in LDS, fine-count 512
// local nodes, LDS scan -> GLOBAL off[] direct, then place each edge at its
// compact slot: write e4 AND the FULLY-EXP'D layer-1 softmax weight
// wb[slot][4] = exp(leaky(as + ae + ad)). ad is known here (dst is
// bucket-local), so the agg kernels never touch logits/exp again.
__global__ __launch_bounds__(512) void k_fine(
    const int* __restrict__ gboff, const uint2* __restrict__ ebuf2,
    const float* __restrict__ lutg, const float* __restrict__ asd,
    int* __restrict__ offp, unsigned* __restrict__ e4,
    float* __restrict__ wb)
{
    __shared__ uint2 eL[FCAP];          // 48 KB
    __shared__ int lcnt[512], lexc[512], ssc[512];
    int b = blockIdx.x, t = threadIdx.x;
    int beg = gboff[b];
    int nb = gboff[b + 1] - beg;
    bool inl = (nb <= FCAP);
    if (inl)
        for (int i = t; i < nb; i += 512) eL[i] = ebuf2[beg + i];
    lcnt[t] = 0;
    __syncthreads();
    for (int i = t; i < nb; i += 512) {
        uint2 u = inl ? eL[i] : ebuf2[beg + i];
        atomicAdd(&lcnt[(u.x >> 15) & 511], 1);
    }
    __syncthreads();
    int c = lcnt[t];
    ssc[t] = c;
    __syncthreads();
    #pragma unroll
    for (int o = 1; o < 512; o <<= 1) {
        int x = (t >= o) ? ssc[t - o] : 0;
        __syncthreads();
        ssc[t] += x;
        __syncthreads();
    }
    lexc[t] = ssc[t] - c;
    int node = b * 512 + t;
    if (node < NN) offp[node] = beg + lexc[t];
    lcnt[t] = 0;                         // reuse as per-node cursor
    __syncthreads();
    for (int i = t; i < nb; i += 512) {
        uint2 u = inl ? eL[i] : ebuf2[beg + i];
        int ln = (int)((u.x >> 15) & 511u);
        int r = atomicAdd(&lcnt[ln], 1);
        int p = beg + lexc[ln] + r;
        unsigned code = u.x & 32767u;
        unsigned s = u.y;
        e4[p] = (s << 15) | code;
        int n = (b << 9) + ln;
        float f = fminf((float)code * 0.0625f, (float)(LUTN - 2));
        int i0 = (int)f;
        float fr = f - (float)i0;
        float4 A = *(const float4*)&lutg[(size_t)i0 * 4];
        float4 B = *(const float4*)&lutg[(size_t)(i0 + 1) * 4];
        float4 as4 = *(const float4*)&asd[(size_t)s * 8];
        float4 ad4 = *(const float4*)&asd[(size_t)n * 8 + 4];
        float v0 = as4.x + ad4.x + A.x + (B.x - A.x) * fr;
        float v1 = as4.y + ad4.y + A.y + (B.y - A.y) * fr;
        float v2 = as4.z + ad4.z + A.z + (B.z - A.z) * fr;
        float v3 = as4.w + ad4.w + A.w + (B.w - A.w) * fr;
        v0 = fmaxf(v0, 0.2f * v0);
        v1 = fmaxf(v1, 0.2f * v1);
        v2 = fmaxf(v2, 0.2f * v2);
        v3 = fmaxf(v3, 0.2f * v3);
        *(float4*)&wb[(size_t)p * 4] = make_float4(
            __expf(v0), __expf(v1), __expf(v2), __expf(v3));
    }
}

// ---------------------------------------------------------------------------
// K6 (MFMA): x = hbuf @ W2 (+ logits) via mfma_f32_16x16x32_f16.
// ---------------------------------------------------------------------------
__global__ __launch_bounds__(256) void k_xm(
    const __half* __restrict__ h, const float* __restrict__ Wg,
    const float* __restrict__ atts, const float* __restrict__ attd,
    __half* __restrict__ x16, float* __restrict__ asd)
{
    __shared__ __half Wt[128 * 136];
    __shared__ float attS[128], attD[128];
    int t = threadIdx.x;
    for (int i = t; i < 128 * 32; i += 256) {
        int c = i & 127, d = (i >> 7) * 4;
        float w0 = Wg[(d + 0) * 128 + c];
        float w1 = Wg[(d + 1) * 128 + c];
        float w2 = Wg[(d + 2) * 128 + c];
        float w3 = Wg[(d + 3) * 128 + c];
        __half2 p0 = __floats2half2_rn(w0, w1);
        __half2 p1 = __floats2half2_rn(w2, w3);
        uint2 pk;
        pk.x = *(unsigned*)&p0;
        pk.y = *(unsigned*)&p1;
        *(uint2*)&Wt[c * 136 + d] = pk;
    }
    if (t < 128) { attS[t] = atts[t]; attD[t] = attd[t]; }
    __syncthreads();
    int wv = t >> 6, lane = t & 63;
    int m16 = lane & 15, quad = lane >> 4;
    int n0 = blockIdx.x * 64 + wv * 16;
    f32x4 acc[8];
    #pragma unroll
    for (int ct = 0; ct < 8; ct++) acc[ct] = (f32x4){0.f, 0.f, 0.f, 0.f};
    #pragma unroll
    for (int ks = 0; ks < 4; ks++) {
        int d0 = ks * 32 + quad * 8;
        half8 bf = *(const half8*)&h[(size_t)(n0 + m16) * 128 + d0];
        #pragma unroll
        for (int ct = 0; ct < 8; ct++) {
            half8 af = *(const half8*)&Wt[(ct * 16 + m16) * 136 + d0];
            acc[ct] = __builtin_amdgcn_mfma_f32_16x16x32_f16(af, bf, acc[ct], 0, 0, 0);
        }
    }
    __half* xrow = &x16[(size_t)(n0 + m16) * 128 + quad * 4];
    float ps[4] = {0.f, 0.f, 0.f, 0.f}, pd[4] = {0.f, 0.f, 0.f, 0.f};
    #pragma unroll
    for (int ct = 0; ct < 8; ct++) {
        f32x4 a = acc[ct];
        __half2 h0p = __floats2half2_rn(a[0], a[1]);
        __half2 h1p = __floats2half2_rn(a[2], a[3]);
        uint2 pk;
        pk.x = *(unsigned*)&h0p;
        pk.y = *(unsigned*)&h1p;
        *(uint2*)&xrow[ct * 16] = pk;
        int cb = ct * 16 + quad * 4;
        int hh = ct >> 1;
        ps[hh] += a[0] * attS[cb] + a[1] * attS[cb + 1]
                + a[2] * attS[cb + 2] + a[3] * attS[cb + 3];
        pd[hh] += a[0] * attD[cb] + a[1] * attD[cb + 1]
                + a[2] * attD[cb + 2] + a[3] * attD[cb + 3];
    }
    #pragma unroll
    for (int hh = 0; hh < 4; hh++) {
        ps[hh] += __shfl_xor(ps[hh], 16, 64);
        ps[hh] += __shfl_xor(ps[hh], 32, 64);
        pd[hh] += __shfl_xor(pd[hh], 16, 64);
        pd[hh] += __shfl_xor(pd[hh], 32, 64);
    }
    if (lane < 16) {
        int n = n0 + m16;
        *(float4*)&asd[(size_t)n * 8]     = make_float4(ps[0], ps[1], ps[2], ps[3]);
        *(float4*)&asd[(size_t)n * 8 + 4] = make_float4(pd[0], pd[1], pd[2], pd[3]);
    }
}

// ---------------------------------------------------------------------------
// K7 (layer-2 weights, node-major, water only): wave per node, lanes
// edge-parallel. Computes wb[slot][4] = exp(leaky(as+ae+ad)) from lut2+asd2.
// Replaces the old streaming k_alphaP2 AND removes exp/leaky from k_agg2.
// ---------------------------------------------------------------------------
__global__ __launch_bounds__(256) void k_w2(
    const int* __restrict__ off, const unsigned* __restrict__ e4,
    const float* __restrict__ lutg, const float* __restrict__ asd,
    float* __restrict__ wb)
{
    int wv = threadIdx.x >> 6, lane = threadIdx.x & 63;
    int n = N_PRO + blockIdx.x * 4 + wv;
    if (n >= NN) return;
    int beg = off[n], end = off[n + 1];
    float4 ad4 = *(const float4*)&asd[(size_t)n * 8 + 4];
    for (int i = beg + lane; i < end; i += 64) {
        unsigned u = e4[i];
        unsigned s = u >> 15;
        float f = fminf((float)(u & 32767u) * 0.0625f, (float)(LUTN - 2));
        int i0 = (int)f;
        float fr = f - (float)i0;
        float4 A = *(const float4*)&lutg[(size_t)i0 * 4];
        float4 B = *(const float4*)&lutg[(size_t)(i0 + 1) * 4];
        float4 as4 = *(const float4*)&asd[(size_t)s * 8];
        float v0 = as4.x + ad4.x + A.x + (B.x - A.x) * fr;
        float v1 = as4.y + ad4.y + A.y + (B.y - A.y) * fr;
        float v2 = as4.z + ad4.z + A.z + (B.z - A.z) * fr;
        float v3 = as4.w + ad4.w + A.w + (B.w - A.w) * fr;
        v0 = fmaxf(v0, 0.2f * v0);
        v1 = fmaxf(v1, 0.2f * v1);
        v2 = fmaxf(v2, 0.2f * v2);
        v3 = fmaxf(v3, 0.2f * v3);
        *(float4*)&wb[(size_t)i * 4] = make_float4(
            __expf(v0), __expf(v1), __expf(v2), __expf(v3));
    }
}

// ---------------------------------------------------------------------------
// K8a: layer-1 aggregation of RAW h0 into z[N,4,32] fp16. LEAN: weights are
// precomputed (wb), so per edge it's just {e4, w, x-gather, 2 fma, lsum}.
// lsum needs no shuffles: the 16 lanes of a head all read the same w.
// ---------------------------------------------------------------------------
__global__ __launch_bounds__(256) void k_aggz(
    const int* __restrict__ off, const unsigned* __restrict__ e4,
    const float* __restrict__ wb, const __half* __restrict__ h016,
    __half* __restrict__ zbuf)
{
    int t = threadIdx.x;
    int w = t >> 6, lane = t & 63;
    int n = blockIdx.x * 4 + w;
    if (n >= NN) return;
    int h = lane >> 4, k16 = lane & 15;
    int beg = off[n];
    int end = off[n + 1];
    const __half2* x2 = (const __half2*)h016;
    float lsum0 = 0.f, lsum1 = 0.f;
    float a00 = 0.f, a01 = 0.f, a10 = 0.f, a11 = 0.f;
    int i = beg;
    for (; i + 3 < end; i += 4) {
        unsigned s0 = e4[i] >> 15, s1 = e4[i + 1] >> 15;
        unsigned s2 = e4[i + 2] >> 15, s3 = e4[i + 3] >> 15;
        float w0 = wb[(unsigned)i * 4u + h];
        float w1 = wb[(unsigned)(i + 1) * 4u + h];
        float w2 = wb[(unsigned)(i + 2) * 4u + h];
        float w3 = wb[(unsigned)(i + 3) * 4u + h];
        float2 xv0 = __half22float2(x2[s0 * 16u + k16]);
        float2 xv1 = __half22float2(x2[s1 * 16u + k16]);
        float2 xv2 = __half22float2(x2[s2 * 16u + k16]);
        float2 xv3 = __half22float2(x2[s3 * 16u + k16]);
        lsum0 += w0 + w2; lsum1 += w1 + w3;
        a00 += w0 * xv0.x + w2 * xv2.x;
        a01 += w0 * xv0.y + w2 * xv2.y;
        a10 += w1 * xv1.x + w3 * xv3.x;
        a11 += w1 * xv1.y + w3 * xv3.y;
    }
    for (; i < end; i++) {
        unsigned s0 = e4[i] >> 15;
        float w0 = wb[(unsigned)i * 4u + h];
        float2 xv0 = __half22float2(x2[s0 * 16u + k16]);
        lsum0 += w0;
        a00 += w0 * xv0.x; a01 += w0 * xv0.y;
    }
    float inv = 1.0f / (lsum0 + lsum1 + 1e-16f);
    *(__half2*)&zbuf[(size_t)n * 128 + lane * 2] =
        __floats2half2_rn((a00 + a10) * inv, (a01 + a11) * inv);
}

// ---------------------------------------------------------------------------
// K8a2 (k_zm, MFMA): hbuf = elu(z @blockdiag(W1) + b1).
// ---------------------------------------------------------------------------
__global__ __launch_bounds__(256) void k_zm(
    const __half* __restrict__ zbuf, const float* __restrict__ W1g,
    const float* __restrict__ b1, __half* __restrict__ hbuf)
{
    __shared__ __half Wt[128 * 40];   // [col c][k], 80B rows (16B aligned)
    int t = threadIdx.x;
    for (int i = t; i < 128 * 8; i += 256) {
        int c = i & 127, k4 = (i >> 7) * 4;
        float w0 = W1g[(k4 + 0) * 128 + c];
        float w1 = W1g[(k4 + 1) * 128 + c];
        float w2 = W1g[(k4 + 2) * 128 + c];
        float w3 = W1g[(k4 + 3) * 128 + c];
        __half2 p0 = __floats2half2_rn(w0, w1);
        __half2 p1 = __floats2half2_rn(w2, w3);
        uint2 pk;
        pk.x = *(unsigned*)&p0;
        pk.y = *(unsigned*)&p1;
        *(uint2*)&Wt[c * 40 + k4] = pk;
    }
    __syncthreads();
    int wv = t >> 6, lane = t & 63;
    int m16 = lane & 15, quad = lane >> 4;
    int n0 = blockIdx.x * 64 + wv * 16;
    half8 bf[4];
    #pragma unroll
    for (int hh = 0; hh < 4; hh++)
        bf[hh] = *(const half8*)&zbuf[(size_t)(n0 + m16) * 128 + hh * 32 + quad * 8];
    f32x4 acc[8];
    #pragma unroll
    for (int ct = 0; ct < 8; ct++) {
        half8 af = *(const half8*)&Wt[(ct * 16 + m16) * 40 + quad * 8];
        acc[ct] = __builtin_amdgcn_mfma_f32_16x16x32_f16(
            af, bf[ct >> 1], (f32x4){0.f, 0.f, 0.f, 0.f}, 0, 0, 0);
    }
    __half* orow = &hbuf[(size_t)(n0 + m16) * 128 + quad * 4];
    #pragma unroll
    for (int ct = 0; ct < 8; ct++) {
        int cb = ct * 16 + quad * 4;
        float4 bb = *(const float4*)&b1[cb];
        float r0 = acc[ct][0] + bb.x;
        float r1 = acc[ct][1] + bb.y;
        float r2 = acc[ct][2] + bb.z;
        float r3 = acc[ct][3] + bb.w;
        r0 = r0 > 0.f ? r0 : __expf(r0) - 1.0f;
        r1 = r1 > 0.f ? r1 : __expf(r1) - 1.0f;
        r2 = r2 > 0.f ? r2 : __expf(r2) - 1.0f;
        r3 = r3 > 0.f ? r3 : __expf(r3) - 1.0f;
        __half2 ha = __floats2half2_rn(r0, r1);
        __half2 hb = __floats2half2_rn(r2, r3);
        uint2 pk;
        pk.x = *(unsigned*)&ha;
        pk.y = *(unsigned*)&hb;
        *(uint2*)&orow[ct * 16] = pk;
    }
}

// ---------------------------------------------------------------------------
// K8b: layer-2 aggregation over pre-GEMMed x16 (water dst only). LEAN.
// ---------------------------------------------------------------------------
__global__ __launch_bounds__(256) void k_agg2(
    const int* __restrict__ off, const unsigned* __restrict__ e4,
    const float* __restrict__ wb, const __half* __restrict__ x16,
    const float* __restrict__ bias, __half* __restrict__ hout)
{
    int t = threadIdx.x;
    int w = t >> 6, lane = t & 63;
    int n = N_PRO + blockIdx.x * 4 + w;
    if (n >= NN) return;
    int h = lane >> 4;
    int beg = off[n];
    int end = off[n + 1];
    const __half2* x2 = (const __half2*)x16;
    float lsum0 = 0.f, lsum1 = 0.f;
    float a00 = 0.f, a01 = 0.f, a10 = 0.f, a11 = 0.f;
    int i = beg;
    for (; i + 3 < end; i += 4) {
        unsigned s0 = e4[i] >> 15, s1 = e4[i + 1] >> 15;
        unsigned s2 = e4[i + 2] >> 15, s3 = e4[i + 3] >> 15;
        float w0 = wb[(unsigned)i * 4u + h];
        float w1 = wb[(unsigned)(i + 1) * 4u + h];
        float w2 = wb[(unsigned)(i + 2) * 4u + h];
        float w3 = wb[(unsigned)(i + 3) * 4u + h];
        float2 xv0 = __half22float2(x2[s0 * 64u + lane]);
        float2 xv1 = __half22float2(x2[s1 * 64u + lane]);
        float2 xv2 = __half22float2(x2[s2 * 64u + lane]);
        float2 xv3 = __half22float2(x2[s3 * 64u + lane]);
        lsum0 += w0 + w2; lsum1 += w1 + w3;
        a00 += w0 * xv0.x + w2 * xv2.x;
        a01 += w0 * xv0.y + w2 * xv2.y;
        a10 += w1 * xv1.x + w3 * xv3.x;
        a11 += w1 * xv1.y + w3 * xv3.y;
    }
    for (; i < end; i++) {
        unsigned s0 = e4[i] >> 15;
        float w0 = wb[(unsigned)i * 4u + h];
        float2 xv0 = __half22float2(x2[s0 * 64u + lane]);
        lsum0 += w0;
        a00 += w0 * xv0.x; a01 += w0 * xv0.y;
    }
    float lsum = lsum0 + lsum1;
    float acc0 = a00 + a10, acc1 = a01 + a11;
    float inv = 1.0f / (lsum + 1e-16f);
    float2 bbv = *(const float2*)&bias[lane * 2];
    float o0 = acc0 * inv + bbv.x;
    float o1 = acc1 * inv + bbv.y;
    o0 = o0 > 0.f ? o0 : __expf(o0) - 1.0f;
    o1 = o1 > 0.f ? o1 : __expf(o1) - 1.0f;
    *(__half2*)&hout[(size_t)n * 128 + lane * 2] = __floats2half2_rn(o0, o1);
}

// ---------------------------------------------------------------------------
// K9: water MLP. 32-node tile/block, padded stride 132, register-blocked.
// ---------------------------------------------------------------------------
__global__ __launch_bounds__(256) void k_mlp(
    const __half* __restrict__ hh, const float* __restrict__ Wm1,
    const float* __restrict__ bm1, const float* __restrict__ Wm2,
    const float* __restrict__ bm2, float* __restrict__ out)
{
    __shared__ float W1s[128 * 64];
    __shared__ float hs[32 * 132];
    int t = threadIdx.x;
    int g = t >> 5, q = t & 31;
    float b1r[2][2], w2r[2][2][2];
    #pragma unroll
    for (int hf = 0; hf < 2; hf++)
        #pragma unroll
        for (int j = 0; j < 2; j++) {
            int c = hf * 64 + q * 2 + j;
            b1r[hf][j] = bm1[c];
            w2r[hf][j][0] = Wm2[c * 2 + 0];
            w2r[hf][j][1] = Wm2[c * 2 + 1];
        }
    float b20 = bm2[0], b21 = bm2[1];
    int tile = blockIdx.x;
    {
        int r = t >> 3, c0 = (t & 7) * 16;
        const __half* src = &hh[(size_t)(N_PRO + tile * 32 + r) * 128 + c0];
        uint4 raw0 = *(const uint4*)src;
        uint4 raw1 = *(const uint4*)(src + 8);
        const __half2* hp0 = (const __half2*)&raw0;
        const __half2* hp1 = (const __half2*)&raw1;
        #pragma unroll
        for (int j = 0; j < 4; j++) {
            float2 fa = __half22float2(j < 2 ? hp0[2 * j] : hp1[2 * (j - 2)]);
            float2 fb = __half22float2(j < 2 ? hp0[2 * j + 1] : hp1[2 * (j - 2) + 1]);
            *(float4*)&hs[r * 132 + c0 + 4 * j] = make_float4(fa.x, fa.y, fb.x, fb.y);
        }
    }
    float p0[4] = {0.f, 0.f, 0.f, 0.f}, p1[4] = {0.f, 0.f, 0.f, 0.f};
    #pragma unroll
    for (int hf = 0; hf < 2; hf++) {
        __syncthreads();
        for (int i = t; i < 128 * 64; i += 256)
            W1s[i] = Wm1[(size_t)(i >> 6) * 128 + hf * 64 + (i & 63)];
        __syncthreads();
        float a[4][2];
        #pragma unroll
        for (int i = 0; i < 4; i++) { a[i][0] = 0.f; a[i][1] = 0.f; }
        for (int d0 = 0; d0 < 128; d0 += 4) {
            float4 hv[4];
            #pragma unroll
            for (int i = 0; i < 4; i++)
                hv[i] = *(const float4*)&hs[(g + 8 * i) * 132 + d0];
            #pragma unroll
            for (int dd = 0; dd < 4; dd++) {
                float2 wv = *(const float2*)&W1s[(d0 + dd) * 64 + q * 2];
                #pragma unroll
                for (int i = 0; i < 4; i++) {
                    float hvv = (&hv[i].x)[dd];
                    a[i][0] += hvv * wv.x;
                    a[i][1] += hvv * wv.y;
                }
            }
        }
        #pragma unroll
        for (int i = 0; i < 4; i++) {
            float a0 = fmaxf(a[i][0] + b1r[hf][0], 0.f);
            float a1 = fmaxf(a[i][1] + b1r[hf][1], 0.f);
            p0[i] += a0 * w2r[hf][0][0] + a1 * w2r[hf][1][0];
            p1[i] += a0 * w2r[hf][0][1] + a1 * w2r[hf][1][1];
        }
    }
    #pragma unroll
    for (int m = 1; m < 32; m <<= 1) {
        #pragma unroll
        for (int i = 0; i < 4; i++) {
            p0[i] += __shfl_xor(p0[i], m, 64);
            p1[i] += __shfl_xor(p1[i], m, 64);
        }
    }
    if (q == 0) {
        #pragma unroll
        for (int i = 0; i < 4; i++) {
            int n = tile * 32 + g + 8 * i;
            *(float2*)&out[n * 2] = make_float2(p0[i] + b20, p1[i] + b21);
        }
    }
}

// ---------------------------------------------------------------------------
extern "C" void kernel_launch(void* const* d_in, const int* in_sizes, int n_in,
                              void* d_out, int out_size, void* d_ws, size_t ws_size,
                              hipStream_t stream)
{
    const float* ppos   = (const float*)d_in[0];
    const float* wpos   = (const float*)d_in[1];
    const float* pfeat  = (const float*)d_in[2];
    const int*   ei     = (const int*)d_in[3];
    const float* gamma  = (const float*)d_in[4];
    const float* Wf     = (const float*)d_in[5];
    const float* bfv    = (const float*)d_in[6];
    const float* We     = (const float*)d_in[7];
    const float* be     = (const float*)d_in[8];
    const float* W1     = (const float*)d_in[9];
    const float* atts1  = (const float*)d_in[10];
    const float* attd1  = (const float*)d_in[11];
    const float* Wedge1 = (const float*)d_in[12];
    const float* atte1  = (const float*)d_in[13];
    const float* b1     = (const float*)d_in[14];
    const float* W2     = (const float*)d_in[15];
    const float* atts2  = (const float*)d_in[16];
    const float* attd2  = (const float*)d_in[17];
    const float* Wedge2 = (const float*)d_in[18];
    const float* atte2  = (const float*)d_in[19];
    const float* b2     = (const float*)d_in[20];
    const float* Wm1    = (const float*)d_in[21];
    const float* bm1    = (const float*)d_in[22];
    const float* Wm2    = (const float*)d_in[23];
    const float* bm2    = (const float*)d_in[24];
    float* out = (float*)d_out;

    char* ws = (char*)d_ws;
    size_t o = 0;
    auto alloc = [&](size_t bytes) -> char* {
        char* p = ws + o;
        o += (bytes + 255) & ~(size_t)255;
        return p;
    };
    __half*   h0      = (__half*)alloc((size_t)NNP * 32 * 2);
    __half*   x16     = (__half*)alloc((size_t)NNP * 128 * 2);   // also zbuf
    __half*   hbuf    = (__half*)alloc((size_t)NNP * 128 * 2);
    float*    asd     = (float*)alloc((size_t)NNP * 8 * 4);
    float*    wb      = (float*)alloc((size_t)NE * 4 * 4);       // exp'd weights
    int*      offp    = (int*)alloc((size_t)(NN + 1) * 4);
    unsigned* e4      = (unsigned*)alloc((size_t)NE * 4);
    int*      gbh     = (int*)alloc(256 * 4);
    int*      gboff   = (int*)alloc(256 * 4);
    int*      gcur    = (int*)alloc(256 * 4);
    float*    smallw  = (float*)alloc(4096);
    float*    lutbuf  = (float*)alloc((size_t)2 * LUTN * 4 * 4);
    // ebuf2 (8 MB) overlays hbuf (25.6 MB): ebuf2 is written by k_scat and
    // last read by k_fine, strictly before hbuf's first write in k_zm.
    uint2*    ebuf2   = (uint2*)hbuf;

    hipMemsetAsync(gbh, 0, 256 * 4, stream);
    k_small<<<1, 256, 0, stream>>>(We, be, Wedge1, atte1, Wedge2, atte2, Wf, bfv,
                                   W1, atts1, attd1, smallw);
    k_lut<<<(2 * LUTN + 255) / 256, 256, 0, stream>>>(smallw, gamma, lutbuf);
    k_h0<<<NH0B, 256, 0, stream>>>(pfeat, Wf, bfv, smallw, h0, asd);
    // CSR build: coarse count -> scan -> bucket scatter -> fine place (+w L1)
    k_bcnt<<<SCATB, 256, 0, stream>>>(ei, gbh);
    k_bscan<<<1, 256, 0, stream>>>(gbh, gboff, gcur, offp);
    k_scat<<<SCATB, 256, 0, stream>>>(ei, ppos, wpos, gcur, ebuf2);
    k_fine<<<NBUCK, 512, 0, stream>>>(gboff, ebuf2, lutbuf, asd, offp, e4, wb);
    // layer 1: lean aggregation (weights prebuilt by k_fine), MFMA W1
    k_aggz<<<NN / 4, 256, 0, stream>>>(offp, e4, wb, h0, x16);
    k_zm<<<NNP / 64, 256, 0, stream>>>(x16, W1, b1, hbuf);
    // layer 2 (water destinations only)
    k_xm<<<NNP / 64, 256, 0, stream>>>(hbuf, W2, atts2, attd2, x16, asd);
    k_w2<<<N_WAT / 4, 256, 0, stream>>>(offp, e4, lutbuf + (size_t)LUTN * 4, asd, wb);
    k_agg2<<<N_WAT / 4, 256, 0, stream>>>(offp, e4, wb, x16, b2, hbuf);
    // MLP on water nodes
    k_mlp<<<N_WAT / 32, 256, 0, stream>>>(hbuf, Wm1, bm1, Wm2, bm2, out);
}

// Round 3
// 354.817 us; speedup vs baseline: 1.0689x; 1.0689x over previous
//
#include <hip/hip_runtime.h>
#include <hip/hip_fp16.h>
#include <stdint.h>

#define N_PRO 60000
#define N_WAT 40000
#define NN    100000
#define NNP   100032            // padded to a multiple of 64 for tiles
#define NE    1000000
#define IN_DIM 21
#define HID    32
#define HEADS  4
#define HC     128
#define EDGE_K 32
#define LUTN   2048             // distance-LUT bins, bin = dist*256 (range [0,8))
#define NH0B  ((NNP * 32) / 256)       // h0 blocks
#define NBUCK 196                      // coarse buckets of 512 nodes (node>>9)
#define EPT   8                        // edges per thread in bcnt/scat
#define SCATB ((NE / EPT + 255) / 256) // 489 blocks
#define FCAP  6144                     // per-bucket LDS staging capacity (edges)

typedef _Float16 half8 __attribute__((ext_vector_type(8)));
typedef float    f32x4 __attribute__((ext_vector_type(4)));

// ---------------------------------------------------------------------------
// K1: tiny fused weights (ONE block). smallw floats: [0..127]=U1,
// [128..131]=aeb1, [132..259]=U2, [260..263]=aeb2, [264..295]=h0w,
// [296..423]=va_s1, [424..551]=va_d1
// ---------------------------------------------------------------------------
__global__ __launch_bounds__(256) void k_small(
    const float* We, const float* be,
    const float* Wedge1, const float* atte1,
    const float* Wedge2, const float* atte2,
    const float* Wf, const float* bfv,
    const float* W1, const float* atts1, const float* attd1,
    float* smallw)
{
    __shared__ float V[2][128];
    int t = threadIdx.x;
    {
        int l = t >> 7, dh = t & 127, d = dh >> 2, h = dh & 3;
        const float* Wg = l ? Wedge2 : Wedge1;
        const float* ae = l ? atte2 : atte1;
        float s = 0.f;
        for (int c = 0; c < HID; c++)
            s += Wg[d * HC + h * HID + c] * ae[h * HID + c];
        V[l][dh] = s;
    }
    __syncthreads();
    {
        int l = t >> 7, kh = t & 127, k = kh >> 2, h = kh & 3;
        float s = 0.f;
        for (int d = 0; d < 32; d++)
            s += We[k * 32 + d] * V[l][d * 4 + h];
        smallw[(l ? 132 : 0) + kh] = s;
    }
    if (t < 8) {
        int l = t >> 2, h = t & 3;
        float s = 0.f;
        for (int d = 0; d < 32; d++)
            s += be[d] * V[l][d * 4 + h];
        smallw[(l ? 260 : 128) + h] = s;
    }
    if (t >= 32 && t < 64) {
        int c = t - 32;
        smallw[264 + c] = Wf[20 * 32 + c] + bfv[c];
    }
    {
        int side = t >> 7;
        int h = (t >> 5) & 3, c = t & 31;
        const float* av = side ? attd1 : atts1;
        float s = 0.f;
        for (int j = 0; j < 32; j++)
            s += W1[c * 128 + h * 32 + j] * av[h * 32 + j];
        smallw[(side ? 424 : 296) + (t & 127)] = s;
    }
}

// ---------------------------------------------------------------------------
// K1b: distance LUT. bin b corresponds to dist = b/256.
// ---------------------------------------------------------------------------
__global__ __launch_bounds__(256) void k_lut(
    const float* __restrict__ smallw, const float* __restrict__ gamma,
    float* __restrict__ lut)
{
    int e = blockIdx.x * 256 + threadIdx.x;
    if (e >= 2 * LUTN) return;
    int layer = e >> 11, bin = e & (LUTN - 1);
    const float* U = smallw + (layer ? 132 : 0);
    const float* aeb = smallw + (layer ? 260 : 128);
    float dd = bin * (1.0f / 256.0f);
    float g = gamma[0];
    float a0 = aeb[0], a1 = aeb[1], a2 = aeb[2], a3 = aeb[3];
    const float step = 5.0f / 31.0f;
    #pragma unroll
    for (int k = 0; k < EDGE_K; k++) {
        float tt = dd - (float)k * step;
        float r = __expf(-g * tt * tt);
        a0 += r * U[k * 4 + 0];
        a1 += r * U[k * 4 + 1];
        a2 += r * U[k * 4 + 2];
        a3 += r * U[k * 4 + 3];
    }
    *(float4*)&lut[(size_t)e * 4] = make_float4(a0, a1, a2, a3);
}

// ---------------------------------------------------------------------------
// K2 (pure): h0 = feats@Wf+bf (fp16) + layer-1 logits asd.
// ---------------------------------------------------------------------------
__global__ __launch_bounds__(256) void k_h0(
    const float* __restrict__ pf, const float* __restrict__ Wf,
    const float* __restrict__ bfv, const float* __restrict__ smallw,
    __half* __restrict__ h0, float* __restrict__ asd)
{
    int t = threadIdx.x;
    __shared__ float Wfs[IN_DIM * 32];
    __shared__ float bfs[32];
    __shared__ float h0w[32];
    __shared__ float vas[128], vad[128];
    for (int i = t; i < IN_DIM * 32; i += 256) Wfs[i] = Wf[i];
    if (t < 32) { bfs[t] = bfv[t]; h0w[t] = smallw[264 + t]; }
    if (t < 128) vas[t] = smallw[296 + t];
    else         vad[t - 128] = smallw[424 + (t - 128)];
    __syncthreads();
    int id = blockIdx.x * 256 + t;
    int n = id >> 5, c = id & 31;
    if (n >= NNP) return;
    float v;
    if (n < N_PRO) {
        float s = bfs[c];
        for (int k = 0; k < IN_DIM; k++)
            s += pf[n * IN_DIM + k] * Wfs[k * 32 + c];
        v = s;
    } else {
        v = h0w[c];
    }
    h0[(size_t)n * 32 + c] = __float2half(v);
    float ps[4], pd[4];
    #pragma unroll
    for (int h = 0; h < 4; h++) {
        ps[h] = v * vas[h * 32 + c];
        pd[h] = v * vad[h * 32 + c];
    }
    #pragma unroll
    for (int m = 1; m < 32; m <<= 1) {
        #pragma unroll
        for (int h = 0; h < 4; h++) {
            ps[h] += __shfl_xor(ps[h], m, 64);
            pd[h] += __shfl_xor(pd[h], m, 64);
        }
    }
    if ((t & 31) == 0) {
        *(float4*)&asd[(size_t)n * 8]     = make_float4(ps[0], ps[1], ps[2], ps[3]);
        *(float4*)&asd[(size_t)n * 8 + 4] = make_float4(pd[0], pd[1], pd[2], pd[3]);
    }
}

// ---------------------------------------------------------------------------
// CSR build, atomic-light. Coarse bucket = dst>>9 (512 nodes per bucket).
// ---------------------------------------------------------------------------
__global__ __launch_bounds__(256) void k_bcnt(
    const int* __restrict__ ei, int* __restrict__ gbh)
{
    __shared__ int lh[256];
    int t = threadIdx.x;
    lh[t] = 0;
    __syncthreads();
    int e0 = (blockIdx.x * 256 + t) * EPT;
    if (e0 < NE) {                       // NE % EPT == 0 -> full vector ok
        int4 da = *(const int4*)&ei[NE + e0];
        int4 db = *(const int4*)&ei[NE + e0 + 4];
        int ds[8] = {da.x, da.y, da.z, da.w, db.x, db.y, db.z, db.w};
        #pragma unroll
        for (int j = 0; j < EPT; j++)
            if ((unsigned)ds[j] < (unsigned)NN)
                atomicAdd(&lh[ds[j] >> 9], 1);
    }
    __syncthreads();
    if (t < NBUCK && lh[t]) atomicAdd(&gbh[t], lh[t]);
}

// scan 196 bucket counts -> global bucket offsets + cursors; off[NN]=total.
__global__ __launch_bounds__(256) void k_bscan(
    const int* __restrict__ gbh, int* __restrict__ gboff,
    int* __restrict__ gcur, int* __restrict__ offp)
{
    __shared__ int s[256];
    int t = threadIdx.x;
    int v = (t < NBUCK) ? gbh[t] : 0;
    s[t] = v;
    __syncthreads();
    #pragma unroll
    for (int o = 1; o < 256; o <<= 1) {
        int x = (t >= o) ? s[t - o] : 0;
        __syncthreads();
        s[t] += x;
        __syncthreads();
    }
    int ex = s[t] - v;
    if (t < NBUCK) { gboff[t] = ex; gcur[t] = ex; }
    if (t == NBUCK - 1) { gboff[NBUCK] = s[t]; offp[NN] = s[t]; }
}

// k_scat: rank edges within (block,bucket) via LDS atomics; one global
// atomic per (block,bucket) for the base; write (dst|code, src) records.
__global__ __launch_bounds__(256) void k_scat(
    const int* __restrict__ ei, const float* __restrict__ ppos,
    const float* __restrict__ wpos, int* __restrict__ gcur,
    uint2* __restrict__ ebuf2)
{
    __shared__ int lh[256];
    __shared__ int lbase[256];
    int t = threadIdx.x;
    lh[t] = 0;
    __syncthreads();
    int e0 = (blockIdx.x * 256 + t) * EPT;
    int bkt[EPT], rnk[EPT];
    unsigned rec0[EPT], rec1[EPT];
    #pragma unroll
    for (int j = 0; j < EPT; j++) bkt[j] = -1;
    if (e0 < NE) {
        int4 sa = *(const int4*)&ei[e0];
        int4 sb = *(const int4*)&ei[e0 + 4];
        int4 da = *(const int4*)&ei[NE + e0];
        int4 db = *(const int4*)&ei[NE + e0 + 4];
        int ss[8] = {sa.x, sa.y, sa.z, sa.w, sb.x, sb.y, sb.z, sb.w};
        int ds[8] = {da.x, da.y, da.z, da.w, db.x, db.y, db.z, db.w};
        #pragma unroll
        for (int j = 0; j < EPT; j++) {
            int s = ss[j], d = ds[j];
            if ((unsigned)d < (unsigned)NN) {
                const float* ps = (s < N_PRO) ? &ppos[s * 3] : &wpos[(s - N_PRO) * 3];
                const float* pd = (d < N_PRO) ? &ppos[d * 3] : &wpos[(d - N_PRO) * 3];
                float dx = pd[0] - ps[0];
                float dy = pd[1] - ps[1];
                float dz = pd[2] - ps[2];
                float dist = sqrtf(dx * dx + dy * dy + dz * dz);
                unsigned code = (unsigned)fminf(dist * 4096.0f, 32767.0f);
                bkt[j] = d >> 9;
                rec0[j] = ((unsigned)d << 15) | code;
                rec1[j] = (unsigned)s;
                rnk[j] = atomicAdd(&lh[bkt[j]], 1);
            }
        }
    }
    __syncthreads();
    if (t < NBUCK) lbase[t] = lh[t] ? atomicAdd(&gcur[t], lh[t]) : 0;
    __syncthreads();
    #pragma unroll
    for (int j = 0; j < EPT; j++)
        if (bkt[j] >= 0)
            ebuf2[lbase[bkt[j]] + rnk[j]] = make_uint2(rec0[j], rec1[j]);
}

// k_fine: one block per bucket, now 1024 threads (occupancy was capped at
// 196 blocks x 8 waves = 19%; 16 waves/block doubles latency-hiding for the
// gather+exp+scatter placement loop). Scan phases guarded to t<512.
__global__ __launch_bounds__(1024) void k_fine(
    const int* __restrict__ gboff, const uint2* __restrict__ ebuf2,
    const float* __restrict__ lutg, const float* __restrict__ asd,
    int* __restrict__ offp, unsigned* __restrict__ e4,
    float* __restrict__ wb)
{
    __shared__ uint2 eL[FCAP];          // 48 KB
    __shared__ int lcnt[512], lexc[512], ssc[512];
    int b = blockIdx.x, t = threadIdx.x;
    int beg = gboff[b];
    int nb = gboff[b + 1] - beg;
    bool inl = (nb <= FCAP);
    if (inl)
        for (int i = t; i < nb; i += 1024) eL[i] = ebuf2[beg + i];
    if (t < 512) lcnt[t] = 0;
    __syncthreads();
    for (int i = t; i < nb; i += 1024) {
        uint2 u = inl ? eL[i] : ebuf2[beg + i];
        atomicAdd(&lcnt[(u.x >> 15) & 511], 1);
    }
    __syncthreads();
    int c = (t < 512) ? lcnt[t] : 0;
    if (t < 512) ssc[t] = c;
    __syncthreads();
    for (int o = 1; o < 512; o <<= 1) {
        int x = (t >= o && t < 512) ? ssc[t - o] : 0;
        __syncthreads();
        if (t < 512) ssc[t] += x;
        __syncthreads();
    }
    if (t < 512) {
        lexc[t] = ssc[t] - c;
        int node = b * 512 + t;
        if (node < NN) offp[node] = beg + lexc[t];
        lcnt[t] = 0;                     // reuse as per-node cursor
    }
    __syncthreads();
    for (int i = t; i < nb; i += 1024) {
        uint2 u = inl ? eL[i] : ebuf2[beg + i];
        int ln = (int)((u.x >> 15) & 511u);
        int r = atomicAdd(&lcnt[ln], 1);
        int p = beg + lexc[ln] + r;
        unsigned code = u.x & 32767u;
        unsigned s = u.y;
        e4[p] = (s << 15) | code;
        int n = (b << 9) + ln;
        float f = fminf((float)code * 0.0625f, (float)(LUTN - 2));
        int i0 = (int)f;
        float fr = f - (float)i0;
        float4 A = *(const float4*)&lutg[(size_t)i0 * 4];
        float4 B = *(const float4*)&lutg[(size_t)(i0 + 1) * 4];
        float4 as4 = *(const float4*)&asd[(size_t)s * 8];
        float4 ad4 = *(const float4*)&asd[(size_t)n * 8 + 4];
        float v0 = as4.x + ad4.x + A.x + (B.x - A.x) * fr;
        float v1 = as4.y + ad4.y + A.y + (B.y - A.y) * fr;
        float v2 = as4.z + ad4.z + A.z + (B.z - A.z) * fr;
        float v3 = as4.w + ad4.w + A.w + (B.w - A.w) * fr;
        v0 = fmaxf(v0, 0.2f * v0);
        v1 = fmaxf(v1, 0.2f * v1);
        v2 = fmaxf(v2, 0.2f * v2);
        v3 = fmaxf(v3, 0.2f * v3);
        *(float4*)&wb[(size_t)p * 4] = make_float4(
            __expf(v0), __expf(v1), __expf(v2), __expf(v3));
    }
}

// ---------------------------------------------------------------------------
// K6 (MFMA): x = hbuf @ W2 (+ logits) via mfma_f32_16x16x32_f16.
// ---------------------------------------------------------------------------
__global__ __launch_bounds__(256) void k_xm(
    const __half* __restrict__ h, const float* __restrict__ Wg,
    const float* __restrict__ atts, const float* __restrict__ attd,
    __half* __restrict__ x16, float* __restrict__ asd)
{
    __shared__ __half Wt[128 * 136];
    __shared__ float attS[128], attD[128];
    int t = threadIdx.x;
    for (int i = t; i < 128 * 32; i += 256) {
        int c = i & 127, d = (i >> 7) * 4;
        float w0 = Wg[(d + 0) * 128 + c];
        float w1 = Wg[(d + 1) * 128 + c];
        float w2 = Wg[(d + 2) * 128 + c];
        float w3 = Wg[(d + 3) * 128 + c];
        __half2 p0 = __floats2half2_rn(w0, w1);
        __half2 p1 = __floats2half2_rn(w2, w3);
        uint2 pk;
        pk.x = *(unsigned*)&p0;
        pk.y = *(unsigned*)&p1;
        *(uint2*)&Wt[c * 136 + d] = pk;
    }
    if (t < 128) { attS[t] = atts[t]; attD[t] = attd[t]; }
    __syncthreads();
    int wv = t >> 6, lane = t & 63;
    int m16 = lane & 15, quad = lane >> 4;
    int n0 = blockIdx.x * 64 + wv * 16;
    f32x4 acc[8];
    #pragma unroll
    for (int ct = 0; ct < 8; ct++) acc[ct] = (f32x4){0.f, 0.f, 0.f, 0.f};
    #pragma unroll
    for (int ks = 0; ks < 4; ks++) {
        int d0 = ks * 32 + quad * 8;
        half8 bf = *(const half8*)&h[(size_t)(n0 + m16) * 128 + d0];
        #pragma unroll
        for (int ct = 0; ct < 8; ct++) {
            half8 af = *(const half8*)&Wt[(ct * 16 + m16) * 136 + d0];
            acc[ct] = __builtin_amdgcn_mfma_f32_16x16x32_f16(af, bf, acc[ct], 0, 0, 0);
        }
    }
    __half* xrow = &x16[(size_t)(n0 + m16) * 128 + quad * 4];
    float ps[4] = {0.f, 0.f, 0.f, 0.f}, pd[4] = {0.f, 0.f, 0.f, 0.f};
    #pragma unroll
    for (int ct = 0; ct < 8; ct++) {
        f32x4 a = acc[ct];
        __half2 h0p = __floats2half2_rn(a[0], a[1]);
        __half2 h1p = __floats2half2_rn(a[2], a[3]);
        uint2 pk;
        pk.x = *(unsigned*)&h0p;
        pk.y = *(unsigned*)&h1p;
        *(uint2*)&xrow[ct * 16] = pk;
        int cb = ct * 16 + quad * 4;
        int hh = ct >> 1;
        ps[hh] += a[0] * attS[cb] + a[1] * attS[cb + 1]
                + a[2] * attS[cb + 2] + a[3] * attS[cb + 3];
        pd[hh] += a[0] * attD[cb] + a[1] * attD[cb + 1]
                + a[2] * attD[cb + 2] + a[3] * attD[cb + 3];
    }
    #pragma unroll
    for (int hh = 0; hh < 4; hh++) {
        ps[hh] += __shfl_xor(ps[hh], 16, 64);
        ps[hh] += __shfl_xor(ps[hh], 32, 64);
        pd[hh] += __shfl_xor(pd[hh], 16, 64);
        pd[hh] += __shfl_xor(pd[hh], 32, 64);
    }
    if (lane < 16) {
        int n = n0 + m16;
        *(float4*)&asd[(size_t)n * 8]     = make_float4(ps[0], ps[1], ps[2], ps[3]);
        *(float4*)&asd[(size_t)n * 8 + 4] = make_float4(pd[0], pd[1], pd[2], pd[3]);
    }
}

// ---------------------------------------------------------------------------
// K7 (layer-2 weights, node-major, water only): wave per node, lanes
// edge-parallel. wb[slot][4] = exp(leaky(as+ae+ad)).
// ---------------------------------------------------------------------------
__global__ __launch_bounds__(256) void k_w2(
    const int* __restrict__ off, const unsigned* __restrict__ e4,
    const float* __restrict__ lutg, const float* __restrict__ asd,
    float* __restrict__ wb)
{
    int wv = threadIdx.x >> 6, lane = threadIdx.x & 63;
    int n = N_PRO + blockIdx.x * 4 + wv;
    if (n >= NN) return;
    int beg = off[n], end = off[n + 1];
    float4 ad4 = *(const float4*)&asd[(size_t)n * 8 + 4];
    for (int i = beg + lane; i < end; i += 64) {
        unsigned u = e4[i];
        unsigned s = u >> 15;
        float f = fminf((float)(u & 32767u) * 0.0625f, (float)(LUTN - 2));
        int i0 = (int)f;
        float fr = f - (float)i0;
        float4 A = *(const float4*)&lutg[(size_t)i0 * 4];
        float4 B = *(const float4*)&lutg[(size_t)(i0 + 1) * 4];
        float4 as4 = *(const float4*)&asd[(size_t)s * 8];
        float v0 = as4.x + ad4.x + A.x + (B.x - A.x) * fr;
        float v1 = as4.y + ad4.y + A.y + (B.y - A.y) * fr;
        float v2 = as4.z + ad4.z + A.z + (B.z - A.z) * fr;
        float v3 = as4.w + ad4.w + A.w + (B.w - A.w) * fr;
        v0 = fmaxf(v0, 0.2f * v0);
        v1 = fmaxf(v1, 0.2f * v1);
        v2 = fmaxf(v2, 0.2f * v2);
        v3 = fmaxf(v3, 0.2f * v3);
        *(float4*)&wb[(size_t)i * 4] = make_float4(
            __expf(v0), __expf(v1), __expf(v2), __expf(v3));
    }
}

// ---------------------------------------------------------------------------
// K8a: layer-1 aggregation, GROUP-RESTRUCTURED for memory-level parallelism.
// 16-lane group per node (4 nodes/wave, 16 nodes/block): q=lane&15 covers the
// 32-half h0 row; each lane accumulates all 4 heads x 2 chans. Same total FMA
// as before, but 4 independent edge streams per wave and 4x fewer load
// instructions (e4/wb are per-group addresses, not wave-uniform).
// ---------------------------------------------------------------------------
__global__ __launch_bounds__(256) void k_aggz(
    const int* __restrict__ off, const unsigned* __restrict__ e4,
    const float* __restrict__ wb, const __half* __restrict__ h016,
    __half* __restrict__ zbuf)
{
    int t = threadIdx.x;
    int wv = t >> 6, lane = t & 63;
    int g = lane >> 4, q = lane & 15;
    int n = blockIdx.x * 16 + wv * 4 + g;        // grid exact: NN/16
    int beg = off[n], end = off[n + 1];
    const __half2* x2 = (const __half2*)h016;
    float a0x = 0.f, a0y = 0.f, a1x = 0.f, a1y = 0.f;
    float a2x = 0.f, a2y = 0.f, a3x = 0.f, a3y = 0.f;
    float l0 = 0.f, l1 = 0.f, l2 = 0.f, l3 = 0.f;
    int i = beg;
    for (; i + 1 < end; i += 2) {
        unsigned u0 = e4[i], u1 = e4[i + 1];
        float4 w0 = *(const float4*)&wb[(size_t)i * 4];
        float4 w1 = *(const float4*)&wb[(size_t)(i + 1) * 4];
        float2 x0 = __half22float2(x2[(u0 >> 15) * 16u + q]);
        float2 x1 = __half22float2(x2[(u1 >> 15) * 16u + q]);
        a0x += w0.x * x0.x + w1.x * x1.x;  a0y += w0.x * x0.y + w1.x * x1.y;
        a1x += w0.y * x0.x + w1.y * x1.x;  a1y += w0.y * x0.y + w1.y * x1.y;
        a2x += w0.z * x0.x + w1.z * x1.x;  a2y += w0.z * x0.y + w1.z * x1.y;
        a3x += w0.w * x0.x + w1.w * x1.x;  a3y += w0.w * x0.y + w1.w * x1.y;
        l0 += w0.x + w1.x;  l1 += w0.y + w1.y;
        l2 += w0.z + w1.z;  l3 += w0.w + w1.w;
    }
    if (i < end) {
        unsigned u0 = e4[i];
        float4 w0 = *(const float4*)&wb[(size_t)i * 4];
        float2 x0 = __half22float2(x2[(u0 >> 15) * 16u + q]);
        a0x += w0.x * x0.x;  a0y += w0.x * x0.y;
        a1x += w0.y * x0.x;  a1y += w0.y * x0.y;
        a2x += w0.z * x0.x;  a2y += w0.z * x0.y;
        a3x += w0.w * x0.x;  a3y += w0.w * x0.y;
        l0 += w0.x; l1 += w0.y; l2 += w0.z; l3 += w0.w;
    }
    float i0v = 1.0f / (l0 + 1e-16f);
    float i1v = 1.0f / (l1 + 1e-16f);
    float i2v = 1.0f / (l2 + 1e-16f);
    float i3v = 1.0f / (l3 + 1e-16f);
    __half* zr = &zbuf[(size_t)n * 128];
    *(__half2*)&zr[      q * 2] = __floats2half2_rn(a0x * i0v, a0y * i0v);
    *(__half2*)&zr[32  + q * 2] = __floats2half2_rn(a1x * i1v, a1y * i1v);
    *(__half2*)&zr[64  + q * 2] = __floats2half2_rn(a2x * i2v, a2y * i2v);
    *(__half2*)&zr[96  + q * 2] = __floats2half2_rn(a3x * i3v, a3y * i3v);
}

// ---------------------------------------------------------------------------
// K8a2 (k_zm, MFMA): hbuf = elu(z @blockdiag(W1) + b1).
// ---------------------------------------------------------------------------
__global__ __launch_bounds__(256) void k_zm(
    const __half* __restrict__ zbuf, const float* __restrict__ W1g,
    const float* __restrict__ b1, __half* __restrict__ hbuf)
{
    __shared__ __half Wt[128 * 40];   // [col c][k], 80B rows (16B aligned)
    int t = threadIdx.x;
    for (int i = t; i < 128 * 8; i += 256) {
        int c = i & 127, k4 = (i >> 7) * 4;
        float w0 = W1g[(k4 + 0) * 128 + c];
        float w1 = W1g[(k4 + 1) * 128 + c];
        float w2 = W1g[(k4 + 2) * 128 + c];
        float w3 = W1g[(k4 + 3) * 128 + c];
        __half2 p0 = __floats2half2_rn(w0, w1);
        __half2 p1 = __floats2half2_rn(w2, w3);
        uint2 pk;
        pk.x = *(unsigned*)&p0;
        pk.y = *(unsigned*)&p1;
        *(uint2*)&Wt[c * 40 + k4] = pk;
    }
    __syncthreads();
    int wv = t >> 6, lane = t & 63;
    int m16 = lane & 15, quad = lane >> 4;
    int n0 = blockIdx.x * 64 + wv * 16;
    half8 bf[4];
    #pragma unroll
    for (int hh = 0; hh < 4; hh++)
        bf[hh] = *(const half8*)&zbuf[(size_t)(n0 + m16) * 128 + hh * 32 + quad * 8];
    f32x4 acc[8];
    #pragma unroll
    for (int ct = 0; ct < 8; ct++) {
        half8 af = *(const half8*)&Wt[(ct * 16 + m16) * 40 + quad * 8];
        acc[ct] = __builtin_amdgcn_mfma_f32_16x16x32_f16(
            af, bf[ct >> 1], (f32x4){0.f, 0.f, 0.f, 0.f}, 0, 0, 0);
    }
    __half* orow = &hbuf[(size_t)(n0 + m16) * 128 + quad * 4];
    #pragma unroll
    for (int ct = 0; ct < 8; ct++) {
        int cb = ct * 16 + quad * 4;
        float4 bb = *(const float4*)&b1[cb];
        float r0 = acc[ct][0] + bb.x;
        float r1 = acc[ct][1] + bb.y;
        float r2 = acc[ct][2] + bb.z;
        float r3 = acc[ct][3] + bb.w;
        r0 = r0 > 0.f ? r0 : __expf(r0) - 1.0f;
        r1 = r1 > 0.f ? r1 : __expf(r1) - 1.0f;
        r2 = r2 > 0.f ? r2 : __expf(r2) - 1.0f;
        r3 = r3 > 0.f ? r3 : __expf(r3) - 1.0f;
        __half2 ha = __floats2half2_rn(r0, r1);
        __half2 hb = __floats2half2_rn(r2, r3);
        uint2 pk;
        pk.x = *(unsigned*)&ha;
        pk.y = *(unsigned*)&hb;
        *(uint2*)&orow[ct * 16] = pk;
    }
}

// ---------------------------------------------------------------------------
// K8b: layer-2 aggregation, GROUP-RESTRUCTURED: 32-lane group per node
// (2 nodes/wave, 8 nodes/block). Lane q=lane&31 covers chans q*4..q*4+3 of
// the 256B x16 row; all 4 chans share head h=q>>3 so lsum is lane-local.
// ---------------------------------------------------------------------------
__global__ __launch_bounds__(256) void k_agg2(
    const int* __restrict__ off, const unsigned* __restrict__ e4,
    const float* __restrict__ wb, const __half* __restrict__ x16,
    const float* __restrict__ bias, __half* __restrict__ hout)
{
    int t = threadIdx.x;
    int wv = t >> 6, lane = t & 63;
    int g = lane >> 5, q = lane & 31;
    int n = N_PRO + blockIdx.x * 8 + wv * 2 + g;  // grid exact: N_WAT/8
    int h = q >> 3;
    int beg = off[n], end = off[n + 1];
    float ax = 0.f, ay = 0.f, az = 0.f, aw = 0.f, ls = 0.f;
    int i = beg;
    for (; i + 1 < end; i += 2) {
        unsigned u0 = e4[i], u1 = e4[i + 1];
        float w0 = wb[(size_t)i * 4 + h];
        float w1 = wb[(size_t)(i + 1) * 4 + h];
        float2 r0 = *(const float2*)&x16[(size_t)(u0 >> 15) * 128 + q * 4];
        float2 r1 = *(const float2*)&x16[(size_t)(u1 >> 15) * 128 + q * 4];
        float2 f00 = __half22float2(*(__half2*)&r0.x);
        float2 f01 = __half22float2(*(__half2*)&r0.y);
        float2 f10 = __half22float2(*(__half2*)&r1.x);
        float2 f11 = __half22float2(*(__half2*)&r1.y);
        ax += w0 * f00.x + w1 * f10.x;
        ay += w0 * f00.y + w1 * f10.y;
        az += w0 * f01.x + w1 * f11.x;
        aw += w0 * f01.y + w1 * f11.y;
        ls += w0 + w1;
    }
    if (i < end) {
        unsigned u0 = e4[i];
        float w0 = wb[(size_t)i * 4 + h];
        float2 r0 = *(const float2*)&x16[(size_t)(u0 >> 15) * 128 + q * 4];
        float2 f00 = __half22float2(*(__half2*)&r0.x);
        float2 f01 = __half22float2(*(__half2*)&r0.y);
        ax += w0 * f00.x; ay += w0 * f00.y;
        az += w0 * f01.x; aw += w0 * f01.y;
        ls += w0;
    }
    float inv = 1.0f / (ls + 1e-16f);
    float4 bb = *(const float4*)&bias[q * 4];
    float o0 = ax * inv + bb.x;
    float o1 = ay * inv + bb.y;
    float o2 = az * inv + bb.z;
    float o3 = aw * inv + bb.w;
    o0 = o0 > 0.f ? o0 : __expf(o0) - 1.0f;
    o1 = o1 > 0.f ? o1 : __expf(o1) - 1.0f;
    o2 = o2 > 0.f ? o2 : __expf(o2) - 1.0f;
    o3 = o3 > 0.f ? o3 : __expf(o3) - 1.0f;
    __half2 ha = __floats2half2_rn(o0, o1);
    __half2 hb = __floats2half2_rn(o2, o3);
    uint2 pk;
    pk.x = *(unsigned*)&ha;
    pk.y = *(unsigned*)&hb;
    *(uint2*)&hout[(size_t)n * 128 + q * 4] = pk;
}

// ---------------------------------------------------------------------------
// K9: water MLP. 32-node tile/block, padded stride 132, register-blocked.
// ---------------------------------------------------------------------------
__global__ __launch_bounds__(256) void k_mlp(
    const __half* __restrict__ hh, const float* __restrict__ Wm1,
    const float* __restrict__ bm1, const float* __restrict__ Wm2,
    const float* __restrict__ bm2, float* __restrict__ out)
{
    __shared__ float W1s[128 * 64];
    __shared__ float hs[32 * 132];
    int t = threadIdx.x;
    int g = t >> 5, q = t & 31;
    float b1r[2][2], w2r[2][2][2];
    #pragma unroll
    for (int hf = 0; hf < 2; hf++)
        #pragma unroll
        for (int j = 0; j < 2; j++) {
            int c = hf * 64 + q * 2 + j;
            b1r[hf][j] = bm1[c];
            w2r[hf][j][0] = Wm2[c * 2 + 0];
            w2r[hf][j][1] = Wm2[c * 2 + 1];
        }
    float b20 = bm2[0], b21 = bm2[1];
    int tile = blockIdx.x;
    {
        int r = t >> 3, c0 = (t & 7) * 16;
        const __half* src = &hh[(size_t)(N_PRO + tile * 32 + r) * 128 + c0];
        uint4 raw0 = *(const uint4*)src;
        uint4 raw1 = *(const uint4*)(src + 8);
        const __half2* hp0 = (const __half2*)&raw0;
        const __half2* hp1 = (const __half2*)&raw1;
        #pragma unroll
        for (int j = 0; j < 4; j++) {
            float2 fa = __half22float2(j < 2 ? hp0[2 * j] : hp1[2 * (j - 2)]);
            float2 fb = __half22float2(j < 2 ? hp0[2 * j + 1] : hp1[2 * (j - 2) + 1]);
            *(float4*)&hs[r * 132 + c0 + 4 * j] = make_float4(fa.x, fa.y, fb.x, fb.y);
        }
    }
    float p0[4] = {0.f, 0.f, 0.f, 0.f}, p1[4] = {0.f, 0.f, 0.f, 0.f};
    #pragma unroll
    for (int hf = 0; hf < 2; hf++) {
        __syncthreads();
        for (int i = t; i < 128 * 64; i += 256)
            W1s[i] = Wm1[(size_t)(i >> 6) * 128 + hf * 64 + (i & 63)];
        __syncthreads();
        float a[4][2];
        #pragma unroll
        for (int i = 0; i < 4; i++) { a[i][0] = 0.f; a[i][1] = 0.f; }
        for (int d0 = 0; d0 < 128; d0 += 4) {
            float4 hv[4];
            #pragma unroll
            for (int i = 0; i < 4; i++)
                hv[i] = *(const float4*)&hs[(g + 8 * i) * 132 + d0];
            #pragma unroll
            for (int dd = 0; dd < 4; dd++) {
                float2 wv = *(const float2*)&W1s[(d0 + dd) * 64 + q * 2];
                #pragma unroll
                for (int i = 0; i < 4; i++) {
                    float hvv = (&hv[i].x)[dd];
                    a[i][0] += hvv * wv.x;
                    a[i][1] += hvv * wv.y;
                }
            }
        }
        #pragma unroll
        for (int i = 0; i < 4; i++) {
            float a0 = fmaxf(a[i][0] + b1r[hf][0], 0.f);
            float a1 = fmaxf(a[i][1] + b1r[hf][1], 0.f);
            p0[i] += a0 * w2r[hf][0][0] + a1 * w2r[hf][1][0];
            p1[i] += a0 * w2r[hf][0][1] + a1 * w2r[hf][1][1];
        }
    }
    #pragma unroll
    for (int m = 1; m < 32; m <<= 1) {
        #pragma unroll
        for (int i = 0; i < 4; i++) {
            p0[i] += __shfl_xor(p0[i], m, 64);
            p1[i] += __shfl_xor(p1[i], m, 64);
        }
    }
    if (q == 0) {
        #pragma unroll
        for (int i = 0; i < 4; i++) {
            int n = tile * 32 + g + 8 * i;
            *(float2*)&out[n * 2] = make_float2(p0[i] + b20, p1[i] + b21);
        }
    }
}

// ---------------------------------------------------------------------------
extern "C" void kernel_launch(void* const* d_in, const int* in_sizes, int n_in,
                              void* d_out, int out_size, void* d_ws, size_t ws_size,
                              hipStream_t stream)
{
    const float* ppos   = (const float*)d_in[0];
    const float* wpos   = (const float*)d_in[1];
    const float* pfeat  = (const float*)d_in[2];
    const int*   ei     = (const int*)d_in[3];
    const float* gamma  = (const float*)d_in[4];
    const float* Wf     = (const float*)d_in[5];
    const float* bfv    = (const float*)d_in[6];
    const float* We     = (const float*)d_in[7];
    const float* be     = (const float*)d_in[8];
    const float* W1     = (const float*)d_in[9];
    const float* atts1  = (const float*)d_in[10];
    const float* attd1  = (const float*)d_in[11];
    const float* Wedge1 = (const float*)d_in[12];
    const float* atte1  = (const float*)d_in[13];
    const float* b1     = (const float*)d_in[14];
    const float* W2     = (const float*)d_in[15];
    const float* atts2  = (const float*)d_in[16];
    const float* attd2  = (const float*)d_in[17];
    const float* Wedge2 = (const float*)d_in[18];
    const float* atte2  = (const float*)d_in[19];
    const float* b2     = (const float*)d_in[20];
    const float* Wm1    = (const float*)d_in[21];
    const float* bm1    = (const float*)d_in[22];
    const float* Wm2    = (const float*)d_in[23];
    const float* bm2    = (const float*)d_in[24];
    float* out = (float*)d_out;

    char* ws = (char*)d_ws;
    size_t o = 0;
    auto alloc = [&](size_t bytes) -> char* {
        char* p = ws + o;
        o += (bytes + 255) & ~(size_t)255;
        return p;
    };
    __half*   h0      = (__half*)alloc((size_t)NNP * 32 * 2);
    __half*   x16     = (__half*)alloc((size_t)NNP * 128 * 2);   // also zbuf
    __half*   hbuf    = (__half*)alloc((size_t)NNP * 128 * 2);
    float*    asd     = (float*)alloc((size_t)NNP * 8 * 4);
    float*    wb      = (float*)alloc((size_t)NE * 4 * 4);       // exp'd weights
    int*      offp    = (int*)alloc((size_t)(NN + 1) * 4);
    unsigned* e4      = (unsigned*)alloc((size_t)NE * 4);
    int*      gbh     = (int*)alloc(256 * 4);
    int*      gboff   = (int*)alloc(256 * 4);
    int*      gcur    = (int*)alloc(256 * 4);
    float*    smallw  = (float*)alloc(4096);
    float*    lutbuf  = (float*)alloc((size_t)2 * LUTN * 4 * 4);
    // ebuf2 (8 MB) overlays hbuf (25.6 MB): ebuf2 is written by k_scat and
    // last read by k_fine, strictly before hbuf's first write in k_zm.
    uint2*    ebuf2   = (uint2*)hbuf;

    hipMemsetAsync(gbh, 0, 256 * 4, stream);
    k_small<<<1, 256, 0, stream>>>(We, be, Wedge1, atte1, Wedge2, atte2, Wf, bfv,
                                   W1, atts1, attd1, smallw);
    k_lut<<<(2 * LUTN + 255) / 256, 256, 0, stream>>>(smallw, gamma, lutbuf);
    k_h0<<<NH0B, 256, 0, stream>>>(pfeat, Wf, bfv, smallw, h0, asd);
    // CSR build: coarse count -> scan -> bucket scatter -> fine place (+w L1)
    k_bcnt<<<SCATB, 256, 0, stream>>>(ei, gbh);
    k_bscan<<<1, 256, 0, stream>>>(gbh, gboff, gcur, offp);
    k_scat<<<SCATB, 256, 0, stream>>>(ei, ppos, wpos, gcur, ebuf2);
    k_fine<<<NBUCK, 1024, 0, stream>>>(gboff, ebuf2, lutbuf, asd, offp, e4, wb);
    // layer 1: lean aggregation (weights prebuilt by k_fine), MFMA W1
    k_aggz<<<NN / 16, 256, 0, stream>>>(offp, e4, wb, h0, x16);
    k_zm<<<NNP / 64, 256, 0, stream>>>(x16, W1, b1, hbuf);
    // layer 2 (water destinations only)
    k_xm<<<NNP / 64, 256, 0, stream>>>(hbuf, W2, atts2, attd2, x16, asd);
    k_w2<<<N_WAT / 4, 256, 0, stream>>>(offp, e4, lutbuf + (size_t)LUTN * 4, asd, wb);
    k_agg2<<<N_WAT / 8, 256, 0, stream>>>(offp, e4, wb, x16, b2, hbuf);
    // MLP on water nodes
    k_mlp<<<N_WAT / 32, 256, 0, stream>>>(hbuf, Wm1, bm1, Wm2, bm2, out);
}

// Round 4
// 325.329 us; speedup vs baseline: 1.1658x; 1.0906x over previous
//
#include <hip/hip_runtime.h>
#include <hip/hip_fp16.h>
#include <stdint.h>

#define N_PRO 60000
#define N_WAT 40000
#define NN    100000
#define NNP   100032            // padded to a multiple of 64 for tiles
#define NE    1000000
#define IN_DIM 21
#define HID    32
#define HEADS  4
#define HC     128
#define EDGE_K 32
#define LUTN   2048             // distance-LUT bins, bin = dist*256 (range [0,8))
#define NH0B  ((NNP * 32) / 256)       // h0 blocks
#define NBUCK 196                      // coarse buckets of 512 nodes (node>>9)
#define EPT   8                        // edges per thread in bcnt/scat
#define SCATB ((NE / EPT + 255) / 256) // 489 blocks
#define FCAP  6144                     // per-bucket LDS staging capacity (edges)

typedef _Float16 half8 __attribute__((ext_vector_type(8)));
typedef float    f32x4 __attribute__((ext_vector_type(4)));

// ---------------------------------------------------------------------------
// K1: tiny fused weights (ONE block). smallw floats: [0..127]=U1,
// [128..131]=aeb1, [132..259]=U2, [260..263]=aeb2, [264..295]=h0w,
// [296..423]=va_s1, [424..551]=va_d1
// ---------------------------------------------------------------------------
__global__ __launch_bounds__(256) void k_small(
    const float* We, const float* be,
    const float* Wedge1, const float* atte1,
    const float* Wedge2, const float* atte2,
    const float* Wf, const float* bfv,
    const float* W1, const float* atts1, const float* attd1,
    float* smallw)
{
    __shared__ float V[2][128];
    int t = threadIdx.x;
    {
        int l = t >> 7, dh = t & 127, d = dh >> 2, h = dh & 3;
        const float* Wg = l ? Wedge2 : Wedge1;
        const float* ae = l ? atte2 : atte1;
        float s = 0.f;
        for (int c = 0; c < HID; c++)
            s += Wg[d * HC + h * HID + c] * ae[h * HID + c];
        V[l][dh] = s;
    }
    __syncthreads();
    {
        int l = t >> 7, kh = t & 127, k = kh >> 2, h = kh & 3;
        float s = 0.f;
        for (int d = 0; d < 32; d++)
            s += We[k * 32 + d] * V[l][d * 4 + h];
        smallw[(l ? 132 : 0) + kh] = s;
    }
    if (t < 8) {
        int l = t >> 2, h = t & 3;
        float s = 0.f;
        for (int d = 0; d < 32; d++)
            s += be[d] * V[l][d * 4 + h];
        smallw[(l ? 260 : 128) + h] = s;
    }
    if (t >= 32 && t < 64) {
        int c = t - 32;
        smallw[264 + c] = Wf[20 * 32 + c] + bfv[c];
    }
    {
        int side = t >> 7;
        int h = (t >> 5) & 3, c = t & 31;
        const float* av = side ? attd1 : atts1;
        float s = 0.f;
        for (int j = 0; j < 32; j++)
            s += W1[c * 128 + h * 32 + j] * av[h * 32 + j];
        smallw[(side ? 424 : 296) + (t & 127)] = s;
    }
}

// ---------------------------------------------------------------------------
// K1b: distance LUT. bin b corresponds to dist = b/256.
// ---------------------------------------------------------------------------
__global__ __launch_bounds__(256) void k_lut(
    const float* __restrict__ smallw, const float* __restrict__ gamma,
    float* __restrict__ lut)
{
    int e = blockIdx.x * 256 + threadIdx.x;
    if (e >= 2 * LUTN) return;
    int layer = e >> 11, bin = e & (LUTN - 1);
    const float* U = smallw + (layer ? 132 : 0);
    const float* aeb = smallw + (layer ? 260 : 128);
    float dd = bin * (1.0f / 256.0f);
    float g = gamma[0];
    float a0 = aeb[0], a1 = aeb[1], a2 = aeb[2], a3 = aeb[3];
    const float step = 5.0f / 31.0f;
    #pragma unroll
    for (int k = 0; k < EDGE_K; k++) {
        float tt = dd - (float)k * step;
        float r = __expf(-g * tt * tt);
        a0 += r * U[k * 4 + 0];
        a1 += r * U[k * 4 + 1];
        a2 += r * U[k * 4 + 2];
        a3 += r * U[k * 4 + 3];
    }
    *(float4*)&lut[(size_t)e * 4] = make_float4(a0, a1, a2, a3);
}

// ---------------------------------------------------------------------------
// K2 (pure): h0 = feats@Wf+bf (fp16) + layer-1 logits asd.
// ---------------------------------------------------------------------------
__global__ __launch_bounds__(256) void k_h0(
    const float* __restrict__ pf, const float* __restrict__ Wf,
    const float* __restrict__ bfv, const float* __restrict__ smallw,
    __half* __restrict__ h0, float* __restrict__ asd)
{
    int t = threadIdx.x;
    __shared__ float Wfs[IN_DIM * 32];
    __shared__ float bfs[32];
    __shared__ float h0w[32];
    __shared__ float vas[128], vad[128];
    for (int i = t; i < IN_DIM * 32; i += 256) Wfs[i] = Wf[i];
    if (t < 32) { bfs[t] = bfv[t]; h0w[t] = smallw[264 + t]; }
    if (t < 128) vas[t] = smallw[296 + t];
    else         vad[t - 128] = smallw[424 + (t - 128)];
    __syncthreads();
    int id = blockIdx.x * 256 + t;
    int n = id >> 5, c = id & 31;
    if (n >= NNP) return;
    float v;
    if (n < N_PRO) {
        float s = bfs[c];
        for (int k = 0; k < IN_DIM; k++)
            s += pf[n * IN_DIM + k] * Wfs[k * 32 + c];
        v = s;
    } else {
        v = h0w[c];
    }
    h0[(size_t)n * 32 + c] = __float2half(v);
    float ps[4], pd[4];
    #pragma unroll
    for (int h = 0; h < 4; h++) {
        ps[h] = v * vas[h * 32 + c];
        pd[h] = v * vad[h * 32 + c];
    }
    #pragma unroll
    for (int m = 1; m < 32; m <<= 1) {
        #pragma unroll
        for (int h = 0; h < 4; h++) {
            ps[h] += __shfl_xor(ps[h], m, 64);
            pd[h] += __shfl_xor(pd[h], m, 64);
        }
    }
    if ((t & 31) == 0) {
        *(float4*)&asd[(size_t)n * 8]     = make_float4(ps[0], ps[1], ps[2], ps[3]);
        *(float4*)&asd[(size_t)n * 8 + 4] = make_float4(pd[0], pd[1], pd[2], pd[3]);
    }
}

// ---------------------------------------------------------------------------
// CSR build, atomic-light. Coarse bucket = dst>>9 (512 nodes per bucket).
// ---------------------------------------------------------------------------
__global__ __launch_bounds__(256) void k_bcnt(
    const int* __restrict__ ei, int* __restrict__ gbh)
{
    __shared__ int lh[256];
    int t = threadIdx.x;
    lh[t] = 0;
    __syncthreads();
    int e0 = (blockIdx.x * 256 + t) * EPT;
    if (e0 < NE) {                       // NE % EPT == 0 -> full vector ok
        int4 da = *(const int4*)&ei[NE + e0];
        int4 db = *(const int4*)&ei[NE + e0 + 4];
        int ds[8] = {da.x, da.y, da.z, da.w, db.x, db.y, db.z, db.w};
        #pragma unroll
        for (int j = 0; j < EPT; j++)
            if ((unsigned)ds[j] < (unsigned)NN)
                atomicAdd(&lh[ds[j] >> 9], 1);
    }
    __syncthreads();
    if (t < NBUCK && lh[t]) atomicAdd(&gbh[t], lh[t]);
}

// scan 196 bucket counts -> global bucket offsets + cursors; off[NN]=total.
__global__ __launch_bounds__(256) void k_bscan(
    const int* __restrict__ gbh, int* __restrict__ gboff,
    int* __restrict__ gcur, int* __restrict__ offp)
{
    __shared__ int s[256];
    int t = threadIdx.x;
    int v = (t < NBUCK) ? gbh[t] : 0;
    s[t] = v;
    __syncthreads();
    #pragma unroll
    for (int o = 1; o < 256; o <<= 1) {
        int x = (t >= o) ? s[t - o] : 0;
        __syncthreads();
        s[t] += x;
        __syncthreads();
    }
    int ex = s[t] - v;
    if (t < NBUCK) { gboff[t] = ex; gcur[t] = ex; }
    if (t == NBUCK - 1) { gboff[NBUCK] = s[t]; offp[NN] = s[t]; }
}

// k_scat: rank edges within (block,bucket) via LDS atomics; one global
// atomic per (block,bucket) for the base; write (dst|code, src) records.
__global__ __launch_bounds__(256) void k_scat(
    const int* __restrict__ ei, const float* __restrict__ ppos,
    const float* __restrict__ wpos, int* __restrict__ gcur,
    uint2* __restrict__ ebuf2)
{
    __shared__ int lh[256];
    __shared__ int lbase[256];
    int t = threadIdx.x;
    lh[t] = 0;
    __syncthreads();
    int e0 = (blockIdx.x * 256 + t) * EPT;
    int bkt[EPT], rnk[EPT];
    unsigned rec0[EPT], rec1[EPT];
    #pragma unroll
    for (int j = 0; j < EPT; j++) bkt[j] = -1;
    if (e0 < NE) {
        int4 sa = *(const int4*)&ei[e0];
        int4 sb = *(const int4*)&ei[e0 + 4];
        int4 da = *(const int4*)&ei[NE + e0];
        int4 db = *(const int4*)&ei[NE + e0 + 4];
        int ss[8] = {sa.x, sa.y, sa.z, sa.w, sb.x, sb.y, sb.z, sb.w};
        int ds[8] = {da.x, da.y, da.z, da.w, db.x, db.y, db.z, db.w};
        #pragma unroll
        for (int j = 0; j < EPT; j++) {
            int s = ss[j], d = ds[j];
            if ((unsigned)d < (unsigned)NN) {
                const float* ps = (s < N_PRO) ? &ppos[s * 3] : &wpos[(s - N_PRO) * 3];
                const float* pd = (d < N_PRO) ? &ppos[d * 3] : &wpos[(d - N_PRO) * 3];
                float dx = pd[0] - ps[0];
                float dy = pd[1] - ps[1];
                float dz = pd[2] - ps[2];
                float dist = sqrtf(dx * dx + dy * dy + dz * dz);
                unsigned code = (unsigned)fminf(dist * 4096.0f, 32767.0f);
                bkt[j] = d >> 9;
                rec0[j] = ((unsigned)d << 15) | code;
                rec1[j] = (unsigned)s;
                rnk[j] = atomicAdd(&lh[bkt[j]], 1);
            }
        }
    }
    __syncthreads();
    if (t < NBUCK) lbase[t] = lh[t] ? atomicAdd(&gcur[t], lh[t]) : 0;
    __syncthreads();
    #pragma unroll
    for (int j = 0; j < EPT; j++)
        if (bkt[j] >= 0)
            ebuf2[lbase[bkt[j]] + rnk[j]] = make_uint2(rec0[j], rec1[j]);
}

// k_fine: one block per bucket, 1024 threads. Stage bucket records in LDS,
// fine-count 512 local nodes, LDS scan -> GLOBAL off[] direct, then place
// each edge at its compact slot: write e4 AND the fully-exp'd layer-1 weight
// wb[slot][4] = exp(leaky(as + ae + ad)).
__global__ __launch_bounds__(1024) void k_fine(
    const int* __restrict__ gboff, const uint2* __restrict__ ebuf2,
    const float* __restrict__ lutg, const float* __restrict__ asd,
    int* __restrict__ offp, unsigned* __restrict__ e4,
    float* __restrict__ wb)
{
    __shared__ uint2 eL[FCAP];          // 48 KB
    __shared__ int lcnt[512], lexc[512], ssc[512];
    int b = blockIdx.x, t = threadIdx.x;
    int beg = gboff[b];
    int nb = gboff[b + 1] - beg;
    bool inl = (nb <= FCAP);
    if (inl)
        for (int i = t; i < nb; i += 1024) eL[i] = ebuf2[beg + i];
    if (t < 512) lcnt[t] = 0;
    __syncthreads();
    for (int i = t; i < nb; i += 1024) {
        uint2 u = inl ? eL[i] : ebuf2[beg + i];
        atomicAdd(&lcnt[(u.x >> 15) & 511], 1);
    }
    __syncthreads();
    int c = (t < 512) ? lcnt[t] : 0;
    if (t < 512) ssc[t] = c;
    __syncthreads();
    for (int o = 1; o < 512; o <<= 1) {
        int x = (t >= o && t < 512) ? ssc[t - o] : 0;
        __syncthreads();
        if (t < 512) ssc[t] += x;
        __syncthreads();
    }
    if (t < 512) {
        lexc[t] = ssc[t] - c;
        int node = b * 512 + t;
        if (node < NN) offp[node] = beg + lexc[t];
        lcnt[t] = 0;                     // reuse as per-node cursor
    }
    __syncthreads();
    for (int i = t; i < nb; i += 1024) {
        uint2 u = inl ? eL[i] : ebuf2[beg + i];
        int ln = (int)((u.x >> 15) & 511u);
        int r = atomicAdd(&lcnt[ln], 1);
        int p = beg + lexc[ln] + r;
        unsigned code = u.x & 32767u;
        unsigned s = u.y;
        e4[p] = (s << 15) | code;
        int n = (b << 9) + ln;
        float f = fminf((float)code * 0.0625f, (float)(LUTN - 2));
        int i0 = (int)f;
        float fr = f - (float)i0;
        float4 A = *(const float4*)&lutg[(size_t)i0 * 4];
        float4 B = *(const float4*)&lutg[(size_t)(i0 + 1) * 4];
        float4 as4 = *(const float4*)&asd[(size_t)s * 8];
        float4 ad4 = *(const float4*)&asd[(size_t)n * 8 + 4];
        float v0 = as4.x + ad4.x + A.x + (B.x - A.x) * fr;
        float v1 = as4.y + ad4.y + A.y + (B.y - A.y) * fr;
        float v2 = as4.z + ad4.z + A.z + (B.z - A.z) * fr;
        float v3 = as4.w + ad4.w + A.w + (B.w - A.w) * fr;
        v0 = fmaxf(v0, 0.2f * v0);
        v1 = fmaxf(v1, 0.2f * v1);
        v2 = fmaxf(v2, 0.2f * v2);
        v3 = fmaxf(v3, 0.2f * v3);
        *(float4*)&wb[(size_t)p * 4] = make_float4(
            __expf(v0), __expf(v1), __expf(v2), __expf(v3));
    }
}

// ---------------------------------------------------------------------------
// K6 (MFMA): x = hbuf @ W2 (+ logits) via mfma_f32_16x16x32_f16.
// ---------------------------------------------------------------------------
__global__ __launch_bounds__(256) void k_xm(
    const __half* __restrict__ h, const float* __restrict__ Wg,
    const float* __restrict__ atts, const float* __restrict__ attd,
    __half* __restrict__ x16, float* __restrict__ asd)
{
    __shared__ __half Wt[128 * 136];
    __shared__ float attS[128], attD[128];
    int t = threadIdx.x;
    for (int i = t; i < 128 * 32; i += 256) {
        int c = i & 127, d = (i >> 7) * 4;
        float w0 = Wg[(d + 0) * 128 + c];
        float w1 = Wg[(d + 1) * 128 + c];
        float w2 = Wg[(d + 2) * 128 + c];
        float w3 = Wg[(d + 3) * 128 + c];
        __half2 p0 = __floats2half2_rn(w0, w1);
        __half2 p1 = __floats2half2_rn(w2, w3);
        uint2 pk;
        pk.x = *(unsigned*)&p0;
        pk.y = *(unsigned*)&p1;
        *(uint2*)&Wt[c * 136 + d] = pk;
    }
    if (t < 128) { attS[t] = atts[t]; attD[t] = attd[t]; }
    __syncthreads();
    int wv = t >> 6, lane = t & 63;
    int m16 = lane & 15, quad = lane >> 4;
    int n0 = blockIdx.x * 64 + wv * 16;
    f32x4 acc[8];
    #pragma unroll
    for (int ct = 0; ct < 8; ct++) acc[ct] = (f32x4){0.f, 0.f, 0.f, 0.f};
    #pragma unroll
    for (int ks = 0; ks < 4; ks++) {
        int d0 = ks * 32 + quad * 8;
        half8 bf = *(const half8*)&h[(size_t)(n0 + m16) * 128 + d0];
        #pragma unroll
        for (int ct = 0; ct < 8; ct++) {
            half8 af = *(const half8*)&Wt[(ct * 16 + m16) * 136 + d0];
            acc[ct] = __builtin_amdgcn_mfma_f32_16x16x32_f16(af, bf, acc[ct], 0, 0, 0);
        }
    }
    __half* xrow = &x16[(size_t)(n0 + m16) * 128 + quad * 4];
    float ps[4] = {0.f, 0.f, 0.f, 0.f}, pd[4] = {0.f, 0.f, 0.f, 0.f};
    #pragma unroll
    for (int ct = 0; ct < 8; ct++) {
        f32x4 a = acc[ct];
        __half2 h0p = __floats2half2_rn(a[0], a[1]);
        __half2 h1p = __floats2half2_rn(a[2], a[3]);
        uint2 pk;
        pk.x = *(unsigned*)&h0p;
        pk.y = *(unsigned*)&h1p;
        *(uint2*)&xrow[ct * 16] = pk;
        int cb = ct * 16 + quad * 4;
        int hh = ct >> 1;
        ps[hh] += a[0] * attS[cb] + a[1] * attS[cb + 1]
                + a[2] * attS[cb + 2] + a[3] * attS[cb + 3];
        pd[hh] += a[0] * attD[cb] + a[1] * attD[cb + 1]
                + a[2] * attD[cb + 2] + a[3] * attD[cb + 3];
    }
    #pragma unroll
    for (int hh = 0; hh < 4; hh++) {
        ps[hh] += __shfl_xor(ps[hh], 16, 64);
        ps[hh] += __shfl_xor(ps[hh], 32, 64);
        pd[hh] += __shfl_xor(pd[hh], 16, 64);
        pd[hh] += __shfl_xor(pd[hh], 32, 64);
    }
    if (lane < 16) {
        int n = n0 + m16;
        *(float4*)&asd[(size_t)n * 8]     = make_float4(ps[0], ps[1], ps[2], ps[3]);
        *(float4*)&asd[(size_t)n * 8 + 4] = make_float4(pd[0], pd[1], pd[2], pd[3]);
    }
}

// ---------------------------------------------------------------------------
// K7 (layer-2 weights, node-major, water only): wave per node, lanes
// edge-parallel. wb[slot][4] = exp(leaky(as+ae+ad)).
// ---------------------------------------------------------------------------
__global__ __launch_bounds__(256) void k_w2(
    const int* __restrict__ off, const unsigned* __restrict__ e4,
    const float* __restrict__ lutg, const float* __restrict__ asd,
    float* __restrict__ wb)
{
    int wv = threadIdx.x >> 6, lane = threadIdx.x & 63;
    int n = N_PRO + blockIdx.x * 4 + wv;
    if (n >= NN) return;
    int beg = off[n], end = off[n + 1];
    float4 ad4 = *(const float4*)&asd[(size_t)n * 8 + 4];
    for (int i = beg + lane; i < end; i += 64) {
        unsigned u = e4[i];
        unsigned s = u >> 15;
        float f = fminf((float)(u & 32767u) * 0.0625f, (float)(LUTN - 2));
        int i0 = (int)f;
        float fr = f - (float)i0;
        float4 A = *(const float4*)&lutg[(size_t)i0 * 4];
        float4 B = *(const float4*)&lutg[(size_t)(i0 + 1) * 4];
        float4 as4 = *(const float4*)&asd[(size_t)s * 8];
        float v0 = as4.x + ad4.x + A.x + (B.x - A.x) * fr;
        float v1 = as4.y + ad4.y + A.y + (B.y - A.y) * fr;
        float v2 = as4.z + ad4.z + A.z + (B.z - A.z) * fr;
        float v3 = as4.w + ad4.w + A.w + (B.w - A.w) * fr;
        v0 = fmaxf(v0, 0.2f * v0);
        v1 = fmaxf(v1, 0.2f * v1);
        v2 = fmaxf(v2, 0.2f * v2);
        v3 = fmaxf(v3, 0.2f * v3);
        *(float4*)&wb[(size_t)i * 4] = make_float4(
            __expf(v0), __expf(v1), __expf(v2), __expf(v3));
    }
}

// ---------------------------------------------------------------------------
// K8a: layer-1 aggregation, 16-lane group per node (4 nodes/wave).
// ---------------------------------------------------------------------------
__global__ __launch_bounds__(256) void k_aggz(
    const int* __restrict__ off, const unsigned* __restrict__ e4,
    const float* __restrict__ wb, const __half* __restrict__ h016,
    __half* __restrict__ zbuf)
{
    int t = threadIdx.x;
    int wv = t >> 6, lane = t & 63;
    int g = lane >> 4, q = lane & 15;
    int n = blockIdx.x * 16 + wv * 4 + g;        // grid exact: NN/16
    int beg = off[n], end = off[n + 1];
    const __half2* x2 = (const __half2*)h016;
    float a0x = 0.f, a0y = 0.f, a1x = 0.f, a1y = 0.f;
    float a2x = 0.f, a2y = 0.f, a3x = 0.f, a3y = 0.f;
    float l0 = 0.f, l1 = 0.f, l2 = 0.f, l3 = 0.f;
    int i = beg;
    for (; i + 1 < end; i += 2) {
        unsigned u0 = e4[i], u1 = e4[i + 1];
        float4 w0 = *(const float4*)&wb[(size_t)i * 4];
        float4 w1 = *(const float4*)&wb[(size_t)(i + 1) * 4];
        float2 x0 = __half22float2(x2[(u0 >> 15) * 16u + q]);
        float2 x1 = __half22float2(x2[(u1 >> 15) * 16u + q]);
        a0x += w0.x * x0.x + w1.x * x1.x;  a0y += w0.x * x0.y + w1.x * x1.y;
        a1x += w0.y * x0.x + w1.y * x1.x;  a1y += w0.y * x0.y + w1.y * x1.y;
        a2x += w0.z * x0.x + w1.z * x1.x;  a2y += w0.z * x0.y + w1.z * x1.y;
        a3x += w0.w * x0.x + w1.w * x1.x;  a3y += w0.w * x0.y + w1.w * x1.y;
        l0 += w0.x + w1.x;  l1 += w0.y + w1.y;
        l2 += w0.z + w1.z;  l3 += w0.w + w1.w;
    }
    if (i < end) {
        unsigned u0 = e4[i];
        float4 w0 = *(const float4*)&wb[(size_t)i * 4];
        float2 x0 = __half22float2(x2[(u0 >> 15) * 16u + q]);
        a0x += w0.x * x0.x;  a0y += w0.x * x0.y;
        a1x += w0.y * x0.x;  a1y += w0.y * x0.y;
        a2x += w0.z * x0.x;  a2y += w0.z * x0.y;
        a3x += w0.w * x0.x;  a3y += w0.w * x0.y;
        l0 += w0.x; l1 += w0.y; l2 += w0.z; l3 += w0.w;
    }
    float i0v = 1.0f / (l0 + 1e-16f);
    float i1v = 1.0f / (l1 + 1e-16f);
    float i2v = 1.0f / (l2 + 1e-16f);
    float i3v = 1.0f / (l3 + 1e-16f);
    __half* zr = &zbuf[(size_t)n * 128];
    *(__half2*)&zr[      q * 2] = __floats2half2_rn(a0x * i0v, a0y * i0v);
    *(__half2*)&zr[32  + q * 2] = __floats2half2_rn(a1x * i1v, a1y * i1v);
    *(__half2*)&zr[64  + q * 2] = __floats2half2_rn(a2x * i2v, a2y * i2v);
    *(__half2*)&zr[96  + q * 2] = __floats2half2_rn(a3x * i3v, a3y * i3v);
}

// ---------------------------------------------------------------------------
// K8a2 (k_zm, MFMA): hbuf = elu(z @blockdiag(W1) + b1).
// ---------------------------------------------------------------------------
__global__ __launch_bounds__(256) void k_zm(
    const __half* __restrict__ zbuf, const float* __restrict__ W1g,
    const float* __restrict__ b1, __half* __restrict__ hbuf)
{
    __shared__ __half Wt[128 * 40];   // [col c][k], 80B rows (16B aligned)
    int t = threadIdx.x;
    for (int i = t; i < 128 * 8; i += 256) {
        int c = i & 127, k4 = (i >> 7) * 4;
        float w0 = W1g[(k4 + 0) * 128 + c];
        float w1 = W1g[(k4 + 1) * 128 + c];
        float w2 = W1g[(k4 + 2) * 128 + c];
        float w3 = W1g[(k4 + 3) * 128 + c];
        __half2 p0 = __floats2half2_rn(w0, w1);
        __half2 p1 = __floats2half2_rn(w2, w3);
        uint2 pk;
        pk.x = *(unsigned*)&p0;
        pk.y = *(unsigned*)&p1;
        *(uint2*)&Wt[c * 40 + k4] = pk;
    }
    __syncthreads();
    int wv = t >> 6, lane = t & 63;
    int m16 = lane & 15, quad = lane >> 4;
    int n0 = blockIdx.x * 64 + wv * 16;
    half8 bf[4];
    #pragma unroll
    for (int hh = 0; hh < 4; hh++)
        bf[hh] = *(const half8*)&zbuf[(size_t)(n0 + m16) * 128 + hh * 32 + quad * 8];
    f32x4 acc[8];
    #pragma unroll
    for (int ct = 0; ct < 8; ct++) {
        half8 af = *(const half8*)&Wt[(ct * 16 + m16) * 40 + quad * 8];
        acc[ct] = __builtin_amdgcn_mfma_f32_16x16x32_f16(
            af, bf[ct >> 1], (f32x4){0.f, 0.f, 0.f, 0.f}, 0, 0, 0);
    }
    __half* orow = &hbuf[(size_t)(n0 + m16) * 128 + quad * 4];
    #pragma unroll
    for (int ct = 0; ct < 8; ct++) {
        int cb = ct * 16 + quad * 4;
        float4 bb = *(const float4*)&b1[cb];
        float r0 = acc[ct][0] + bb.x;
        float r1 = acc[ct][1] + bb.y;
        float r2 = acc[ct][2] + bb.z;
        float r3 = acc[ct][3] + bb.w;
        r0 = r0 > 0.f ? r0 : __expf(r0) - 1.0f;
        r1 = r1 > 0.f ? r1 : __expf(r1) - 1.0f;
        r2 = r2 > 0.f ? r2 : __expf(r2) - 1.0f;
        r3 = r3 > 0.f ? r3 : __expf(r3) - 1.0f;
        __half2 ha = __floats2half2_rn(r0, r1);
        __half2 hb = __floats2half2_rn(r2, r3);
        uint2 pk;
        pk.x = *(unsigned*)&ha;
        pk.y = *(unsigned*)&hb;
        *(uint2*)&orow[ct * 16] = pk;
    }
}

// ---------------------------------------------------------------------------
// K8b: layer-2 aggregation, 32-lane group per node (2 nodes/wave).
// ---------------------------------------------------------------------------
__global__ __launch_bounds__(256) void k_agg2(
    const int* __restrict__ off, const unsigned* __restrict__ e4,
    const float* __restrict__ wb, const __half* __restrict__ x16,
    const float* __restrict__ bias, __half* __restrict__ hout)
{
    int t = threadIdx.x;
    int wv = t >> 6, lane = t & 63;
    int g = lane >> 5, q = lane & 31;
    int n = N_PRO + blockIdx.x * 8 + wv * 2 + g;  // grid exact: N_WAT/8
    int h = q >> 3;
    int beg = off[n], end = off[n + 1];
    float ax = 0.f, ay = 0.f, az = 0.f, aw = 0.f, ls = 0.f;
    int i = beg;
    for (; i + 1 < end; i += 2) {
        unsigned u0 = e4[i], u1 = e4[i + 1];
        float w0 = wb[(size_t)i * 4 + h];
        float w1 = wb[(size_t)(i + 1) * 4 + h];
        float2 r0 = *(const float2*)&x16[(size_t)(u0 >> 15) * 128 + q * 4];
        float2 r1 = *(const float2*)&x16[(size_t)(u1 >> 15) * 128 + q * 4];
        float2 f00 = __half22float2(*(__half2*)&r0.x);
        float2 f01 = __half22float2(*(__half2*)&r0.y);
        float2 f10 = __half22float2(*(__half2*)&r1.x);
        float2 f11 = __half22float2(*(__half2*)&r1.y);
        ax += w0 * f00.x + w1 * f10.x;
        ay += w0 * f00.y + w1 * f10.y;
        az += w0 * f01.x + w1 * f11.x;
        aw += w0 * f01.y + w1 * f11.y;
        ls += w0 + w1;
    }
    if (i < end) {
        unsigned u0 = e4[i];
        float w0 = wb[(size_t)i * 4 + h];
        float2 r0 = *(const float2*)&x16[(size_t)(u0 >> 15) * 128 + q * 4];
        float2 f00 = __half22float2(*(__half2*)&r0.x);
        float2 f01 = __half22float2(*(__half2*)&r0.y);
        ax += w0 * f00.x; ay += w0 * f00.y;
        az += w0 * f01.x; aw += w0 * f01.y;
        ls += w0;
    }
    float inv = 1.0f / (ls + 1e-16f);
    float4 bb = *(const float4*)&bias[q * 4];
    float o0 = ax * inv + bb.x;
    float o1 = ay * inv + bb.y;
    float o2 = az * inv + bb.z;
    float o3 = aw * inv + bb.w;
    o0 = o0 > 0.f ? o0 : __expf(o0) - 1.0f;
    o1 = o1 > 0.f ? o1 : __expf(o1) - 1.0f;
    o2 = o2 > 0.f ? o2 : __expf(o2) - 1.0f;
    o3 = o3 > 0.f ? o3 : __expf(o3) - 1.0f;
    __half2 ha = __floats2half2_rn(o0, o1);
    __half2 hb = __floats2half2_rn(o2, o3);
    uint2 pk;
    pk.x = *(unsigned*)&ha;
    pk.y = *(unsigned*)&hb;
    *(uint2*)&hout[(size_t)n * 128 + q * 4] = pk;
}

// ---------------------------------------------------------------------------
// K9 (MFMA rewrite): water MLP. Structure cloned from k_xm (proven layout):
// 64 nodes/block (4 waves x 16 rows), Wm1^T staged fp16 in LDS [c*136+d]
// (conflict-free), mfma_f32_16x16x32_f16 over K=128; epilogue does
// bias+ReLU in fp32 regs, then the 128->2 layer-2 as per-lane partial dots
// over its 32 channels + 2 shuffle-reduces (k_xm's logit pattern).
// Old SIMT version: 46.8us, 480K bank conflicts, 25% occupancy.
// ---------------------------------------------------------------------------
__global__ __launch_bounds__(256) void k_mlp(
    const __half* __restrict__ hh, const float* __restrict__ Wm1,
    const float* __restrict__ bm1, const float* __restrict__ Wm2,
    const float* __restrict__ bm2, float* __restrict__ out)
{
    __shared__ __half Wt[128 * 136];
    __shared__ float b1s[128];
    __shared__ float w2s[256];
    int t = threadIdx.x;
    for (int i = t; i < 128 * 32; i += 256) {
        int c = i & 127, d = (i >> 7) * 4;
        float w0 = Wm1[(d + 0) * 128 + c];
        float w1 = Wm1[(d + 1) * 128 + c];
        float w2 = Wm1[(d + 2) * 128 + c];
        float w3 = Wm1[(d + 3) * 128 + c];
        __half2 p0 = __floats2half2_rn(w0, w1);
        __half2 p1 = __floats2half2_rn(w2, w3);
        uint2 pk;
        pk.x = *(unsigned*)&p0;
        pk.y = *(unsigned*)&p1;
        *(uint2*)&Wt[c * 136 + d] = pk;
    }
    if (t < 128) b1s[t] = bm1[t];
    w2s[t] = Wm2[t];                       // 256 floats = [128][2]
    __syncthreads();
    int wv = t >> 6, lane = t & 63;
    int m16 = lane & 15, quad = lane >> 4;
    int n0 = blockIdx.x * 64 + wv * 16;    // water-local node base
    f32x4 acc[8];
    #pragma unroll
    for (int ct = 0; ct < 8; ct++) acc[ct] = (f32x4){0.f, 0.f, 0.f, 0.f};
    #pragma unroll
    for (int ks = 0; ks < 4; ks++) {
        int d0 = ks * 32 + quad * 8;
        half8 bf = *(const half8*)&hh[(size_t)(N_PRO + n0 + m16) * 128 + d0];
        #pragma unroll
        for (int ct = 0; ct < 8; ct++) {
            half8 af = *(const half8*)&Wt[(ct * 16 + m16) * 136 + d0];
            acc[ct] = __builtin_amdgcn_mfma_f32_16x16x32_f16(af, bf, acc[ct], 0, 0, 0);
        }
    }
    float p0 = 0.f, p1 = 0.f;
    #pragma unroll
    for (int ct = 0; ct < 8; ct++) {
        int cb = ct * 16 + quad * 4;
        float4 bb = *(const float4*)&b1s[cb];
        float r0 = fmaxf(acc[ct][0] + bb.x, 0.f);
        float r1 = fmaxf(acc[ct][1] + bb.y, 0.f);
        float r2 = fmaxf(acc[ct][2] + bb.z, 0.f);
        float r3 = fmaxf(acc[ct][3] + bb.w, 0.f);
        p0 += r0 * w2s[(cb + 0) * 2] + r1 * w2s[(cb + 1) * 2]
            + r2 * w2s[(cb + 2) * 2] + r3 * w2s[(cb + 3) * 2];
        p1 += r0 * w2s[(cb + 0) * 2 + 1] + r1 * w2s[(cb + 1) * 2 + 1]
            + r2 * w2s[(cb + 2) * 2 + 1] + r3 * w2s[(cb + 3) * 2 + 1];
    }
    p0 += __shfl_xor(p0, 16, 64);
    p0 += __shfl_xor(p0, 32, 64);
    p1 += __shfl_xor(p1, 16, 64);
    p1 += __shfl_xor(p1, 32, 64);
    if (lane < 16) {
        int wn = n0 + m16;
        *(float2*)&out[(size_t)wn * 2] = make_float2(p0 + bm2[0], p1 + bm2[1]);
    }
}

// ---------------------------------------------------------------------------
extern "C" void kernel_launch(void* const* d_in, const int* in_sizes, int n_in,
                              void* d_out, int out_size, void* d_ws, size_t ws_size,
                              hipStream_t stream)
{
    const float* ppos   = (const float*)d_in[0];
    const float* wpos   = (const float*)d_in[1];
    const float* pfeat  = (const float*)d_in[2];
    const int*   ei     = (const int*)d_in[3];
    const float* gamma  = (const float*)d_in[4];
    const float* Wf     = (const float*)d_in[5];
    const float* bfv    = (const float*)d_in[6];
    const float* We     = (const float*)d_in[7];
    const float* be     = (const float*)d_in[8];
    const float* W1     = (const float*)d_in[9];
    const float* atts1  = (const float*)d_in[10];
    const float* attd1  = (const float*)d_in[11];
    const float* Wedge1 = (const float*)d_in[12];
    const float* atte1  = (const float*)d_in[13];
    const float* b1     = (const float*)d_in[14];
    const float* W2     = (const float*)d_in[15];
    const float* atts2  = (const float*)d_in[16];
    const float* attd2  = (const float*)d_in[17];
    const float* Wedge2 = (const float*)d_in[18];
    const float* atte2  = (const float*)d_in[19];
    const float* b2     = (const float*)d_in[20];
    const float* Wm1    = (const float*)d_in[21];
    const float* bm1    = (const float*)d_in[22];
    const float* Wm2    = (const float*)d_in[23];
    const float* bm2    = (const float*)d_in[24];
    float* out = (float*)d_out;

    char* ws = (char*)d_ws;
    size_t o = 0;
    auto alloc = [&](size_t bytes) -> char* {
        char* p = ws + o;
        o += (bytes + 255) & ~(size_t)255;
        return p;
    };
    __half*   h0      = (__half*)alloc((size_t)NNP * 32 * 2);
    __half*   x16     = (__half*)alloc((size_t)NNP * 128 * 2);   // also zbuf
    __half*   hbuf    = (__half*)alloc((size_t)NNP * 128 * 2);
    float*    asd     = (float*)alloc((size_t)NNP * 8 * 4);
    float*    wb      = (float*)alloc((size_t)NE * 4 * 4);       // exp'd weights
    int*      offp    = (int*)alloc((size_t)(NN + 1) * 4);
    unsigned* e4      = (unsigned*)alloc((size_t)NE * 4);
    int*      gbh     = (int*)alloc(256 * 4);
    int*      gboff   = (int*)alloc(256 * 4);
    int*      gcur    = (int*)alloc(256 * 4);
    float*    smallw  = (float*)alloc(4096);
    float*    lutbuf  = (float*)alloc((size_t)2 * LUTN * 4 * 4);
    // ebuf2 (8 MB) overlays hbuf (25.6 MB): ebuf2 is written by k_scat and
    // last read by k_fine, strictly before hbuf's first write in k_zm.
    uint2*    ebuf2   = (uint2*)hbuf;

    hipMemsetAsync(gbh, 0, 256 * 4, stream);
    k_small<<<1, 256, 0, stream>>>(We, be, Wedge1, atte1, Wedge2, atte2, Wf, bfv,
                                   W1, atts1, attd1, smallw);
    k_lut<<<(2 * LUTN + 255) / 256, 256, 0, stream>>>(smallw, gamma, lutbuf);
    k_h0<<<NH0B, 256, 0, stream>>>(pfeat, Wf, bfv, smallw, h0, asd);
    // CSR build: coarse count -> scan -> bucket scatter -> fine place (+w L1)
    k_bcnt<<<SCATB, 256, 0, stream>>>(ei, gbh);
    k_bscan<<<1, 256, 0, stream>>>(gbh, gboff, gcur, offp);
    k_scat<<<SCATB, 256, 0, stream>>>(ei, ppos, wpos, gcur, ebuf2);
    k_fine<<<NBUCK, 1024, 0, stream>>>(gboff, ebuf2, lutbuf, asd, offp, e4, wb);
    // layer 1: lean aggregation (weights prebuilt by k_fine), MFMA W1
    k_aggz<<<NN / 16, 256, 0, stream>>>(offp, e4, wb, h0, x16);
    k_zm<<<NNP / 64, 256, 0, stream>>>(x16, W1, b1, hbuf);
    // layer 2 (water destinations only)
    k_xm<<<NNP / 64, 256, 0, stream>>>(hbuf, W2, atts2, attd2, x16, asd);
    k_w2<<<N_WAT / 4, 256, 0, stream>>>(offp, e4, lutbuf + (size_t)LUTN * 4, asd, wb);
    k_agg2<<<N_WAT / 8, 256, 0, stream>>>(offp, e4, wb, x16, b2, hbuf);
    // MLP on water nodes (MFMA)
    k_mlp<<<N_WAT / 64, 256, 0, stream>>>(hbuf, Wm1, bm1, Wm2, bm2, out);
}

// Round 5
// 310.473 us; speedup vs baseline: 1.2215x; 1.0478x over previous
//
#include <hip/hip_runtime.h>
#include <hip/hip_fp16.h>
#include <stdint.h>

#define N_PRO 60000
#define N_WAT 40000
#define NN    100000
#define NNP   100032            // padded to a multiple of 64 for tiles
#define NE    1000000
#define IN_DIM 21
#define HID    32
#define HEADS  4
#define HC     128
#define EDGE_K 32
#define LUTN   2048             // distance-LUT bins, bin = dist*256 (range [0,8))
#define NH0B  ((NNP * 32) / 256)       // h0 blocks
#define NBUCK 196                      // coarse buckets of 512 nodes (node>>9)
#define EPT   8                        // edges per thread in bcnt/scat
#define SCATB ((NE / EPT + 255) / 256) // 489 blocks
#define FCAP  6144                     // per-bucket LDS staging capacity (edges)

typedef _Float16 half8 __attribute__((ext_vector_type(8)));
typedef float    f32x4 __attribute__((ext_vector_type(4)));

// ---------------------------------------------------------------------------
// K1: tiny fused weights (ONE block). smallw floats: [0..127]=U1,
// [128..131]=aeb1, [132..259]=U2, [260..263]=aeb2, [264..295]=h0w,
// [296..423]=va_s1, [424..551]=va_d1
// ---------------------------------------------------------------------------
__global__ __launch_bounds__(256) void k_small(
    const float* We, const float* be,
    const float* Wedge1, const float* atte1,
    const float* Wedge2, const float* atte2,
    const float* Wf, const float* bfv,
    const float* W1, const float* atts1, const float* attd1,
    float* smallw)
{
    __shared__ float V[2][128];
    int t = threadIdx.x;
    {
        int l = t >> 7, dh = t & 127, d = dh >> 2, h = dh & 3;
        const float* Wg = l ? Wedge2 : Wedge1;
        const float* ae = l ? atte2 : atte1;
        float s = 0.f;
        for (int c = 0; c < HID; c++)
            s += Wg[d * HC + h * HID + c] * ae[h * HID + c];
        V[l][dh] = s;
    }
    __syncthreads();
    {
        int l = t >> 7, kh = t & 127, k = kh >> 2, h = kh & 3;
        float s = 0.f;
        for (int d = 0; d < 32; d++)
            s += We[k * 32 + d] * V[l][d * 4 + h];
        smallw[(l ? 132 : 0) + kh] = s;
    }
    if (t < 8) {
        int l = t >> 2, h = t & 3;
        float s = 0.f;
        for (int d = 0; d < 32; d++)
            s += be[d] * V[l][d * 4 + h];
        smallw[(l ? 260 : 128) + h] = s;
    }
    if (t >= 32 && t < 64) {
        int c = t - 32;
        smallw[264 + c] = Wf[20 * 32 + c] + bfv[c];
    }
    {
        int side = t >> 7;
        int h = (t >> 5) & 3, c = t & 31;
        const float* av = side ? attd1 : atts1;
        float s = 0.f;
        for (int j = 0; j < 32; j++)
            s += W1[c * 128 + h * 32 + j] * av[h * 32 + j];
        smallw[(side ? 424 : 296) + (t & 127)] = s;
    }
}

// ---------------------------------------------------------------------------
// K1b: distance LUT. bin b corresponds to dist = b/256.
// ---------------------------------------------------------------------------
__global__ __launch_bounds__(256) void k_lut(
    const float* __restrict__ smallw, const float* __restrict__ gamma,
    float* __restrict__ lut)
{
    int e = blockIdx.x * 256 + threadIdx.x;
    if (e >= 2 * LUTN) return;
    int layer = e >> 11, bin = e & (LUTN - 1);
    const float* U = smallw + (layer ? 132 : 0);
    const float* aeb = smallw + (layer ? 260 : 128);
    float dd = bin * (1.0f / 256.0f);
    float g = gamma[0];
    float a0 = aeb[0], a1 = aeb[1], a2 = aeb[2], a3 = aeb[3];
    const float step = 5.0f / 31.0f;
    #pragma unroll
    for (int k = 0; k < EDGE_K; k++) {
        float tt = dd - (float)k * step;
        float r = __expf(-g * tt * tt);
        a0 += r * U[k * 4 + 0];
        a1 += r * U[k * 4 + 1];
        a2 += r * U[k * 4 + 2];
        a3 += r * U[k * 4 + 3];
    }
    *(float4*)&lut[(size_t)e * 4] = make_float4(a0, a1, a2, a3);
}

// ---------------------------------------------------------------------------
// K2: h0 = feats@Wf+bf (fp16) + layer-1 logits asd. Blocks >= NH0B run the
// coarse-bucket degree histogram (LDS, 196 global atomics/block) — re-fused
// to drop one kernel launch and overlap count with h0 compute.
// ---------------------------------------------------------------------------
__global__ __launch_bounds__(256) void k_h0(
    const float* __restrict__ pf, const float* __restrict__ Wf,
    const float* __restrict__ bfv, const float* __restrict__ smallw,
    const int* __restrict__ ei, int* __restrict__ gbh,
    __half* __restrict__ h0, float* __restrict__ asd)
{
    int t = threadIdx.x;
    if (blockIdx.x >= NH0B) {
        __shared__ int lh[256];
        lh[t] = 0;
        __syncthreads();
        int e0 = ((blockIdx.x - NH0B) * 256 + t) * EPT;
        if (e0 < NE) {                   // NE % EPT == 0 -> full vector ok
            int4 da = *(const int4*)&ei[NE + e0];
            int4 db = *(const int4*)&ei[NE + e0 + 4];
            int ds[8] = {da.x, da.y, da.z, da.w, db.x, db.y, db.z, db.w};
            #pragma unroll
            for (int j = 0; j < EPT; j++)
                if ((unsigned)ds[j] < (unsigned)NN)
                    atomicAdd(&lh[ds[j] >> 9], 1);
        }
        __syncthreads();
        if (t < NBUCK && lh[t]) atomicAdd(&gbh[t], lh[t]);
        return;
    }
    __shared__ float Wfs[IN_DIM * 32];
    __shared__ float bfs[32];
    __shared__ float h0w[32];
    __shared__ float vas[128], vad[128];
    for (int i = t; i < IN_DIM * 32; i += 256) Wfs[i] = Wf[i];
    if (t < 32) { bfs[t] = bfv[t]; h0w[t] = smallw[264 + t]; }
    if (t < 128) vas[t] = smallw[296 + t];
    else         vad[t - 128] = smallw[424 + (t - 128)];
    __syncthreads();
    int id = blockIdx.x * 256 + t;
    int n = id >> 5, c = id & 31;
    if (n >= NNP) return;
    float v;
    if (n < N_PRO) {
        float s = bfs[c];
        for (int k = 0; k < IN_DIM; k++)
            s += pf[n * IN_DIM + k] * Wfs[k * 32 + c];
        v = s;
    } else {
        v = h0w[c];
    }
    h0[(size_t)n * 32 + c] = __float2half(v);
    float ps[4], pd[4];
    #pragma unroll
    for (int h = 0; h < 4; h++) {
        ps[h] = v * vas[h * 32 + c];
        pd[h] = v * vad[h * 32 + c];
    }
    #pragma unroll
    for (int m = 1; m < 32; m <<= 1) {
        #pragma unroll
        for (int h = 0; h < 4; h++) {
            ps[h] += __shfl_xor(ps[h], m, 64);
            pd[h] += __shfl_xor(pd[h], m, 64);
        }
    }
    if ((t & 31) == 0) {
        *(float4*)&asd[(size_t)n * 8]     = make_float4(ps[0], ps[1], ps[2], ps[3]);
        *(float4*)&asd[(size_t)n * 8 + 4] = make_float4(pd[0], pd[1], pd[2], pd[3]);
    }
}

// scan 196 bucket counts -> global bucket offsets + cursors; off[NN]=total.
__global__ __launch_bounds__(256) void k_bscan(
    const int* __restrict__ gbh, int* __restrict__ gboff,
    int* __restrict__ gcur, int* __restrict__ offp)
{
    __shared__ int s[256];
    int t = threadIdx.x;
    int v = (t < NBUCK) ? gbh[t] : 0;
    s[t] = v;
    __syncthreads();
    #pragma unroll
    for (int o = 1; o < 256; o <<= 1) {
        int x = (t >= o) ? s[t - o] : 0;
        __syncthreads();
        s[t] += x;
        __syncthreads();
    }
    int ex = s[t] - v;
    if (t < NBUCK) { gboff[t] = ex; gcur[t] = ex; }
    if (t == NBUCK - 1) { gboff[NBUCK] = s[t]; offp[NN] = s[t]; }
}

// k_scat: rank edges within (block,bucket) via LDS atomics; one global
// atomic per (block,bucket) for the base; write (dst|code, src) records.
__global__ __launch_bounds__(256) void k_scat(
    const int* __restrict__ ei, const float* __restrict__ ppos,
    const float* __restrict__ wpos, int* __restrict__ gcur,
    uint2* __restrict__ ebuf2)
{
    __shared__ int lh[256];
    __shared__ int lbase[256];
    int t = threadIdx.x;
    lh[t] = 0;
    __syncthreads();
    int e0 = (blockIdx.x * 256 + t) * EPT;
    int bkt[EPT], rnk[EPT];
    unsigned rec0[EPT], rec1[EPT];
    #pragma unroll
    for (int j = 0; j < EPT; j++) bkt[j] = -1;
    if (e0 < NE) {
        int4 sa = *(const int4*)&ei[e0];
        int4 sb = *(const int4*)&ei[e0 + 4];
        int4 da = *(const int4*)&ei[NE + e0];
        int4 db = *(const int4*)&ei[NE + e0 + 4];
        int ss[8] = {sa.x, sa.y, sa.z, sa.w, sb.x, sb.y, sb.z, sb.w};
        int ds[8] = {da.x, da.y, da.z, da.w, db.x, db.y, db.z, db.w};
        #pragma unroll
        for (int j = 0; j < EPT; j++) {
            int s = ss[j], d = ds[j];
            if ((unsigned)d < (unsigned)NN) {
                const float* ps = (s < N_PRO) ? &ppos[s * 3] : &wpos[(s - N_PRO) * 3];
                const float* pd = (d < N_PRO) ? &ppos[d * 3] : &wpos[(d - N_PRO) * 3];
                float dx = pd[0] - ps[0];
                float dy = pd[1] - ps[1];
                float dz = pd[2] - ps[2];
                float dist = sqrtf(dx * dx + dy * dy + dz * dz);
                unsigned code = (unsigned)fminf(dist * 4096.0f, 32767.0f);
                bkt[j] = d >> 9;
                rec0[j] = ((unsigned)d << 15) | code;
                rec1[j] = (unsigned)s;
                rnk[j] = atomicAdd(&lh[bkt[j]], 1);
            }
        }
    }
    __syncthreads();
    if (t < NBUCK) lbase[t] = lh[t] ? atomicAdd(&gcur[t], lh[t]) : 0;
    __syncthreads();
    #pragma unroll
    for (int j = 0; j < EPT; j++)
        if (bkt[j] >= 0)
            ebuf2[lbase[bkt[j]] + rnk[j]] = make_uint2(rec0[j], rec1[j]);
}

// k_fine: one block per bucket, 1024 threads. LDS staging, fine-count of the
// 512 local nodes, then a WAVE-SHUFFLE scan (3 barriers vs 18 — with 16
// waves/block and ~2 blocks/CU barriers were the serial cost), GLOBAL off[]
// direct, then place each edge: e4 + fully-exp'd layer-1 weight wb[slot][4].
__global__ __launch_bounds__(1024) void k_fine(
    const int* __restrict__ gboff, const uint2* __restrict__ ebuf2,
    const float* __restrict__ lutg, const float* __restrict__ asd,
    int* __restrict__ offp, unsigned* __restrict__ e4,
    float* __restrict__ wb)
{
    __shared__ uint2 eL[FCAP];          // 48 KB
    __shared__ int lcnt[512], lexc[512];
    __shared__ int wsum[8];
    int b = blockIdx.x, t = threadIdx.x;
    int beg = gboff[b];
    int nb = gboff[b + 1] - beg;
    bool inl = (nb <= FCAP);
    if (inl)
        for (int i = t; i < nb; i += 1024) eL[i] = ebuf2[beg + i];
    if (t < 512) lcnt[t] = 0;
    __syncthreads();
    for (int i = t; i < nb; i += 1024) {
        uint2 u = inl ? eL[i] : ebuf2[beg + i];
        atomicAdd(&lcnt[(u.x >> 15) & 511], 1);
    }
    __syncthreads();
    if (t < 512) {                       // waves 0..7 fully active
        int c = lcnt[t];
        int lane = t & 63;
        int v = c;
        #pragma unroll
        for (int d = 1; d < 64; d <<= 1) {
            int x = __shfl_up(v, d, 64);
            if (lane >= d) v += x;
        }
        if (lane == 63) wsum[t >> 6] = v;
        lexc[t] = v - c;                 // wave-local exclusive prefix
    }
    __syncthreads();
    if (t < 8) {                         // exclusive scan of 8 wave sums
        int orig = wsum[t];
        int v = orig;
        #pragma unroll
        for (int d = 1; d < 8; d <<= 1) {
            int x = __shfl_up(v, d, 64);
            if (t >= d) v += x;
        }
        wsum[t] = v - orig;
    }
    __syncthreads();
    if (t < 512) {
        lexc[t] += wsum[t >> 6];
        int node = b * 512 + t;
        if (node < NN) offp[node] = beg + lexc[t];
        lcnt[t] = 0;                     // reuse as per-node cursor
    }
    __syncthreads();
    for (int i = t; i < nb; i += 1024) {
        uint2 u = inl ? eL[i] : ebuf2[beg + i];
        int ln = (int)((u.x >> 15) & 511u);
        int r = atomicAdd(&lcnt[ln], 1);
        int p = beg + lexc[ln] + r;
        unsigned code = u.x & 32767u;
        unsigned s = u.y;
        e4[p] = (s << 15) | code;
        int n = (b << 9) + ln;
        float f = fminf((float)code * 0.0625f, (float)(LUTN - 2));
        int i0 = (int)f;
        float fr = f - (float)i0;
        float4 A = *(const float4*)&lutg[(size_t)i0 * 4];
        float4 B = *(const float4*)&lutg[(size_t)(i0 + 1) * 4];
        float4 as4 = *(const float4*)&asd[(size_t)s * 8];
        float4 ad4 = *(const float4*)&asd[(size_t)n * 8 + 4];
        float v0 = as4.x + ad4.x + A.x + (B.x - A.x) * fr;
        float v1 = as4.y + ad4.y + A.y + (B.y - A.y) * fr;
        float v2 = as4.z + ad4.z + A.z + (B.z - A.z) * fr;
        float v3 = as4.w + ad4.w + A.w + (B.w - A.w) * fr;
        v0 = fmaxf(v0, 0.2f * v0);
        v1 = fmaxf(v1, 0.2f * v1);
        v2 = fmaxf(v2, 0.2f * v2);
        v3 = fmaxf(v3, 0.2f * v3);
        *(float4*)&wb[(size_t)p * 4] = make_float4(
            __expf(v0), __expf(v1), __expf(v2), __expf(v3));
    }
}

// ---------------------------------------------------------------------------
// K6 (MFMA): x = hbuf @ W2 (+ logits) via mfma_f32_16x16x32_f16.
// ---------------------------------------------------------------------------
__global__ __launch_bounds__(256) void k_xm(
    const __half* __restrict__ h, const float* __restrict__ Wg,
    const float* __restrict__ atts, const float* __restrict__ attd,
    __half* __restrict__ x16, float* __restrict__ asd)
{
    __shared__ __half Wt[128 * 136];
    __shared__ float attS[128], attD[128];
    int t = threadIdx.x;
    for (int i = t; i < 128 * 32; i += 256) {
        int c = i & 127, d = (i >> 7) * 4;
        float w0 = Wg[(d + 0) * 128 + c];
        float w1 = Wg[(d + 1) * 128 + c];
        float w2 = Wg[(d + 2) * 128 + c];
        float w3 = Wg[(d + 3) * 128 + c];
        __half2 p0 = __floats2half2_rn(w0, w1);
        __half2 p1 = __floats2half2_rn(w2, w3);
        uint2 pk;
        pk.x = *(unsigned*)&p0;
        pk.y = *(unsigned*)&p1;
        *(uint2*)&Wt[c * 136 + d] = pk;
    }
    if (t < 128) { attS[t] = atts[t]; attD[t] = attd[t]; }
    __syncthreads();
    int wv = t >> 6, lane = t & 63;
    int m16 = lane & 15, quad = lane >> 4;
    int n0 = blockIdx.x * 64 + wv * 16;
    f32x4 acc[8];
    #pragma unroll
    for (int ct = 0; ct < 8; ct++) acc[ct] = (f32x4){0.f, 0.f, 0.f, 0.f};
    #pragma unroll
    for (int ks = 0; ks < 4; ks++) {
        int d0 = ks * 32 + quad * 8;
        half8 bf = *(const half8*)&h[(size_t)(n0 + m16) * 128 + d0];
        #pragma unroll
        for (int ct = 0; ct < 8; ct++) {
            half8 af = *(const half8*)&Wt[(ct * 16 + m16) * 136 + d0];
            acc[ct] = __builtin_amdgcn_mfma_f32_16x16x32_f16(af, bf, acc[ct], 0, 0, 0);
        }
    }
    __half* xrow = &x16[(size_t)(n0 + m16) * 128 + quad * 4];
    float ps[4] = {0.f, 0.f, 0.f, 0.f}, pd[4] = {0.f, 0.f, 0.f, 0.f};
    #pragma unroll
    for (int ct = 0; ct < 8; ct++) {
        f32x4 a = acc[ct];
        __half2 h0p = __floats2half2_rn(a[0], a[1]);
        __half2 h1p = __floats2half2_rn(a[2], a[3]);
        uint2 pk;
        pk.x = *(unsigned*)&h0p;
        pk.y = *(unsigned*)&h1p;
        *(uint2*)&xrow[ct * 16] = pk;
        int cb = ct * 16 + quad * 4;
        int hh = ct >> 1;
        ps[hh] += a[0] * attS[cb] + a[1] * attS[cb + 1]
                + a[2] * attS[cb + 2] + a[3] * attS[cb + 3];
        pd[hh] += a[0] * attD[cb] + a[1] * attD[cb + 1]
                + a[2] * attD[cb + 2] + a[3] * attD[cb + 3];
    }
    #pragma unroll
    for (int hh = 0; hh < 4; hh++) {
        ps[hh] += __shfl_xor(ps[hh], 16, 64);
        ps[hh] += __shfl_xor(ps[hh], 32, 64);
        pd[hh] += __shfl_xor(pd[hh], 16, 64);
        pd[hh] += __shfl_xor(pd[hh], 32, 64);
    }
    if (lane < 16) {
        int n = n0 + m16;
        *(float4*)&asd[(size_t)n * 8]     = make_float4(ps[0], ps[1], ps[2], ps[3]);
        *(float4*)&asd[(size_t)n * 8 + 4] = make_float4(pd[0], pd[1], pd[2], pd[3]);
    }
}

// ---------------------------------------------------------------------------
// K8a: layer-1 aggregation, 16-lane group per node (4 nodes/wave), unroll 4
// for deeper memory-level parallelism (was latency-bound at unroll 2).
// ---------------------------------------------------------------------------
__global__ __launch_bounds__(256) void k_aggz(
    const int* __restrict__ off, const unsigned* __restrict__ e4,
    const float* __restrict__ wb, const __half* __restrict__ h016,
    __half* __restrict__ zbuf)
{
    int t = threadIdx.x;
    int wv = t >> 6, lane = t & 63;
    int g = lane >> 4, q = lane & 15;
    int n = blockIdx.x * 16 + wv * 4 + g;        // grid exact: NN/16
    int beg = off[n], end = off[n + 1];
    const __half2* x2 = (const __half2*)h016;
    float a0x = 0.f, a0y = 0.f, a1x = 0.f, a1y = 0.f;
    float a2x = 0.f, a2y = 0.f, a3x = 0.f, a3y = 0.f;
    float l0 = 0.f, l1 = 0.f, l2 = 0.f, l3 = 0.f;
    int i = beg;
    for (; i + 3 < end; i += 4) {
        unsigned u0 = e4[i],     u1 = e4[i + 1];
        unsigned u2 = e4[i + 2], u3 = e4[i + 3];
        float4 w0 = *(const float4*)&wb[(size_t)i * 4];
        float4 w1 = *(const float4*)&wb[(size_t)(i + 1) * 4];
        float4 w2 = *(const float4*)&wb[(size_t)(i + 2) * 4];
        float4 w3 = *(const float4*)&wb[(size_t)(i + 3) * 4];
        float2 x0 = __half22float2(x2[(u0 >> 15) * 16u + q]);
        float2 x1 = __half22float2(x2[(u1 >> 15) * 16u + q]);
        float2 x2v = __half22float2(x2[(u2 >> 15) * 16u + q]);
        float2 x3 = __half22float2(x2[(u3 >> 15) * 16u + q]);
        a0x += w0.x * x0.x + w1.x * x1.x + w2.x * x2v.x + w3.x * x3.x;
        a0y += w0.x * x0.y + w1.x * x1.y + w2.x * x2v.y + w3.x * x3.y;
        a1x += w0.y * x0.x + w1.y * x1.x + w2.y * x2v.x + w3.y * x3.x;
        a1y += w0.y * x0.y + w1.y * x1.y + w2.y * x2v.y + w3.y * x3.y;
        a2x += w0.z * x0.x + w1.z * x1.x + w2.z * x2v.x + w3.z * x3.x;
        a2y += w0.z * x0.y + w1.z * x1.y + w2.z * x2v.y + w3.z * x3.y;
        a3x += w0.w * x0.x + w1.w * x1.x + w2.w * x2v.x + w3.w * x3.x;
        a3y += w0.w * x0.y + w1.w * x1.y + w2.w * x2v.y + w3.w * x3.y;
        l0 += (w0.x + w1.x) + (w2.x + w3.x);
        l1 += (w0.y + w1.y) + (w2.y + w3.y);
        l2 += (w0.z + w1.z) + (w2.z + w3.z);
        l3 += (w0.w + w1.w) + (w2.w + w3.w);
    }
    for (; i < end; i++) {
        unsigned u0 = e4[i];
        float4 w0 = *(const float4*)&wb[(size_t)i * 4];
        float2 x0 = __half22float2(x2[(u0 >> 15) * 16u + q]);
        a0x += w0.x * x0.x;  a0y += w0.x * x0.y;
        a1x += w0.y * x0.x;  a1y += w0.y * x0.y;
        a2x += w0.z * x0.x;  a2y += w0.z * x0.y;
        a3x += w0.w * x0.x;  a3y += w0.w * x0.y;
        l0 += w0.x; l1 += w0.y; l2 += w0.z; l3 += w0.w;
    }
    float i0v = 1.0f / (l0 + 1e-16f);
    float i1v = 1.0f / (l1 + 1e-16f);
    float i2v = 1.0f / (l2 + 1e-16f);
    float i3v = 1.0f / (l3 + 1e-16f);
    __half* zr = &zbuf[(size_t)n * 128];
    *(__half2*)&zr[      q * 2] = __floats2half2_rn(a0x * i0v, a0y * i0v);
    *(__half2*)&zr[32  + q * 2] = __floats2half2_rn(a1x * i1v, a1y * i1v);
    *(__half2*)&zr[64  + q * 2] = __floats2half2_rn(a2x * i2v, a2y * i2v);
    *(__half2*)&zr[96  + q * 2] = __floats2half2_rn(a3x * i3v, a3y * i3v);
}

// ---------------------------------------------------------------------------
// K8a2 (k_zm, MFMA): hbuf = elu(z @blockdiag(W1) + b1).
// ---------------------------------------------------------------------------
__global__ __launch_bounds__(256) void k_zm(
    const __half* __restrict__ zbuf, const float* __restrict__ W1g,
    const float* __restrict__ b1, __half* __restrict__ hbuf)
{
    __shared__ __half Wt[128 * 40];   // [col c][k], 80B rows (16B aligned)
    int t = threadIdx.x;
    for (int i = t; i < 128 * 8; i += 256) {
        int c = i & 127, k4 = (i >> 7) * 4;
        float w0 = W1g[(k4 + 0) * 128 + c];
        float w1 = W1g[(k4 + 1) * 128 + c];
        float w2 = W1g[(k4 + 2) * 128 + c];
        float w3 = W1g[(k4 + 3) * 128 + c];
        __half2 p0 = __floats2half2_rn(w0, w1);
        __half2 p1 = __floats2half2_rn(w2, w3);
        uint2 pk;
        pk.x = *(unsigned*)&p0;
        pk.y = *(unsigned*)&p1;
        *(uint2*)&Wt[c * 40 + k4] = pk;
    }
    __syncthreads();
    int wv = t >> 6, lane = t & 63;
    int m16 = lane & 15, quad = lane >> 4;
    int n0 = blockIdx.x * 64 + wv * 16;
    half8 bf[4];
    #pragma unroll
    for (int hh = 0; hh < 4; hh++)
        bf[hh] = *(const half8*)&zbuf[(size_t)(n0 + m16) * 128 + hh * 32 + quad * 8];
    f32x4 acc[8];
    #pragma unroll
    for (int ct = 0; ct < 8; ct++) {
        half8 af = *(const half8*)&Wt[(ct * 16 + m16) * 40 + quad * 8];
        acc[ct] = __builtin_amdgcn_mfma_f32_16x16x32_f16(
            af, bf[ct >> 1], (f32x4){0.f, 0.f, 0.f, 0.f}, 0, 0, 0);
    }
    __half* orow = &hbuf[(size_t)(n0 + m16) * 128 + quad * 4];
    #pragma unroll
    for (int ct = 0; ct < 8; ct++) {
        int cb = ct * 16 + quad * 4;
        float4 bb = *(const float4*)&b1[cb];
        float r0 = acc[ct][0] + bb.x;
        float r1 = acc[ct][1] + bb.y;
        float r2 = acc[ct][2] + bb.z;
        float r3 = acc[ct][3] + bb.w;
        r0 = r0 > 0.f ? r0 : __expf(r0) - 1.0f;
        r1 = r1 > 0.f ? r1 : __expf(r1) - 1.0f;
        r2 = r2 > 0.f ? r2 : __expf(r2) - 1.0f;
        r3 = r3 > 0.f ? r3 : __expf(r3) - 1.0f;
        __half2 ha = __floats2half2_rn(r0, r1);
        __half2 hb = __floats2half2_rn(r2, r3);
        uint2 pk;
        pk.x = *(unsigned*)&ha;
        pk.y = *(unsigned*)&hb;
        *(uint2*)&orow[ct * 16] = pk;
    }
}

// ---------------------------------------------------------------------------
// K8b: layer-2 aggregation with INLINE weight computation (k_w2 deleted).
// 32-lane group per node; head h=q>>3; weight = exp(leaky(as+ae+ad)) computed
// head-redundantly (8x) — ~1us extra TRANS total, saves a full kernel pass
// and the wb round-trip for layer 2.
// ---------------------------------------------------------------------------
__global__ __launch_bounds__(256) void k_agg2(
    const int* __restrict__ off, const unsigned* __restrict__ e4,
    const float* __restrict__ lutg, const float* __restrict__ asd,
    const __half* __restrict__ x16, const float* __restrict__ bias,
    __half* __restrict__ hout)
{
    int t = threadIdx.x;
    int wv = t >> 6, lane = t & 63;
    int g = lane >> 5, q = lane & 31;
    int n = N_PRO + blockIdx.x * 8 + wv * 2 + g;  // grid exact: N_WAT/8
    int h = q >> 3;
    int beg = off[n], end = off[n + 1];
    float adh = asd[(size_t)n * 8 + 4 + h];
    float ax = 0.f, ay = 0.f, az = 0.f, aw = 0.f, ls = 0.f;
    int i = beg;
    for (; i + 1 < end; i += 2) {
        unsigned u0 = e4[i], u1 = e4[i + 1];
        unsigned s0 = u0 >> 15, s1 = u1 >> 15;
        float f0 = fminf((float)(u0 & 32767u) * 0.0625f, (float)(LUTN - 2));
        float f1 = fminf((float)(u1 & 32767u) * 0.0625f, (float)(LUTN - 2));
        int i00 = (int)f0, i10 = (int)f1;
        float fr0 = f0 - (float)i00, fr1 = f1 - (float)i10;
        float A0 = lutg[i00 * 4 + h], B0 = lutg[(i00 + 1) * 4 + h];
        float A1 = lutg[i10 * 4 + h], B1 = lutg[(i10 + 1) * 4 + h];
        float as0 = asd[(size_t)s0 * 8 + h], as1 = asd[(size_t)s1 * 8 + h];
        float2 r0 = *(const float2*)&x16[(size_t)s0 * 128 + q * 4];
        float2 r1 = *(const float2*)&x16[(size_t)s1 * 128 + q * 4];
        float v0 = as0 + adh + A0 + (B0 - A0) * fr0;
        float v1 = as1 + adh + A1 + (B1 - A1) * fr1;
        v0 = fmaxf(v0, 0.2f * v0);
        v1 = fmaxf(v1, 0.2f * v1);
        float w0 = __expf(v0), w1 = __expf(v1);
        float2 f00 = __half22float2(*(__half2*)&r0.x);
        float2 f01 = __half22float2(*(__half2*)&r0.y);
        float2 f10 = __half22float2(*(__half2*)&r1.x);
        float2 f11 = __half22float2(*(__half2*)&r1.y);
        ax += w0 * f00.x + w1 * f10.x;
        ay += w0 * f00.y + w1 * f10.y;
        az += w0 * f01.x + w1 * f11.x;
        aw += w0 * f01.y + w1 * f11.y;
        ls += w0 + w1;
    }
    if (i < end) {
        unsigned u0 = e4[i];
        unsigned s0 = u0 >> 15;
        float f0 = fminf((float)(u0 & 32767u) * 0.0625f, (float)(LUTN - 2));
        int i00 = (int)f0;
        float fr0 = f0 - (float)i00;
        float A0 = lutg[i00 * 4 + h], B0 = lutg[(i00 + 1) * 4 + h];
        float as0 = asd[(size_t)s0 * 8 + h];
        float2 r0 = *(const float2*)&x16[(size_t)s0 * 128 + q * 4];
        float v0 = as0 + adh + A0 + (B0 - A0) * fr0;
        v0 = fmaxf(v0, 0.2f * v0);
        float w0 = __expf(v0);
        float2 f00 = __half22float2(*(__half2*)&r0.x);
        float2 f01 = __half22float2(*(__half2*)&r0.y);
        ax += w0 * f00.x; ay += w0 * f00.y;
        az += w0 * f01.x; aw += w0 * f01.y;
        ls += w0;
    }
    float inv = 1.0f / (ls + 1e-16f);
    float4 bb = *(const float4*)&bias[q * 4];
    float o0 = ax * inv + bb.x;
    float o1 = ay * inv + bb.y;
    float o2 = az * inv + bb.z;
    float o3 = aw * inv + bb.w;
    o0 = o0 > 0.f ? o0 : __expf(o0) - 1.0f;
    o1 = o1 > 0.f ? o1 : __expf(o1) - 1.0f;
    o2 = o2 > 0.f ? o2 : __expf(o2) - 1.0f;
    o3 = o3 > 0.f ? o3 : __expf(o3) - 1.0f;
    __half2 ha = __floats2half2_rn(o0, o1);
    __half2 hb = __floats2half2_rn(o2, o3);
    uint2 pk;
    pk.x = *(unsigned*)&ha;
    pk.y = *(unsigned*)&hb;
    *(uint2*)&hout[(size_t)n * 128 + q * 4] = pk;
}

// ---------------------------------------------------------------------------
// K9 (MFMA): water MLP, k_xm-structure. 64 nodes/block, Wm1^T fp16 in LDS,
// epilogue bias+ReLU then 128->2 layer-2 via per-lane dots + shuffle-reduce.
// ---------------------------------------------------------------------------
__global__ __launch_bounds__(256) void k_mlp(
    const __half* __restrict__ hh, const float* __restrict__ Wm1,
    const float* __restrict__ bm1, const float* __restrict__ Wm2,
    const float* __restrict__ bm2, float* __restrict__ out)
{
    __shared__ __half Wt[128 * 136];
    __shared__ float b1s[128];
    __shared__ float w2s[256];
    int t = threadIdx.x;
    for (int i = t; i < 128 * 32; i += 256) {
        int c = i & 127, d = (i >> 7) * 4;
        float w0 = Wm1[(d + 0) * 128 + c];
        float w1 = Wm1[(d + 1) * 128 + c];
        float w2 = Wm1[(d + 2) * 128 + c];
        float w3 = Wm1[(d + 3) * 128 + c];
        __half2 p0 = __floats2half2_rn(w0, w1);
        __half2 p1 = __floats2half2_rn(w2, w3);
        uint2 pk;
        pk.x = *(unsigned*)&p0;
        pk.y = *(unsigned*)&p1;
        *(uint2*)&Wt[c * 136 + d] = pk;
    }
    if (t < 128) b1s[t] = bm1[t];
    w2s[t] = Wm2[t];                       // 256 floats = [128][2]
    __syncthreads();
    int wv = t >> 6, lane = t & 63;
    int m16 = lane & 15, quad = lane >> 4;
    int n0 = blockIdx.x * 64 + wv * 16;    // water-local node base
    f32x4 acc[8];
    #pragma unroll
    for (int ct = 0; ct < 8; ct++) acc[ct] = (f32x4){0.f, 0.f, 0.f, 0.f};
    #pragma unroll
    for (int ks = 0; ks < 4; ks++) {
        int d0 = ks * 32 + quad * 8;
        half8 bf = *(const half8*)&hh[(size_t)(N_PRO + n0 + m16) * 128 + d0];
        #pragma unroll
        for (int ct = 0; ct < 8; ct++) {
            half8 af = *(const half8*)&Wt[(ct * 16 + m16) * 136 + d0];
            acc[ct] = __builtin_amdgcn_mfma_f32_16x16x32_f16(af, bf, acc[ct], 0, 0, 0);
        }
    }
    float p0 = 0.f, p1 = 0.f;
    #pragma unroll
    for (int ct = 0; ct < 8; ct++) {
        int cb = ct * 16 + quad * 4;
        float4 bb = *(const float4*)&b1s[cb];
        float r0 = fmaxf(acc[ct][0] + bb.x, 0.f);
        float r1 = fmaxf(acc[ct][1] + bb.y, 0.f);
        float r2 = fmaxf(acc[ct][2] + bb.z, 0.f);
        float r3 = fmaxf(acc[ct][3] + bb.w, 0.f);
        p0 += r0 * w2s[(cb + 0) * 2] + r1 * w2s[(cb + 1) * 2]
            + r2 * w2s[(cb + 2) * 2] + r3 * w2s[(cb + 3) * 2];
        p1 += r0 * w2s[(cb + 0) * 2 + 1] + r1 * w2s[(cb + 1) * 2 + 1]
            + r2 * w2s[(cb + 2) * 2 + 1] + r3 * w2s[(cb + 3) * 2 + 1];
    }
    p0 += __shfl_xor(p0, 16, 64);
    p0 += __shfl_xor(p0, 32, 64);
    p1 += __shfl_xor(p1, 16, 64);
    p1 += __shfl_xor(p1, 32, 64);
    if (lane < 16) {
        int wn = n0 + m16;
        *(float2*)&out[(size_t)wn * 2] = make_float2(p0 + bm2[0], p1 + bm2[1]);
    }
}

// ---------------------------------------------------------------------------
extern "C" void kernel_launch(void* const* d_in, const int* in_sizes, int n_in,
                              void* d_out, int out_size, void* d_ws, size_t ws_size,
                              hipStream_t stream)
{
    const float* ppos   = (const float*)d_in[0];
    const float* wpos   = (const float*)d_in[1];
    const float* pfeat  = (const float*)d_in[2];
    const int*   ei     = (const int*)d_in[3];
    const float* gamma  = (const float*)d_in[4];
    const float* Wf     = (const float*)d_in[5];
    const float* bfv    = (const float*)d_in[6];
    const float* We     = (const float*)d_in[7];
    const float* be     = (const float*)d_in[8];
    const float* W1     = (const float*)d_in[9];
    const float* atts1  = (const float*)d_in[10];
    const float* attd1  = (const float*)d_in[11];
    const float* Wedge1 = (const float*)d_in[12];
    const float* atte1  = (const float*)d_in[13];
    const float* b1     = (const float*)d_in[14];
    const float* W2     = (const float*)d_in[15];
    const float* atts2  = (const float*)d_in[16];
    const float* attd2  = (const float*)d_in[17];
    const float* Wedge2 = (const float*)d_in[18];
    const float* atte2  = (const float*)d_in[19];
    const float* b2     = (const float*)d_in[20];
    const float* Wm1    = (const float*)d_in[21];
    const float* bm1    = (const float*)d_in[22];
    const float* Wm2    = (const float*)d_in[23];
    const float* bm2    = (const float*)d_in[24];
    float* out = (float*)d_out;

    char* ws = (char*)d_ws;
    size_t o = 0;
    auto alloc = [&](size_t bytes) -> char* {
        char* p = ws + o;
        o += (bytes + 255) & ~(size_t)255;
        return p;
    };
    __half*   h0      = (__half*)alloc((size_t)NNP * 32 * 2);
    __half*   x16     = (__half*)alloc((size_t)NNP * 128 * 2);   // also zbuf
    __half*   hbuf    = (__half*)alloc((size_t)NNP * 128 * 2);
    float*    asd     = (float*)alloc((size_t)NNP * 8 * 4);
    float*    wb      = (float*)alloc((size_t)NE * 4 * 4);       // L1 exp'd weights
    int*      offp    = (int*)alloc((size_t)(NN + 1) * 4);
    unsigned* e4      = (unsigned*)alloc((size_t)NE * 4);
    int*      gbh     = (int*)alloc(256 * 4);
    int*      gboff   = (int*)alloc(256 * 4);
    int*      gcur    = (int*)alloc(256 * 4);
    float*    smallw  = (float*)alloc(4096);
    float*    lutbuf  = (float*)alloc((size_t)2 * LUTN * 4 * 4);
    // ebuf2 (8 MB) overlays hbuf (25.6 MB): ebuf2 is written by k_scat and
    // last read by k_fine, strictly before hbuf's first write in k_zm.
    uint2*    ebuf2   = (uint2*)hbuf;

    hipMemsetAsync(gbh, 0, 256 * 4, stream);
    k_small<<<1, 256, 0, stream>>>(We, be, Wedge1, atte1, Wedge2, atte2, Wf, bfv,
                                   W1, atts1, attd1, smallw);
    k_lut<<<(2 * LUTN + 255) / 256, 256, 0, stream>>>(smallw, gamma, lutbuf);
    // h0 + fused degree histogram
    k_h0<<<NH0B + SCATB, 256, 0, stream>>>(pfeat, Wf, bfv, smallw, ei, gbh, h0, asd);
    k_bscan<<<1, 256, 0, stream>>>(gbh, gboff, gcur, offp);
    k_scat<<<SCATB, 256, 0, stream>>>(ei, ppos, wpos, gcur, ebuf2);
    k_fine<<<NBUCK, 1024, 0, stream>>>(gboff, ebuf2, lutbuf, asd, offp, e4, wb);
    // layer 1: lean aggregation (weights prebuilt by k_fine), MFMA W1
    k_aggz<<<NN / 16, 256, 0, stream>>>(offp, e4, wb, h0, x16);
    k_zm<<<NNP / 64, 256, 0, stream>>>(x16, W1, b1, hbuf);
    // layer 2 (water destinations only; weights computed inline in k_agg2)
    k_xm<<<NNP / 64, 256, 0, stream>>>(hbuf, W2, atts2, attd2, x16, asd);
    k_agg2<<<N_WAT / 8, 256, 0, stream>>>(offp, e4, lutbuf + (size_t)LUTN * 4, asd, x16, b2, hbuf);
    // MLP on water nodes (MFMA)
    k_mlp<<<N_WAT / 64, 256, 0, stream>>>(hbuf, Wm1, bm1, Wm2, bm2, out);
}

// Round 6
// 288.184 us; speedup vs baseline: 1.3160x; 1.0773x over previous
//
#include <hip/hip_runtime.h>
#include <hip/hip_fp16.h>
#include <stdint.h>

#define N_PRO 60000
#define N_WAT 40000
#define NN    100000
#define NNP   100032            // padded to a multiple of 64 for tiles
#define NE    1000000
#define IN_DIM 21
#define HID    32
#define HEADS  4
#define HC     128
#define EDGE_K 32
#define LUTN   2048             // distance-LUT bins, bin = dist*256 (range [0,8))
#define NH0B  ((NNP * 32) / 256)       // h0 blocks
#define NBUCK 196                      // coarse buckets of 512 nodes (node>>9)
#define EPT   8                        // edges per thread in scat
#define SCATB ((NE / EPT + 255) / 256) // 489 blocks
#define FCAP  6144                     // per-bucket region capacity (edges)
#define SLOTS (NBUCK * FCAP)           // 1,204,224 region-addressed slots

typedef _Float16 half8 __attribute__((ext_vector_type(8)));
typedef float    f32x4 __attribute__((ext_vector_type(4)));

// ---------------------------------------------------------------------------
// K0 (k_pre, 17 blocks): block 16 = tiny fused weights (smallw) + W1->fp16
// pack (w1h, k_zm's [c*40+k] layout) + gcur zero. Blocks 0..15 = distance
// LUT, recomputing their layer's U/aeb locally (8K FMA — free) so the old
// k_small->k_lut dependency/launch disappears.
// smallw floats: [0..127]=U1, [128..131]=aeb1, [132..259]=U2, [260..263]=aeb2,
// [264..295]=h0w, [296..423]=va_s1, [424..551]=va_d1
// ---------------------------------------------------------------------------
__global__ __launch_bounds__(256) void k_pre(
    const float* We, const float* be,
    const float* Wedge1, const float* atte1,
    const float* Wedge2, const float* atte2,
    const float* Wf, const float* bfv,
    const float* W1, const float* atts1, const float* attd1,
    const float* gamma,
    float* smallw, float* lut, __half* w1h, int* gcur)
{
    __shared__ float V[2][128];
    __shared__ float aebs[4];
    int t = threadIdx.x;
    if (blockIdx.x == 16) {
        {
            int l = t >> 7, dh = t & 127, d = dh >> 2, h = dh & 3;
            const float* Wg = l ? Wedge2 : Wedge1;
            const float* ae = l ? atte2 : atte1;
            float s = 0.f;
            for (int c = 0; c < HID; c++)
                s += Wg[d * HC + h * HID + c] * ae[h * HID + c];
            V[l][dh] = s;
        }
        __syncthreads();
        {
            int l = t >> 7, kh = t & 127, k = kh >> 2, h = kh & 3;
            float s = 0.f;
            for (int d = 0; d < 32; d++)
                s += We[k * 32 + d] * V[l][d * 4 + h];
            smallw[(l ? 132 : 0) + kh] = s;
        }
        if (t < 8) {
            int l = t >> 2, h = t & 3;
            float s = 0.f;
            for (int d = 0; d < 32; d++)
                s += be[d] * V[l][d * 4 + h];
            smallw[(l ? 260 : 128) + h] = s;
        }
        if (t >= 32 && t < 64) {
            int c = t - 32;
            smallw[264 + c] = Wf[20 * 32 + c] + bfv[c];
        }
        {
            int side = t >> 7;
            int h = (t >> 5) & 3, c = t & 31;
            const float* av = side ? attd1 : atts1;
            float s = 0.f;
            for (int j = 0; j < 32; j++)
                s += W1[c * 128 + h * 32 + j] * av[h * 32 + j];
            smallw[(side ? 424 : 296) + (t & 127)] = s;
        }
        // W1 -> fp16, k_zm Wt layout [c*40 + k], 80B rows
        for (int i = t; i < 128 * 8; i += 256) {
            int c = i & 127, k4 = (i >> 7) * 4;
            float w0 = W1[(k4 + 0) * 128 + c];
            float w1v = W1[(k4 + 1) * 128 + c];
            float w2 = W1[(k4 + 2) * 128 + c];
            float w3 = W1[(k4 + 3) * 128 + c];
            __half2 p0 = __floats2half2_rn(w0, w1v);
            __half2 p1 = __floats2half2_rn(w2, w3);
            uint2 pk;
            pk.x = *(unsigned*)&p0;
            pk.y = *(unsigned*)&p1;
            *(uint2*)&w1h[c * 40 + k4] = pk;
        }
        gcur[t] = 0;
        return;
    }
    // LUT blocks: 256 entries each; layer uniform per block.
    int e = blockIdx.x * 256 + t;
    int layer = e >> 11, bin = e & (LUTN - 1);
    const float* Wg = layer ? Wedge2 : Wedge1;
    const float* ae = layer ? atte2 : atte1;
    if (t < 128) {
        int d = t >> 2, h = t & 3;
        float s = 0.f;
        for (int c = 0; c < 32; c++)
            s += Wg[d * HC + h * HID + c] * ae[h * HID + c];
        V[0][t] = s;
    }
    __syncthreads();
    if (t < 128) {
        int k = t >> 2, h = t & 3;
        float s = 0.f;
        for (int d = 0; d < 32; d++)
            s += We[k * 32 + d] * V[0][d * 4 + h];
        V[1][t] = s;
    }
    if (t >= 128 && t < 132) {
        int h = t - 128;
        float s = 0.f;
        for (int d = 0; d < 32; d++)
            s += be[d] * V[0][d * 4 + h];
        aebs[h] = s;
    }
    __syncthreads();
    const float* U = V[1];
    float dd = bin * (1.0f / 256.0f);
    float g = gamma[0];
    float a0 = aebs[0], a1 = aebs[1], a2 = aebs[2], a3 = aebs[3];
    const float step = 5.0f / 31.0f;
    #pragma unroll
    for (int k = 0; k < EDGE_K; k++) {
        float tt = dd - (float)k * step;
        float r = __expf(-g * tt * tt);
        a0 += r * U[k * 4 + 0];
        a1 += r * U[k * 4 + 1];
        a2 += r * U[k * 4 + 2];
        a3 += r * U[k * 4 + 3];
    }
    *(float4*)&lut[(size_t)e * 4] = make_float4(a0, a1, a2, a3);
}

// ---------------------------------------------------------------------------
// K2: h0 = feats@Wf+bf (fp16) + layer-1 logits asd (histogram removed — the
// bucket counts now come from k_scat's own gcur atomics).
// ---------------------------------------------------------------------------
__global__ __launch_bounds__(256) void k_h0(
    const float* __restrict__ pf, const float* __restrict__ Wf,
    const float* __restrict__ bfv, const float* __restrict__ smallw,
    __half* __restrict__ h0, float* __restrict__ asd)
{
    int t = threadIdx.x;
    __shared__ float Wfs[IN_DIM * 32];
    __shared__ float bfs[32];
    __shared__ float h0w[32];
    __shared__ float vas[128], vad[128];
    for (int i = t; i < IN_DIM * 32; i += 256) Wfs[i] = Wf[i];
    if (t < 32) { bfs[t] = bfv[t]; h0w[t] = smallw[264 + t]; }
    if (t < 128) vas[t] = smallw[296 + t];
    else         vad[t - 128] = smallw[424 + (t - 128)];
    __syncthreads();
    int id = blockIdx.x * 256 + t;
    int n = id >> 5, c = id & 31;
    if (n >= NNP) return;
    float v;
    if (n < N_PRO) {
        float s = bfs[c];
        for (int k = 0; k < IN_DIM; k++)
            s += pf[n * IN_DIM + k] * Wfs[k * 32 + c];
        v = s;
    } else {
        v = h0w[c];
    }
    h0[(size_t)n * 32 + c] = __float2half(v);
    float ps[4], pd[4];
    #pragma unroll
    for (int h = 0; h < 4; h++) {
        ps[h] = v * vas[h * 32 + c];
        pd[h] = v * vad[h * 32 + c];
    }
    #pragma unroll
    for (int m = 1; m < 32; m <<= 1) {
        #pragma unroll
        for (int h = 0; h < 4; h++) {
            ps[h] += __shfl_xor(ps[h], m, 64);
            pd[h] += __shfl_xor(pd[h], m, 64);
        }
    }
    if ((t & 31) == 0) {
        *(float4*)&asd[(size_t)n * 8]     = make_float4(ps[0], ps[1], ps[2], ps[3]);
        *(float4*)&asd[(size_t)n * 8 + 4] = make_float4(pd[0], pd[1], pd[2], pd[3]);
    }
}

// ---------------------------------------------------------------------------
// k_scat: FIXED-REGION bucket scatter. Bucket b owns [b*FCAP, ...); gcur[b]
// (zeroed in k_pre) both allocates and counts — no histogram, no scan.
// ---------------------------------------------------------------------------
__global__ __launch_bounds__(256) void k_scat(
    const int* __restrict__ ei, const float* __restrict__ ppos,
    const float* __restrict__ wpos, int* __restrict__ gcur,
    uint2* __restrict__ ebuf2)
{
    __shared__ int lh[256];
    __shared__ int lbase[256];
    int t = threadIdx.x;
    lh[t] = 0;
    __syncthreads();
    int e0 = (blockIdx.x * 256 + t) * EPT;
    int bkt[EPT], rnk[EPT];
    unsigned rec0[EPT], rec1[EPT];
    #pragma unroll
    for (int j = 0; j < EPT; j++) bkt[j] = -1;
    if (e0 < NE) {
        int4 sa = *(const int4*)&ei[e0];
        int4 sb = *(const int4*)&ei[e0 + 4];
        int4 da = *(const int4*)&ei[NE + e0];
        int4 db = *(const int4*)&ei[NE + e0 + 4];
        int ss[8] = {sa.x, sa.y, sa.z, sa.w, sb.x, sb.y, sb.z, sb.w};
        int ds[8] = {da.x, da.y, da.z, da.w, db.x, db.y, db.z, db.w};
        #pragma unroll
        for (int j = 0; j < EPT; j++) {
            int s = ss[j], d = ds[j];
            if ((unsigned)d < (unsigned)NN) {
                const float* ps = (s < N_PRO) ? &ppos[s * 3] : &wpos[(s - N_PRO) * 3];
                const float* pd = (d < N_PRO) ? &ppos[d * 3] : &wpos[(d - N_PRO) * 3];
                float dx = pd[0] - ps[0];
                float dy = pd[1] - ps[1];
                float dz = pd[2] - ps[2];
                float dist = sqrtf(dx * dx + dy * dy + dz * dz);
                unsigned code = (unsigned)fminf(dist * 4096.0f, 32767.0f);
                bkt[j] = d >> 9;
                rec0[j] = ((unsigned)d << 15) | code;
                rec1[j] = (unsigned)s;
                rnk[j] = atomicAdd(&lh[bkt[j]], 1);
            }
        }
    }
    __syncthreads();
    if (t < NBUCK) lbase[t] = lh[t] ? atomicAdd(&gcur[t], lh[t]) : 0;
    __syncthreads();
    #pragma unroll
    for (int j = 0; j < EPT; j++)
        if (bkt[j] >= 0) {
            int p = lbase[bkt[j]] + rnk[j];
            if (p < FCAP)   // 14-sigma overflow guard
                ebuf2[(size_t)bkt[j] * FCAP + p] = make_uint2(rec0[j], rec1[j]);
        }
}

// ---------------------------------------------------------------------------
// k_fine: one block per bucket, 1024 threads. nb from gcur (counts). LDS
// staging, fine-count, wave-shuffle scan, write GLOBAL offA/offE (explicit
// end — bucket regions have gaps), then place e4 + exp'd layer-1 wb.
// ---------------------------------------------------------------------------
__global__ __launch_bounds__(1024) void k_fine(
    const int* __restrict__ gcur, const uint2* __restrict__ ebuf2,
    const float* __restrict__ lutg, const float* __restrict__ asd,
    int* __restrict__ offA, int* __restrict__ offE,
    unsigned* __restrict__ e4, float* __restrict__ wb)
{
    __shared__ uint2 eL[FCAP];          // 48 KB
    __shared__ int lcnt[512], lexc[512];
    __shared__ int wsum[8];
    int b = blockIdx.x, t = threadIdx.x;
    int beg = b * FCAP;
    int nb = gcur[b];
    if (nb > FCAP) nb = FCAP;
    for (int i = t; i < nb; i += 1024) eL[i] = ebuf2[beg + i];
    if (t < 512) lcnt[t] = 0;
    __syncthreads();
    for (int i = t; i < nb; i += 1024)
        atomicAdd(&lcnt[(eL[i].x >> 15) & 511], 1);
    __syncthreads();
    int c = 0;
    if (t < 512) {                       // waves 0..7 fully active
        c = lcnt[t];
        int lane = t & 63;
        int v = c;
        #pragma unroll
        for (int d = 1; d < 64; d <<= 1) {
            int x = __shfl_up(v, d, 64);
            if (lane >= d) v += x;
        }
        if (lane == 63) wsum[t >> 6] = v;
        lexc[t] = v - c;                 // wave-local exclusive prefix
    }
    __syncthreads();
    if (t < 8) {                         // exclusive scan of 8 wave sums
        int orig = wsum[t];
        int v = orig;
        #pragma unroll
        for (int d = 1; d < 8; d <<= 1) {
            int x = __shfl_up(v, d, 64);
            if (t >= d) v += x;
        }
        wsum[t] = v - orig;
    }
    __syncthreads();
    if (t < 512) {
        lexc[t] += wsum[t >> 6];
        int node = b * 512 + t;
        if (node < NN) {
            offA[node] = beg + lexc[t];
            offE[node] = beg + lexc[t] + c;
        }
        lcnt[t] = 0;                     // reuse as per-node cursor
    }
    __syncthreads();
    for (int i = t; i < nb; i += 1024) {
        uint2 u = eL[i];
        int ln = (int)((u.x >> 15) & 511u);
        int r = atomicAdd(&lcnt[ln], 1);
        int p = beg + lexc[ln] + r;
        unsigned code = u.x & 32767u;
        unsigned s = u.y;
        e4[p] = (s << 15) | code;
        int n = (b << 9) + ln;
        float f = fminf((float)code * 0.0625f, (float)(LUTN - 2));
        int i0 = (int)f;
        float fr = f - (float)i0;
        float4 A = *(const float4*)&lutg[(size_t)i0 * 4];
        float4 B = *(const float4*)&lutg[(size_t)(i0 + 1) * 4];
        float4 as4 = *(const float4*)&asd[(size_t)s * 8];
        float4 ad4 = *(const float4*)&asd[(size_t)n * 8 + 4];
        float v0 = as4.x + ad4.x + A.x + (B.x - A.x) * fr;
        float v1 = as4.y + ad4.y + A.y + (B.y - A.y) * fr;
        float v2 = as4.z + ad4.z + A.z + (B.z - A.z) * fr;
        float v3 = as4.w + ad4.w + A.w + (B.w - A.w) * fr;
        v0 = fmaxf(v0, 0.2f * v0);
        v1 = fmaxf(v1, 0.2f * v1);
        v2 = fmaxf(v2, 0.2f * v2);
        v3 = fmaxf(v3, 0.2f * v3);
        *(float4*)&wb[(size_t)p * 4] = make_float4(
            __expf(v0), __expf(v1), __expf(v2), __expf(v3));
    }
}

// ---------------------------------------------------------------------------
// K6 (MFMA): x = hbuf @ W2 (+ logits) via mfma_f32_16x16x32_f16.
// ---------------------------------------------------------------------------
__global__ __launch_bounds__(256) void k_xm(
    const __half* __restrict__ h, const float* __restrict__ Wg,
    const float* __restrict__ atts, const float* __restrict__ attd,
    __half* __restrict__ x16, float* __restrict__ asd)
{
    __shared__ __half Wt[128 * 136];
    __shared__ float attS[128], attD[128];
    int t = threadIdx.x;
    for (int i = t; i < 128 * 32; i += 256) {
        int c = i & 127, d = (i >> 7) * 4;
        float w0 = Wg[(d + 0) * 128 + c];
        float w1 = Wg[(d + 1) * 128 + c];
        float w2 = Wg[(d + 2) * 128 + c];
        float w3 = Wg[(d + 3) * 128 + c];
        __half2 p0 = __floats2half2_rn(w0, w1);
        __half2 p1 = __floats2half2_rn(w2, w3);
        uint2 pk;
        pk.x = *(unsigned*)&p0;
        pk.y = *(unsigned*)&p1;
        *(uint2*)&Wt[c * 136 + d] = pk;
    }
    if (t < 128) { attS[t] = atts[t]; attD[t] = attd[t]; }
    __syncthreads();
    int wv = t >> 6, lane = t & 63;
    int m16 = lane & 15, quad = lane >> 4;
    int n0 = blockIdx.x * 64 + wv * 16;
    f32x4 acc[8];
    #pragma unroll
    for (int ct = 0; ct < 8; ct++) acc[ct] = (f32x4){0.f, 0.f, 0.f, 0.f};
    #pragma unroll
    for (int ks = 0; ks < 4; ks++) {
        int d0 = ks * 32 + quad * 8;
        half8 bf = *(const half8*)&h[(size_t)(n0 + m16) * 128 + d0];
        #pragma unroll
        for (int ct = 0; ct < 8; ct++) {
            half8 af = *(const half8*)&Wt[(ct * 16 + m16) * 136 + d0];
            acc[ct] = __builtin_amdgcn_mfma_f32_16x16x32_f16(af, bf, acc[ct], 0, 0, 0);
        }
    }
    __half* xrow = &x16[(size_t)(n0 + m16) * 128 + quad * 4];
    float ps[4] = {0.f, 0.f, 0.f, 0.f}, pd[4] = {0.f, 0.f, 0.f, 0.f};
    #pragma unroll
    for (int ct = 0; ct < 8; ct++) {
        f32x4 a = acc[ct];
        __half2 h0p = __floats2half2_rn(a[0], a[1]);
        __half2 h1p = __floats2half2_rn(a[2], a[3]);
        uint2 pk;
        pk.x = *(unsigned*)&h0p;
        pk.y = *(unsigned*)&h1p;
        *(uint2*)&xrow[ct * 16] = pk;
        int cb = ct * 16 + quad * 4;
        int hh = ct >> 1;
        ps[hh] += a[0] * attS[cb] + a[1] * attS[cb + 1]
                + a[2] * attS[cb + 2] + a[3] * attS[cb + 3];
        pd[hh] += a[0] * attD[cb] + a[1] * attD[cb + 1]
                + a[2] * attD[cb + 2] + a[3] * attD[cb + 3];
    }
    #pragma unroll
    for (int hh = 0; hh < 4; hh++) {
        ps[hh] += __shfl_xor(ps[hh], 16, 64);
        ps[hh] += __shfl_xor(ps[hh], 32, 64);
        pd[hh] += __shfl_xor(pd[hh], 16, 64);
        pd[hh] += __shfl_xor(pd[hh], 32, 64);
    }
    if (lane < 16) {
        int n = n0 + m16;
        *(float4*)&asd[(size_t)n * 8]     = make_float4(ps[0], ps[1], ps[2], ps[3]);
        *(float4*)&asd[(size_t)n * 8 + 4] = make_float4(pd[0], pd[1], pd[2], pd[3]);
    }
}

// ---------------------------------------------------------------------------
// K8a (k_zm FUSED): layer-1 aggregation (16-lane group/node, unroll 4) THEN
// the blockdiag-W1 MFMA in the same block: z rows -> LDS zs[16][136]
// (padded, <=2-way conflicts), barrier, 4 waves x 2 col-tiles of
// mfma_f32_16x16x32_f16, k_zm's exact epilogue (bias+ELU) -> hbuf.
// Kills the 51 MB zbuf round-trip and one launch. Wt comes pre-packed (w1h).
// ---------------------------------------------------------------------------
__global__ __launch_bounds__(256) void k_aggz(
    const int* __restrict__ offA, const int* __restrict__ offE,
    const unsigned* __restrict__ e4, const float* __restrict__ wb,
    const __half* __restrict__ h016, const __half* __restrict__ w1h,
    const float* __restrict__ b1, __half* __restrict__ hbuf)
{
    __shared__ __half Wt[128 * 40];     // 10240 B, [c*40+k]
    __shared__ __half zs[16][136];      // 4352 B, padded rows
    int t = threadIdx.x;
    {
        uint4* dst = (uint4*)Wt;
        const uint4* src = (const uint4*)w1h;
        for (int i = t; i < 640; i += 256) dst[i] = src[i];
    }
    int wv = t >> 6, lane = t & 63;
    int g = lane >> 4, q = lane & 15;
    int n = blockIdx.x * 16 + wv * 4 + g;        // grid exact: NN/16
    int beg = offA[n], end = offE[n];
    const __half2* x2 = (const __half2*)h016;
    float a0x = 0.f, a0y = 0.f, a1x = 0.f, a1y = 0.f;
    float a2x = 0.f, a2y = 0.f, a3x = 0.f, a3y = 0.f;
    float l0 = 0.f, l1 = 0.f, l2 = 0.f, l3 = 0.f;
    int i = beg;
    for (; i + 3 < end; i += 4) {
        unsigned u0 = e4[i],     u1 = e4[i + 1];
        unsigned u2 = e4[i + 2], u3 = e4[i + 3];
        float4 w0 = *(const float4*)&wb[(size_t)i * 4];
        float4 w1 = *(const float4*)&wb[(size_t)(i + 1) * 4];
        float4 w2 = *(const float4*)&wb[(size_t)(i + 2) * 4];
        float4 w3 = *(const float4*)&wb[(size_t)(i + 3) * 4];
        float2 x0 = __half22float2(x2[(u0 >> 15) * 16u + q]);
        float2 x1 = __half22float2(x2[(u1 >> 15) * 16u + q]);
        float2 x2v = __half22float2(x2[(u2 >> 15) * 16u + q]);
        float2 x3 = __half22float2(x2[(u3 >> 15) * 16u + q]);
        a0x += w0.x * x0.x + w1.x * x1.x + w2.x * x2v.x + w3.x * x3.x;
        a0y += w0.x * x0.y + w1.x * x1.y + w2.x * x2v.y + w3.x * x3.y;
        a1x += w0.y * x0.x + w1.y * x1.x + w2.y * x2v.x + w3.y * x3.x;
        a1y += w0.y * x0.y + w1.y * x1.y + w2.y * x2v.y + w3.y * x3.y;
        a2x += w0.z * x0.x + w1.z * x1.x + w2.z * x2v.x + w3.z * x3.x;
        a2y += w0.z * x0.y + w1.z * x1.y + w2.z * x2v.y + w3.z * x3.y;
        a3x += w0.w * x0.x + w1.w * x1.x + w2.w * x2v.x + w3.w * x3.x;
        a3y += w0.w * x0.y + w1.w * x1.y + w2.w * x2v.y + w3.w * x3.y;
        l0 += (w0.x + w1.x) + (w2.x + w3.x);
        l1 += (w0.y + w1.y) + (w2.y + w3.y);
        l2 += (w0.z + w1.z) + (w2.z + w3.z);
        l3 += (w0.w + w1.w) + (w2.w + w3.w);
    }
    for (; i < end; i++) {
        unsigned u0 = e4[i];
        float4 w0 = *(const float4*)&wb[(size_t)i * 4];
        float2 x0 = __half22float2(x2[(u0 >> 15) * 16u + q]);
        a0x += w0.x * x0.x;  a0y += w0.x * x0.y;
        a1x += w0.y * x0.x;  a1y += w0.y * x0.y;
        a2x += w0.z * x0.x;  a2y += w0.z * x0.y;
        a3x += w0.w * x0.x;  a3y += w0.w * x0.y;
        l0 += w0.x; l1 += w0.y; l2 += w0.z; l3 += w0.w;
    }
    float i0v = 1.0f / (l0 + 1e-16f);
    float i1v = 1.0f / (l1 + 1e-16f);
    float i2v = 1.0f / (l2 + 1e-16f);
    float i3v = 1.0f / (l3 + 1e-16f);
    int nl = wv * 4 + g;
    *(__half2*)&zs[nl][     q * 2] = __floats2half2_rn(a0x * i0v, a0y * i0v);
    *(__half2*)&zs[nl][32 + q * 2] = __floats2half2_rn(a1x * i1v, a1y * i1v);
    *(__half2*)&zs[nl][64 + q * 2] = __floats2half2_rn(a2x * i2v, a2y * i2v);
    *(__half2*)&zs[nl][96 + q * 2] = __floats2half2_rn(a3x * i3v, a3y * i3v);
    __syncthreads();
    // MFMA: wave wv owns col-tiles {2wv, 2wv+1} (head wv) for all 16 rows.
    int m16 = lane & 15, quad = lane >> 4;
    half8 bf = *(const half8*)&zs[m16][wv * 32 + quad * 8];
    __half* orow = &hbuf[(size_t)(blockIdx.x * 16 + m16) * 128 + quad * 4];
    #pragma unroll
    for (int c2 = 0; c2 < 2; c2++) {
        int ct = wv * 2 + c2;
        half8 af = *(const half8*)&Wt[(ct * 16 + m16) * 40 + quad * 8];
        f32x4 acc = __builtin_amdgcn_mfma_f32_16x16x32_f16(
            af, bf, (f32x4){0.f, 0.f, 0.f, 0.f}, 0, 0, 0);
        int cb = ct * 16 + quad * 4;
        float4 bb = *(const float4*)&b1[cb];
        float r0 = acc[0] + bb.x;
        float r1 = acc[1] + bb.y;
        float r2 = acc[2] + bb.z;
        float r3 = acc[3] + bb.w;
        r0 = r0 > 0.f ? r0 : __expf(r0) - 1.0f;
        r1 = r1 > 0.f ? r1 : __expf(r1) - 1.0f;
        r2 = r2 > 0.f ? r2 : __expf(r2) - 1.0f;
        r3 = r3 > 0.f ? r3 : __expf(r3) - 1.0f;
        __half2 ha = __floats2half2_rn(r0, r1);
        __half2 hb = __floats2half2_rn(r2, r3);
        uint2 pk;
        pk.x = *(unsigned*)&ha;
        pk.y = *(unsigned*)&hb;
        *(uint2*)&orow[ct * 16] = pk;
    }
}

// ---------------------------------------------------------------------------
// K8b: layer-2 aggregation with INLINE weight computation. 32-lane group per
// node; head h=q>>3; weight = exp(leaky(as+ae+ad)) head-redundantly.
// ---------------------------------------------------------------------------
__global__ __launch_bounds__(256) void k_agg2(
    const int* __restrict__ offA, const int* __restrict__ offE,
    const unsigned* __restrict__ e4,
    const float* __restrict__ lutg, const float* __restrict__ asd,
    const __half* __restrict__ x16, const float* __restrict__ bias,
    __half* __restrict__ hout)
{
    int t = threadIdx.x;
    int wv = t >> 6, lane = t & 63;
    int g = lane >> 5, q = lane & 31;
    int n = N_PRO + blockIdx.x * 8 + wv * 2 + g;  // grid exact: N_WAT/8
    int h = q >> 3;
    int beg = offA[n], end = offE[n];
    float adh = asd[(size_t)n * 8 + 4 + h];
    float ax = 0.f, ay = 0.f, az = 0.f, aw = 0.f, ls = 0.f;
    int i = beg;
    for (; i + 1 < end; i += 2) {
        unsigned u0 = e4[i], u1 = e4[i + 1];
        unsigned s0 = u0 >> 15, s1 = u1 >> 15;
        float f0 = fminf((float)(u0 & 32767u) * 0.0625f, (float)(LUTN - 2));
        float f1 = fminf((float)(u1 & 32767u) * 0.0625f, (float)(LUTN - 2));
        int i00 = (int)f0, i10 = (int)f1;
        float fr0 = f0 - (float)i00, fr1 = f1 - (float)i10;
        float A0 = lutg[i00 * 4 + h], B0 = lutg[(i00 + 1) * 4 + h];
        float A1 = lutg[i10 * 4 + h], B1 = lutg[(i10 + 1) * 4 + h];
        float as0 = asd[(size_t)s0 * 8 + h], as1 = asd[(size_t)s1 * 8 + h];
        float2 r0 = *(const float2*)&x16[(size_t)s0 * 128 + q * 4];
        float2 r1 = *(const float2*)&x16[(size_t)s1 * 128 + q * 4];
        float v0 = as0 + adh + A0 + (B0 - A0) * fr0;
        float v1 = as1 + adh + A1 + (B1 - A1) * fr1;
        v0 = fmaxf(v0, 0.2f * v0);
        v1 = fmaxf(v1, 0.2f * v1);
        float w0 = __expf(v0), w1 = __expf(v1);
        float2 f00 = __half22float2(*(__half2*)&r0.x);
        float2 f01 = __half22float2(*(__half2*)&r0.y);
        float2 f10 = __half22float2(*(__half2*)&r1.x);
        float2 f11 = __half22float2(*(__half2*)&r1.y);
        ax += w0 * f00.x + w1 * f10.x;
        ay += w0 * f00.y + w1 * f10.y;
        az += w0 * f01.x + w1 * f11.x;
        aw += w0 * f01.y + w1 * f11.y;
        ls += w0 + w1;
    }
    if (i < end) {
        unsigned u0 = e4[i];
        unsigned s0 = u0 >> 15;
        float f0 = fminf((float)(u0 & 32767u) * 0.0625f, (float)(LUTN - 2));
        int i00 = (int)f0;
        float fr0 = f0 - (float)i00;
        float A0 = lutg[i00 * 4 + h], B0 = lutg[(i00 + 1) * 4 + h];
        float as0 = asd[(size_t)s0 * 8 + h];
        float2 r0 = *(const float2*)&x16[(size_t)s0 * 128 + q * 4];
        float v0 = as0 + adh + A0 + (B0 - A0) * fr0;
        v0 = fmaxf(v0, 0.2f * v0);
        float w0 = __expf(v0);
        float2 f00 = __half22float2(*(__half2*)&r0.x);
        float2 f01 = __half22float2(*(__half2*)&r0.y);
        ax += w0 * f00.x; ay += w0 * f00.y;
        az += w0 * f01.x; aw += w0 * f01.y;
        ls += w0;
    }
    float inv = 1.0f / (ls + 1e-16f);
    float4 bb = *(const float4*)&bias[q * 4];
    float o0 = ax * inv + bb.x;
    float o1 = ay * inv + bb.y;
    float o2 = az * inv + bb.z;
    float o3 = aw * inv + bb.w;
    o0 = o0 > 0.f ? o0 : __expf(o0) - 1.0f;
    o1 = o1 > 0.f ? o1 : __expf(o1) - 1.0f;
    o2 = o2 > 0.f ? o2 : __expf(o2) - 1.0f;
    o3 = o3 > 0.f ? o3 : __expf(o3) - 1.0f;
    __half2 ha = __floats2half2_rn(o0, o1);
    __half2 hb = __floats2half2_rn(o2, o3);
    uint2 pk;
    pk.x = *(unsigned*)&ha;
    pk.y = *(unsigned*)&hb;
    *(uint2*)&hout[(size_t)n * 128 + q * 4] = pk;
}

// ---------------------------------------------------------------------------
// K9 (MFMA): water MLP, k_xm-structure. 64 nodes/block, Wm1^T fp16 in LDS,
// epilogue bias+ReLU then 128->2 layer-2 via per-lane dots + shuffle-reduce.
// ---------------------------------------------------------------------------
__global__ __launch_bounds__(256) void k_mlp(
    const __half* __restrict__ hh, const float* __restrict__ Wm1,
    const float* __restrict__ bm1, const float* __restrict__ Wm2,
    const float* __restrict__ bm2, float* __restrict__ out)
{
    __shared__ __half Wt[128 * 136];
    __shared__ float b1s[128];
    __shared__ float w2s[256];
    int t = threadIdx.x;
    for (int i = t; i < 128 * 32; i += 256) {
        int c = i & 127, d = (i >> 7) * 4;
        float w0 = Wm1[(d + 0) * 128 + c];
        float w1 = Wm1[(d + 1) * 128 + c];
        float w2 = Wm1[(d + 2) * 128 + c];
        float w3 = Wm1[(d + 3) * 128 + c];
        __half2 p0 = __floats2half2_rn(w0, w1);
        __half2 p1 = __floats2half2_rn(w2, w3);
        uint2 pk;
        pk.x = *(unsigned*)&p0;
        pk.y = *(unsigned*)&p1;
        *(uint2*)&Wt[c * 136 + d] = pk;
    }
    if (t < 128) b1s[t] = bm1[t];
    w2s[t] = Wm2[t];                       // 256 floats = [128][2]
    __syncthreads();
    int wv = t >> 6, lane = t & 63;
    int m16 = lane & 15, quad = lane >> 4;
    int n0 = blockIdx.x * 64 + wv * 16;    // water-local node base
    f32x4 acc[8];
    #pragma unroll
    for (int ct = 0; ct < 8; ct++) acc[ct] = (f32x4){0.f, 0.f, 0.f, 0.f};
    #pragma unroll
    for (int ks = 0; ks < 4; ks++) {
        int d0 = ks * 32 + quad * 8;
        half8 bf = *(const half8*)&hh[(size_t)(N_PRO + n0 + m16) * 128 + d0];
        #pragma unroll
        for (int ct = 0; ct < 8; ct++) {
            half8 af = *(const half8*)&Wt[(ct * 16 + m16) * 136 + d0];
            acc[ct] = __builtin_amdgcn_mfma_f32_16x16x32_f16(af, bf, acc[ct], 0, 0, 0);
        }
    }
    float p0 = 0.f, p1 = 0.f;
    #pragma unroll
    for (int ct = 0; ct < 8; ct++) {
        int cb = ct * 16 + quad * 4;
        float4 bb = *(const float4*)&b1s[cb];
        float r0 = fmaxf(acc[ct][0] + bb.x, 0.f);
        float r1 = fmaxf(acc[ct][1] + bb.y, 0.f);
        float r2 = fmaxf(acc[ct][2] + bb.z, 0.f);
        float r3 = fmaxf(acc[ct][3] + bb.w, 0.f);
        p0 += r0 * w2s[(cb + 0) * 2] + r1 * w2s[(cb + 1) * 2]
            + r2 * w2s[(cb + 2) * 2] + r3 * w2s[(cb + 3) * 2];
        p1 += r0 * w2s[(cb + 0) * 2 + 1] + r1 * w2s[(cb + 1) * 2 + 1]
            + r2 * w2s[(cb + 2) * 2 + 1] + r3 * w2s[(cb + 3) * 2 + 1];
    }
    p0 += __shfl_xor(p0, 16, 64);
    p0 += __shfl_xor(p0, 32, 64);
    p1 += __shfl_xor(p1, 16, 64);
    p1 += __shfl_xor(p1, 32, 64);
    if (lane < 16) {
        int wn = n0 + m16;
        *(float2*)&out[(size_t)wn * 2] = make_float2(p0 + bm2[0], p1 + bm2[1]);
    }
}

// ---------------------------------------------------------------------------
extern "C" void kernel_launch(void* const* d_in, const int* in_sizes, int n_in,
                              void* d_out, int out_size, void* d_ws, size_t ws_size,
                              hipStream_t stream)
{
    const float* ppos   = (const float*)d_in[0];
    const float* wpos   = (const float*)d_in[1];
    const float* pfeat  = (const float*)d_in[2];
    const int*   ei     = (const int*)d_in[3];
    const float* gamma  = (const float*)d_in[4];
    const float* Wf     = (const float*)d_in[5];
    const float* bfv    = (const float*)d_in[6];
    const float* We     = (const float*)d_in[7];
    const float* be     = (const float*)d_in[8];
    const float* W1     = (const float*)d_in[9];
    const float* atts1  = (const float*)d_in[10];
    const float* attd1  = (const float*)d_in[11];
    const float* Wedge1 = (const float*)d_in[12];
    const float* atte1  = (const float*)d_in[13];
    const float* b1     = (const float*)d_in[14];
    const float* W2     = (const float*)d_in[15];
    const float* atts2  = (const float*)d_in[16];
    const float* attd2  = (const float*)d_in[17];
    const float* Wedge2 = (const float*)d_in[18];
    const float* atte2  = (const float*)d_in[19];
    const float* b2     = (const float*)d_in[20];
    const float* Wm1    = (const float*)d_in[21];
    const float* bm1    = (const float*)d_in[22];
    const float* Wm2    = (const float*)d_in[23];
    const float* bm2    = (const float*)d_in[24];
    float* out = (float*)d_out;

    char* ws = (char*)d_ws;
    size_t o = 0;
    auto alloc = [&](size_t bytes) -> char* {
        char* p = ws + o;
        o += (bytes + 255) & ~(size_t)255;
        return p;
    };
    __half*   h0      = (__half*)alloc((size_t)NNP * 32 * 2);
    __half*   x16     = (__half*)alloc((size_t)NNP * 128 * 2);
    __half*   hbuf    = (__half*)alloc((size_t)NNP * 128 * 2);
    float*    asd     = (float*)alloc((size_t)NNP * 8 * 4);
    float*    wb      = (float*)alloc((size_t)SLOTS * 4 * 4);    // region-addressed
    int*      offA    = (int*)alloc((size_t)NN * 4);
    int*      offE    = (int*)alloc((size_t)NN * 4);
    unsigned* e4      = (unsigned*)alloc((size_t)SLOTS * 4);
    int*      gcur    = (int*)alloc(256 * 4);
    float*    smallw  = (float*)alloc(4096);
    float*    lutbuf  = (float*)alloc((size_t)2 * LUTN * 4 * 4);
    __half*   w1h     = (__half*)alloc((size_t)128 * 40 * 2);
    // ebuf2 (9.6 MB) overlays hbuf (25.6 MB): written by k_scat, last read by
    // k_fine, strictly before hbuf's first write in (fused) k_aggz.
    uint2*    ebuf2   = (uint2*)hbuf;

    // 8 dispatches total (was 12 + memset).
    k_pre<<<17, 256, 0, stream>>>(We, be, Wedge1, atte1, Wedge2, atte2, Wf, bfv,
                                  W1, atts1, attd1, gamma,
                                  smallw, lutbuf, w1h, gcur);
    k_h0<<<NH0B, 256, 0, stream>>>(pfeat, Wf, bfv, smallw, h0, asd);
    k_scat<<<SCATB, 256, 0, stream>>>(ei, ppos, wpos, gcur, ebuf2);
    k_fine<<<NBUCK, 1024, 0, stream>>>(gcur, ebuf2, lutbuf, asd, offA, offE, e4, wb);
    k_aggz<<<NN / 16, 256, 0, stream>>>(offA, offE, e4, wb, h0, w1h, b1, hbuf);
    k_xm<<<NNP / 64, 256, 0, stream>>>(hbuf, W2, atts2, attd2, x16, asd);
    k_agg2<<<N_WAT / 8, 256, 0, stream>>>(offA, offE, e4,
                                          lutbuf + (size_t)LUTN * 4, asd, x16, b2, hbuf);
    k_mlp<<<N_WAT / 64, 256, 0, stream>>>(hbuf, Wm1, bm1, Wm2, bm2, out);
}

// Round 7
// 282.677 us; speedup vs baseline: 1.3417x; 1.0195x over previous
//
#include <hip/hip_runtime.h>
#include <hip/hip_fp16.h>
#include <stdint.h>

#define N_PRO 60000
#define N_WAT 40000
#define NN    100000
#define NNP   100032            // padded to a multiple of 64 for tiles
#define NE    1000000
#define IN_DIM 21
#define HID    32
#define HEADS  4
#define HC     128
#define EDGE_K 32
#define LUTN   2048             // distance-LUT bins, bin = dist*256 (range [0,8))
#define NH0B  ((NNP * 32) / 256)       // h0 blocks
#define NBUCK 196                      // coarse buckets of 512 nodes (node>>9)
#define EPT   8                        // edges per thread in scat
#define SCATB ((NE / EPT + 255) / 256) // 489 blocks
#define FCAP  6144                     // per-bucket region capacity (edges)
#define SLOTS (NBUCK * FCAP)           // 1,204,224 region-addressed slots

typedef _Float16 half8 __attribute__((ext_vector_type(8)));
typedef float    f32x4 __attribute__((ext_vector_type(4)));

// ---------------------------------------------------------------------------
// K0 (k_pre, 17 blocks): block 16 = tiny fused weights (smallw) + W1->fp16
// pack (w1h) + gcur zero. Blocks 0..15 = distance LUT (recompute local U/aeb).
// smallw floats: [0..127]=U1, [128..131]=aeb1, [132..259]=U2, [260..263]=aeb2,
// [264..295]=h0w, [296..423]=va_s1, [424..551]=va_d1
// ---------------------------------------------------------------------------
__global__ __launch_bounds__(256) void k_pre(
    const float* We, const float* be,
    const float* Wedge1, const float* atte1,
    const float* Wedge2, const float* atte2,
    const float* Wf, const float* bfv,
    const float* W1, const float* atts1, const float* attd1,
    const float* gamma,
    float* smallw, float* lut, __half* w1h, int* gcur)
{
    __shared__ float V[2][128];
    __shared__ float aebs[4];
    int t = threadIdx.x;
    if (blockIdx.x == 16) {
        {
            int l = t >> 7, dh = t & 127, d = dh >> 2, h = dh & 3;
            const float* Wg = l ? Wedge2 : Wedge1;
            const float* ae = l ? atte2 : atte1;
            float s = 0.f;
            for (int c = 0; c < HID; c++)
                s += Wg[d * HC + h * HID + c] * ae[h * HID + c];
            V[l][dh] = s;
        }
        __syncthreads();
        {
            int l = t >> 7, kh = t & 127, k = kh >> 2, h = kh & 3;
            float s = 0.f;
            for (int d = 0; d < 32; d++)
                s += We[k * 32 + d] * V[l][d * 4 + h];
            smallw[(l ? 132 : 0) + kh] = s;
        }
        if (t < 8) {
            int l = t >> 2, h = t & 3;
            float s = 0.f;
            for (int d = 0; d < 32; d++)
                s += be[d] * V[l][d * 4 + h];
            smallw[(l ? 260 : 128) + h] = s;
        }
        if (t >= 32 && t < 64) {
            int c = t - 32;
            smallw[264 + c] = Wf[20 * 32 + c] + bfv[c];
        }
        {
            int side = t >> 7;
            int h = (t >> 5) & 3, c = t & 31;
            const float* av = side ? attd1 : atts1;
            float s = 0.f;
            for (int j = 0; j < 32; j++)
                s += W1[c * 128 + h * 32 + j] * av[h * 32 + j];
            smallw[(side ? 424 : 296) + (t & 127)] = s;
        }
        // W1 -> fp16, k_zm Wt layout [c*40 + k], 80B rows
        for (int i = t; i < 128 * 8; i += 256) {
            int c = i & 127, k4 = (i >> 7) * 4;
            float w0 = W1[(k4 + 0) * 128 + c];
            float w1v = W1[(k4 + 1) * 128 + c];
            float w2 = W1[(k4 + 2) * 128 + c];
            float w3 = W1[(k4 + 3) * 128 + c];
            __half2 p0 = __floats2half2_rn(w0, w1v);
            __half2 p1 = __floats2half2_rn(w2, w3);
            uint2 pk;
            pk.x = *(unsigned*)&p0;
            pk.y = *(unsigned*)&p1;
            *(uint2*)&w1h[c * 40 + k4] = pk;
        }
        gcur[t] = 0;
        return;
    }
    // LUT blocks: 256 entries each; layer uniform per block.
    int e = blockIdx.x * 256 + t;
    int layer = e >> 11, bin = e & (LUTN - 1);
    const float* Wg = layer ? Wedge2 : Wedge1;
    const float* ae = layer ? atte2 : atte1;
    if (t < 128) {
        int d = t >> 2, h = t & 3;
        float s = 0.f;
        for (int c = 0; c < 32; c++)
            s += Wg[d * HC + h * HID + c] * ae[h * HID + c];
        V[0][t] = s;
    }
    __syncthreads();
    if (t < 128) {
        int k = t >> 2, h = t & 3;
        float s = 0.f;
        for (int d = 0; d < 32; d++)
            s += We[k * 32 + d] * V[0][d * 4 + h];
        V[1][t] = s;
    }
    if (t >= 128 && t < 132) {
        int h = t - 128;
        float s = 0.f;
        for (int d = 0; d < 32; d++)
            s += be[d] * V[0][d * 4 + h];
        aebs[h] = s;
    }
    __syncthreads();
    const float* U = V[1];
    float dd = bin * (1.0f / 256.0f);
    float g = gamma[0];
    float a0 = aebs[0], a1 = aebs[1], a2 = aebs[2], a3 = aebs[3];
    const float step = 5.0f / 31.0f;
    #pragma unroll
    for (int k = 0; k < EDGE_K; k++) {
        float tt = dd - (float)k * step;
        float r = __expf(-g * tt * tt);
        a0 += r * U[k * 4 + 0];
        a1 += r * U[k * 4 + 1];
        a2 += r * U[k * 4 + 2];
        a3 += r * U[k * 4 + 3];
    }
    *(float4*)&lut[(size_t)e * 4] = make_float4(a0, a1, a2, a3);
}

// ---------------------------------------------------------------------------
// K2 (k_hs, MERGED): blocks < NH0B: h0 = feats@Wf+bf (fp16) + layer-1 logits
// asd. Blocks >= NH0B: fixed-region bucket scatter (the old k_scat). The two
// halves are independent (h0: VALU/L1-bound; scat: HBM/atomic-bound) and
// overlap on the device — one launch instead of two.
// ---------------------------------------------------------------------------
__global__ __launch_bounds__(256) void k_hs(
    const float* __restrict__ pf, const float* __restrict__ Wf,
    const float* __restrict__ bfv, const float* __restrict__ smallw,
    const int* __restrict__ ei, const float* __restrict__ ppos,
    const float* __restrict__ wpos, int* __restrict__ gcur,
    uint2* __restrict__ ebuf2,
    __half* __restrict__ h0, float* __restrict__ asd)
{
    int t = threadIdx.x;
    if (blockIdx.x >= NH0B) {
        // ---- scat half ----
        __shared__ int lh[256];
        __shared__ int lbase[256];
        lh[t] = 0;
        __syncthreads();
        int e0 = ((blockIdx.x - NH0B) * 256 + t) * EPT;
        int bkt[EPT], rnk[EPT];
        unsigned rec0[EPT], rec1[EPT];
        #pragma unroll
        for (int j = 0; j < EPT; j++) bkt[j] = -1;
        if (e0 < NE) {
            int4 sa = *(const int4*)&ei[e0];
            int4 sb = *(const int4*)&ei[e0 + 4];
            int4 da = *(const int4*)&ei[NE + e0];
            int4 db = *(const int4*)&ei[NE + e0 + 4];
            int ss[8] = {sa.x, sa.y, sa.z, sa.w, sb.x, sb.y, sb.z, sb.w};
            int ds[8] = {da.x, da.y, da.z, da.w, db.x, db.y, db.z, db.w};
            #pragma unroll
            for (int j = 0; j < EPT; j++) {
                int s = ss[j], d = ds[j];
                if ((unsigned)d < (unsigned)NN) {
                    const float* ps = (s < N_PRO) ? &ppos[s * 3] : &wpos[(s - N_PRO) * 3];
                    const float* pd = (d < N_PRO) ? &ppos[d * 3] : &wpos[(d - N_PRO) * 3];
                    float dx = pd[0] - ps[0];
                    float dy = pd[1] - ps[1];
                    float dz = pd[2] - ps[2];
                    float dist = sqrtf(dx * dx + dy * dy + dz * dz);
                    unsigned code = (unsigned)fminf(dist * 4096.0f, 32767.0f);
                    bkt[j] = d >> 9;
                    rec0[j] = ((unsigned)d << 15) | code;
                    rec1[j] = (unsigned)s;
                    rnk[j] = atomicAdd(&lh[bkt[j]], 1);
                }
            }
        }
        __syncthreads();
        if (t < NBUCK) lbase[t] = lh[t] ? atomicAdd(&gcur[t], lh[t]) : 0;
        __syncthreads();
        #pragma unroll
        for (int j = 0; j < EPT; j++)
            if (bkt[j] >= 0) {
                int p = lbase[bkt[j]] + rnk[j];
                if (p < FCAP)   // 14-sigma overflow guard
                    ebuf2[(size_t)bkt[j] * FCAP + p] = make_uint2(rec0[j], rec1[j]);
            }
        return;
    }
    // ---- h0 half ----
    __shared__ float Wfs[IN_DIM * 32];
    __shared__ float bfs[32];
    __shared__ float h0w[32];
    __shared__ float vas[128], vad[128];
    for (int i = t; i < IN_DIM * 32; i += 256) Wfs[i] = Wf[i];
    if (t < 32) { bfs[t] = bfv[t]; h0w[t] = smallw[264 + t]; }
    if (t < 128) vas[t] = smallw[296 + t];
    else         vad[t - 128] = smallw[424 + (t - 128)];
    __syncthreads();
    int id = blockIdx.x * 256 + t;
    int n = id >> 5, c = id & 31;
    if (n >= NNP) return;
    float v;
    if (n < N_PRO) {
        float s = bfs[c];
        for (int k = 0; k < IN_DIM; k++)
            s += pf[n * IN_DIM + k] * Wfs[k * 32 + c];
        v = s;
    } else {
        v = h0w[c];
    }
    h0[(size_t)n * 32 + c] = __float2half(v);
    float ps[4], pd[4];
    #pragma unroll
    for (int h = 0; h < 4; h++) {
        ps[h] = v * vas[h * 32 + c];
        pd[h] = v * vad[h * 32 + c];
    }
    #pragma unroll
    for (int m = 1; m < 32; m <<= 1) {
        #pragma unroll
        for (int h = 0; h < 4; h++) {
            ps[h] += __shfl_xor(ps[h], m, 64);
            pd[h] += __shfl_xor(pd[h], m, 64);
        }
    }
    if ((t & 31) == 0) {
        *(float4*)&asd[(size_t)n * 8]     = make_float4(ps[0], ps[1], ps[2], ps[3]);
        *(float4*)&asd[(size_t)n * 8 + 4] = make_float4(pd[0], pd[1], pd[2], pd[3]);
    }
}

// ---------------------------------------------------------------------------
// k_fine: one block per bucket, 1024 threads. nb from gcur (counts). LDS
// staging, fine-count, wave-shuffle scan, write GLOBAL offA/offE, then place
// e4 + exp'd layer-1 wb.
// ---------------------------------------------------------------------------
__global__ __launch_bounds__(1024) void k_fine(
    const int* __restrict__ gcur, const uint2* __restrict__ ebuf2,
    const float* __restrict__ lutg, const float* __restrict__ asd,
    int* __restrict__ offA, int* __restrict__ offE,
    unsigned* __restrict__ e4, float* __restrict__ wb)
{
    __shared__ uint2 eL[FCAP];          // 48 KB
    __shared__ int lcnt[512], lexc[512];
    __shared__ int wsum[8];
    int b = blockIdx.x, t = threadIdx.x;
    int beg = b * FCAP;
    int nb = gcur[b];
    if (nb > FCAP) nb = FCAP;
    for (int i = t; i < nb; i += 1024) eL[i] = ebuf2[beg + i];
    if (t < 512) lcnt[t] = 0;
    __syncthreads();
    for (int i = t; i < nb; i += 1024)
        atomicAdd(&lcnt[(eL[i].x >> 15) & 511], 1);
    __syncthreads();
    int c = 0;
    if (t < 512) {                       // waves 0..7 fully active
        c = lcnt[t];
        int lane = t & 63;
        int v = c;
        #pragma unroll
        for (int d = 1; d < 64; d <<= 1) {
            int x = __shfl_up(v, d, 64);
            if (lane >= d) v += x;
        }
        if (lane == 63) wsum[t >> 6] = v;
        lexc[t] = v - c;                 // wave-local exclusive prefix
    }
    __syncthreads();
    if (t < 8) {                         // exclusive scan of 8 wave sums
        int orig = wsum[t];
        int v = orig;
        #pragma unroll
        for (int d = 1; d < 8; d <<= 1) {
            int x = __shfl_up(v, d, 64);
            if (t >= d) v += x;
        }
        wsum[t] = v - orig;
    }
    __syncthreads();
    if (t < 512) {
        lexc[t] += wsum[t >> 6];
        int node = b * 512 + t;
        if (node < NN) {
            offA[node] = beg + lexc[t];
            offE[node] = beg + lexc[t] + c;
        }
        lcnt[t] = 0;                     // reuse as per-node cursor
    }
    __syncthreads();
    for (int i = t; i < nb; i += 1024) {
        uint2 u = eL[i];
        int ln = (int)((u.x >> 15) & 511u);
        int r = atomicAdd(&lcnt[ln], 1);
        int p = beg + lexc[ln] + r;
        unsigned code = u.x & 32767u;
        unsigned s = u.y;
        e4[p] = (s << 15) | code;
        int n = (b << 9) + ln;
        float f = fminf((float)code * 0.0625f, (float)(LUTN - 2));
        int i0 = (int)f;
        float fr = f - (float)i0;
        float4 A = *(const float4*)&lutg[(size_t)i0 * 4];
        float4 B = *(const float4*)&lutg[(size_t)(i0 + 1) * 4];
        float4 as4 = *(const float4*)&asd[(size_t)s * 8];
        float4 ad4 = *(const float4*)&asd[(size_t)n * 8 + 4];
        float v0 = as4.x + ad4.x + A.x + (B.x - A.x) * fr;
        float v1 = as4.y + ad4.y + A.y + (B.y - A.y) * fr;
        float v2 = as4.z + ad4.z + A.z + (B.z - A.z) * fr;
        float v3 = as4.w + ad4.w + A.w + (B.w - A.w) * fr;
        v0 = fmaxf(v0, 0.2f * v0);
        v1 = fmaxf(v1, 0.2f * v1);
        v2 = fmaxf(v2, 0.2f * v2);
        v3 = fmaxf(v3, 0.2f * v3);
        *(float4*)&wb[(size_t)p * 4] = make_float4(
            __expf(v0), __expf(v1), __expf(v2), __expf(v3));
    }
}

// ---------------------------------------------------------------------------
// K6 (MFMA): x = hbuf @ W2 (+ logits) via mfma_f32_16x16x32_f16.
// ---------------------------------------------------------------------------
__global__ __launch_bounds__(256) void k_xm(
    const __half* __restrict__ h, const float* __restrict__ Wg,
    const float* __restrict__ atts, const float* __restrict__ attd,
    __half* __restrict__ x16, float* __restrict__ asd)
{
    __shared__ __half Wt[128 * 136];
    __shared__ float attS[128], attD[128];
    int t = threadIdx.x;
    for (int i = t; i < 128 * 32; i += 256) {
        int c = i & 127, d = (i >> 7) * 4;
        float w0 = Wg[(d + 0) * 128 + c];
        float w1 = Wg[(d + 1) * 128 + c];
        float w2 = Wg[(d + 2) * 128 + c];
        float w3 = Wg[(d + 3) * 128 + c];
        __half2 p0 = __floats2half2_rn(w0, w1);
        __half2 p1 = __floats2half2_rn(w2, w3);
        uint2 pk;
        pk.x = *(unsigned*)&p0;
        pk.y = *(unsigned*)&p1;
        *(uint2*)&Wt[c * 136 + d] = pk;
    }
    if (t < 128) { attS[t] = atts[t]; attD[t] = attd[t]; }
    __syncthreads();
    int wv = t >> 6, lane = t & 63;
    int m16 = lane & 15, quad = lane >> 4;
    int n0 = blockIdx.x * 64 + wv * 16;
    f32x4 acc[8];
    #pragma unroll
    for (int ct = 0; ct < 8; ct++) acc[ct] = (f32x4){0.f, 0.f, 0.f, 0.f};
    #pragma unroll
    for (int ks = 0; ks < 4; ks++) {
        int d0 = ks * 32 + quad * 8;
        half8 bf = *(const half8*)&h[(size_t)(n0 + m16) * 128 + d0];
        #pragma unroll
        for (int ct = 0; ct < 8; ct++) {
            half8 af = *(const half8*)&Wt[(ct * 16 + m16) * 136 + d0];
            acc[ct] = __builtin_amdgcn_mfma_f32_16x16x32_f16(af, bf, acc[ct], 0, 0, 0);
        }
    }
    __half* xrow = &x16[(size_t)(n0 + m16) * 128 + quad * 4];
    float ps[4] = {0.f, 0.f, 0.f, 0.f}, pd[4] = {0.f, 0.f, 0.f, 0.f};
    #pragma unroll
    for (int ct = 0; ct < 8; ct++) {
        f32x4 a = acc[ct];
        __half2 h0p = __floats2half2_rn(a[0], a[1]);
        __half2 h1p = __floats2half2_rn(a[2], a[3]);
        uint2 pk;
        pk.x = *(unsigned*)&h0p;
        pk.y = *(unsigned*)&h1p;
        *(uint2*)&xrow[ct * 16] = pk;
        int cb = ct * 16 + quad * 4;
        int hh = ct >> 1;
        ps[hh] += a[0] * attS[cb] + a[1] * attS[cb + 1]
                + a[2] * attS[cb + 2] + a[3] * attS[cb + 3];
        pd[hh] += a[0] * attD[cb] + a[1] * attD[cb + 1]
                + a[2] * attD[cb + 2] + a[3] * attD[cb + 3];
    }
    #pragma unroll
    for (int hh = 0; hh < 4; hh++) {
        ps[hh] += __shfl_xor(ps[hh], 16, 64);
        ps[hh] += __shfl_xor(ps[hh], 32, 64);
        pd[hh] += __shfl_xor(pd[hh], 16, 64);
        pd[hh] += __shfl_xor(pd[hh], 32, 64);
    }
    if (lane < 16) {
        int n = n0 + m16;
        *(float4*)&asd[(size_t)n * 8]     = make_float4(ps[0], ps[1], ps[2], ps[3]);
        *(float4*)&asd[(size_t)n * 8 + 4] = make_float4(pd[0], pd[1], pd[2], pd[3]);
    }
}

// ---------------------------------------------------------------------------
// K8a (k_zm FUSED): layer-1 aggregation (16-lane group/node, unroll 4) THEN
// the blockdiag-W1 MFMA in the same block (zs LDS tile + k_zm epilogue).
// ---------------------------------------------------------------------------
__global__ __launch_bounds__(256) void k_aggz(
    const int* __restrict__ offA, const int* __restrict__ offE,
    const unsigned* __restrict__ e4, const float* __restrict__ wb,
    const __half* __restrict__ h016, const __half* __restrict__ w1h,
    const float* __restrict__ b1, __half* __restrict__ hbuf)
{
    __shared__ __half Wt[128 * 40];     // 10240 B, [c*40+k]
    __shared__ __half zs[16][136];      // 4352 B, padded rows
    int t = threadIdx.x;
    {
        uint4* dst = (uint4*)Wt;
        const uint4* src = (const uint4*)w1h;
        for (int i = t; i < 640; i += 256) dst[i] = src[i];
    }
    int wv = t >> 6, lane = t & 63;
    int g = lane >> 4, q = lane & 15;
    int n = blockIdx.x * 16 + wv * 4 + g;        // grid exact: NN/16
    int beg = offA[n], end = offE[n];
    const __half2* x2 = (const __half2*)h016;
    float a0x = 0.f, a0y = 0.f, a1x = 0.f, a1y = 0.f;
    float a2x = 0.f, a2y = 0.f, a3x = 0.f, a3y = 0.f;
    float l0 = 0.f, l1 = 0.f, l2 = 0.f, l3 = 0.f;
    int i = beg;
    for (; i + 3 < end; i += 4) {
        unsigned u0 = e4[i],     u1 = e4[i + 1];
        unsigned u2 = e4[i + 2], u3 = e4[i + 3];
        float4 w0 = *(const float4*)&wb[(size_t)i * 4];
        float4 w1 = *(const float4*)&wb[(size_t)(i + 1) * 4];
        float4 w2 = *(const float4*)&wb[(size_t)(i + 2) * 4];
        float4 w3 = *(const float4*)&wb[(size_t)(i + 3) * 4];
        float2 x0 = __half22float2(x2[(u0 >> 15) * 16u + q]);
        float2 x1 = __half22float2(x2[(u1 >> 15) * 16u + q]);
        float2 x2v = __half22float2(x2[(u2 >> 15) * 16u + q]);
        float2 x3 = __half22float2(x2[(u3 >> 15) * 16u + q]);
        a0x += w0.x * x0.x + w1.x * x1.x + w2.x * x2v.x + w3.x * x3.x;
        a0y += w0.x * x0.y + w1.x * x1.y + w2.x * x2v.y + w3.x * x3.y;
        a1x += w0.y * x0.x + w1.y * x1.x + w2.y * x2v.x + w3.y * x3.x;
        a1y += w0.y * x0.y + w1.y * x1.y + w2.y * x2v.y + w3.y * x3.y;
        a2x += w0.z * x0.x + w1.z * x1.x + w2.z * x2v.x + w3.z * x3.x;
        a2y += w0.z * x0.y + w1.z * x1.y + w2.z * x2v.y + w3.z * x3.y;
        a3x += w0.w * x0.x + w1.w * x1.x + w2.w * x2v.x + w3.w * x3.x;
        a3y += w0.w * x0.y + w1.w * x1.y + w2.w * x2v.y + w3.w * x3.y;
        l0 += (w0.x + w1.x) + (w2.x + w3.x);
        l1 += (w0.y + w1.y) + (w2.y + w3.y);
        l2 += (w0.z + w1.z) + (w2.z + w3.z);
        l3 += (w0.w + w1.w) + (w2.w + w3.w);
    }
    for (; i < end; i++) {
        unsigned u0 = e4[i];
        float4 w0 = *(const float4*)&wb[(size_t)i * 4];
        float2 x0 = __half22float2(x2[(u0 >> 15) * 16u + q]);
        a0x += w0.x * x0.x;  a0y += w0.x * x0.y;
        a1x += w0.y * x0.x;  a1y += w0.y * x0.y;
        a2x += w0.z * x0.x;  a2y += w0.z * x0.y;
        a3x += w0.w * x0.x;  a3y += w0.w * x0.y;
        l0 += w0.x; l1 += w0.y; l2 += w0.z; l3 += w0.w;
    }
    float i0v = 1.0f / (l0 + 1e-16f);
    float i1v = 1.0f / (l1 + 1e-16f);
    float i2v = 1.0f / (l2 + 1e-16f);
    float i3v = 1.0f / (l3 + 1e-16f);
    int nl = wv * 4 + g;
    *(__half2*)&zs[nl][     q * 2] = __floats2half2_rn(a0x * i0v, a0y * i0v);
    *(__half2*)&zs[nl][32 + q * 2] = __floats2half2_rn(a1x * i1v, a1y * i1v);
    *(__half2*)&zs[nl][64 + q * 2] = __floats2half2_rn(a2x * i2v, a2y * i2v);
    *(__half2*)&zs[nl][96 + q * 2] = __floats2half2_rn(a3x * i3v, a3y * i3v);
    __syncthreads();
    // MFMA: wave wv owns col-tiles {2wv, 2wv+1} (head wv) for all 16 rows.
    int m16 = lane & 15, quad = lane >> 4;
    half8 bf = *(const half8*)&zs[m16][wv * 32 + quad * 8];
    __half* orow = &hbuf[(size_t)(blockIdx.x * 16 + m16) * 128 + quad * 4];
    #pragma unroll
    for (int c2 = 0; c2 < 2; c2++) {
        int ct = wv * 2 + c2;
        half8 af = *(const half8*)&Wt[(ct * 16 + m16) * 40 + quad * 8];
        f32x4 acc = __builtin_amdgcn_mfma_f32_16x16x32_f16(
            af, bf, (f32x4){0.f, 0.f, 0.f, 0.f}, 0, 0, 0);
        int cb = ct * 16 + quad * 4;
        float4 bb = *(const float4*)&b1[cb];
        float r0 = acc[0] + bb.x;
        float r1 = acc[1] + bb.y;
        float r2 = acc[2] + bb.z;
        float r3 = acc[3] + bb.w;
        r0 = r0 > 0.f ? r0 : __expf(r0) - 1.0f;
        r1 = r1 > 0.f ? r1 : __expf(r1) - 1.0f;
        r2 = r2 > 0.f ? r2 : __expf(r2) - 1.0f;
        r3 = r3 > 0.f ? r3 : __expf(r3) - 1.0f;
        __half2 ha = __floats2half2_rn(r0, r1);
        __half2 hb = __floats2half2_rn(r2, r3);
        uint2 pk;
        pk.x = *(unsigned*)&ha;
        pk.y = *(unsigned*)&hb;
        *(uint2*)&orow[ct * 16] = pk;
    }
}

// ---------------------------------------------------------------------------
// K8b: layer-2 aggregation with INLINE weight computation, UNROLL 4 (deeper
// MLP — same lever that paid off in k_aggz). 32-lane group per node.
// ---------------------------------------------------------------------------
__global__ __launch_bounds__(256) void k_agg2(
    const int* __restrict__ offA, const int* __restrict__ offE,
    const unsigned* __restrict__ e4,
    const float* __restrict__ lutg, const float* __restrict__ asd,
    const __half* __restrict__ x16, const float* __restrict__ bias,
    __half* __restrict__ hout)
{
    int t = threadIdx.x;
    int wv = t >> 6, lane = t & 63;
    int g = lane >> 5, q = lane & 31;
    int n = N_PRO + blockIdx.x * 8 + wv * 2 + g;  // grid exact: N_WAT/8
    int h = q >> 3;
    int beg = offA[n], end = offE[n];
    float adh = asd[(size_t)n * 8 + 4 + h];
    float ax = 0.f, ay = 0.f, az = 0.f, aw = 0.f, ls = 0.f;
    int i = beg;
    for (; i + 3 < end; i += 4) {
        unsigned uu[4];
        float ww[4];
        float2 rr[4];
        #pragma unroll
        for (int j = 0; j < 4; j++) uu[j] = e4[i + j];
        #pragma unroll
        for (int j = 0; j < 4; j++) {
            unsigned s = uu[j] >> 15;
            float f = fminf((float)(uu[j] & 32767u) * 0.0625f, (float)(LUTN - 2));
            int i0 = (int)f;
            float fr = f - (float)i0;
            float A = lutg[i0 * 4 + h], B = lutg[(i0 + 1) * 4 + h];
            float as0 = asd[(size_t)s * 8 + h];
            rr[j] = *(const float2*)&x16[(size_t)s * 128 + q * 4];
            float v = as0 + adh + A + (B - A) * fr;
            v = fmaxf(v, 0.2f * v);
            ww[j] = __expf(v);
        }
        #pragma unroll
        for (int j = 0; j < 4; j++) {
            float2 fa = __half22float2(*(__half2*)&rr[j].x);
            float2 fb = __half22float2(*(__half2*)&rr[j].y);
            ax += ww[j] * fa.x;
            ay += ww[j] * fa.y;
            az += ww[j] * fb.x;
            aw += ww[j] * fb.y;
            ls += ww[j];
        }
    }
    for (; i < end; i++) {
        unsigned u0 = e4[i];
        unsigned s0 = u0 >> 15;
        float f0 = fminf((float)(u0 & 32767u) * 0.0625f, (float)(LUTN - 2));
        int i00 = (int)f0;
        float fr0 = f0 - (float)i00;
        float A0 = lutg[i00 * 4 + h], B0 = lutg[(i00 + 1) * 4 + h];
        float as0 = asd[(size_t)s0 * 8 + h];
        float2 r0 = *(const float2*)&x16[(size_t)s0 * 128 + q * 4];
        float v0 = as0 + adh + A0 + (B0 - A0) * fr0;
        v0 = fmaxf(v0, 0.2f * v0);
        float w0 = __expf(v0);
        float2 f00 = __half22float2(*(__half2*)&r0.x);
        float2 f01 = __half22float2(*(__half2*)&r0.y);
        ax += w0 * f00.x; ay += w0 * f00.y;
        az += w0 * f01.x; aw += w0 * f01.y;
        ls += w0;
    }
    float inv = 1.0f / (ls + 1e-16f);
    float4 bb = *(const float4*)&bias[q * 4];
    float o0 = ax * inv + bb.x;
    float o1 = ay * inv + bb.y;
    float o2 = az * inv + bb.z;
    float o3 = aw * inv + bb.w;
    o0 = o0 > 0.f ? o0 : __expf(o0) - 1.0f;
    o1 = o1 > 0.f ? o1 : __expf(o1) - 1.0f;
    o2 = o2 > 0.f ? o2 : __expf(o2) - 1.0f;
    o3 = o3 > 0.f ? o3 : __expf(o3) - 1.0f;
    __half2 ha = __floats2half2_rn(o0, o1);
    __half2 hb = __floats2half2_rn(o2, o3);
    uint2 pk;
    pk.x = *(unsigned*)&ha;
    pk.y = *(unsigned*)&hb;
    *(uint2*)&hout[(size_t)n * 128 + q * 4] = pk;
}

// ---------------------------------------------------------------------------
// K9 (MFMA): water MLP, k_xm-structure. 64 nodes/block, Wm1^T fp16 in LDS,
// epilogue bias+ReLU then 128->2 layer-2 via per-lane dots + shuffle-reduce.
// ---------------------------------------------------------------------------
__global__ __launch_bounds__(256) void k_mlp(
    const __half* __restrict__ hh, const float* __restrict__ Wm1,
    const float* __restrict__ bm1, const float* __restrict__ Wm2,
    const float* __restrict__ bm2, float* __restrict__ out)
{
    __shared__ __half Wt[128 * 136];
    __shared__ float b1s[128];
    __shared__ float w2s[256];
    int t = threadIdx.x;
    for (int i = t; i < 128 * 32; i += 256) {
        int c = i & 127, d = (i >> 7) * 4;
        float w0 = Wm1[(d + 0) * 128 + c];
        float w1 = Wm1[(d + 1) * 128 + c];
        float w2 = Wm1[(d + 2) * 128 + c];
        float w3 = Wm1[(d + 3) * 128 + c];
        __half2 p0 = __floats2half2_rn(w0, w1);
        __half2 p1 = __floats2half2_rn(w2, w3);
        uint2 pk;
        pk.x = *(unsigned*)&p0;
        pk.y = *(unsigned*)&p1;
        *(uint2*)&Wt[c * 136 + d] = pk;
    }
    if (t < 128) b1s[t] = bm1[t];
    w2s[t] = Wm2[t];                       // 256 floats = [128][2]
    __syncthreads();
    int wv = t >> 6, lane = t & 63;
    int m16 = lane & 15, quad = lane >> 4;
    int n0 = blockIdx.x * 64 + wv * 16;    // water-local node base
    f32x4 acc[8];
    #pragma unroll
    for (int ct = 0; ct < 8; ct++) acc[ct] = (f32x4){0.f, 0.f, 0.f, 0.f};
    #pragma unroll
    for (int ks = 0; ks < 4; ks++) {
        int d0 = ks * 32 + quad * 8;
        half8 bf = *(const half8*)&hh[(size_t)(N_PRO + n0 + m16) * 128 + d0];
        #pragma unroll
        for (int ct = 0; ct < 8; ct++) {
            half8 af = *(const half8*)&Wt[(ct * 16 + m16) * 136 + d0];
            acc[ct] = __builtin_amdgcn_mfma_f32_16x16x32_f16(af, bf, acc[ct], 0, 0, 0);
        }
    }
    float p0 = 0.f, p1 = 0.f;
    #pragma unroll
    for (int ct = 0; ct < 8; ct++) {
        int cb = ct * 16 + quad * 4;
        float4 bb = *(const float4*)&b1s[cb];
        float r0 = fmaxf(acc[ct][0] + bb.x, 0.f);
        float r1 = fmaxf(acc[ct][1] + bb.y, 0.f);
        float r2 = fmaxf(acc[ct][2] + bb.z, 0.f);
        float r3 = fmaxf(acc[ct][3] + bb.w, 0.f);
        p0 += r0 * w2s[(cb + 0) * 2] + r1 * w2s[(cb + 1) * 2]
            + r2 * w2s[(cb + 2) * 2] + r3 * w2s[(cb + 3) * 2];
        p1 += r0 * w2s[(cb + 0) * 2 + 1] + r1 * w2s[(cb + 1) * 2 + 1]
            + r2 * w2s[(cb + 2) * 2 + 1] + r3 * w2s[(cb + 3) * 2 + 1];
    }
    p0 += __shfl_xor(p0, 16, 64);
    p0 += __shfl_xor(p0, 32, 64);
    p1 += __shfl_xor(p1, 16, 64);
    p1 += __shfl_xor(p1, 32, 64);
    if (lane < 16) {
        int wn = n0 + m16;
        *(float2*)&out[(size_t)wn * 2] = make_float2(p0 + bm2[0], p1 + bm2[1]);
    }
}

// ---------------------------------------------------------------------------
extern "C" void kernel_launch(void* const* d_in, const int* in_sizes, int n_in,
                              void* d_out, int out_size, void* d_ws, size_t ws_size,
                              hipStream_t stream)
{
    const float* ppos   = (const float*)d_in[0];
    const float* wpos   = (const float*)d_in[1];
    const float* pfeat  = (const float*)d_in[2];
    const int*   ei     = (const int*)d_in[3];
    const float* gamma  = (const float*)d_in[4];
    const float* Wf     = (const float*)d_in[5];
    const float* bfv    = (const float*)d_in[6];
    const float* We     = (const float*)d_in[7];
    const float* be     = (const float*)d_in[8];
    const float* W1     = (const float*)d_in[9];
    const float* atts1  = (const float*)d_in[10];
    const float* attd1  = (const float*)d_in[11];
    const float* Wedge1 = (const float*)d_in[12];
    const float* atte1  = (const float*)d_in[13];
    const float* b1     = (const float*)d_in[14];
    const float* W2     = (const float*)d_in[15];
    const float* atts2  = (const float*)d_in[16];
    const float* attd2  = (const float*)d_in[17];
    const float* Wedge2 = (const float*)d_in[18];
    const float* atte2  = (const float*)d_in[19];
    const float* b2     = (const float*)d_in[20];
    const float* Wm1    = (const float*)d_in[21];
    const float* bm1    = (const float*)d_in[22];
    const float* Wm2    = (const float*)d_in[23];
    const float* bm2    = (const float*)d_in[24];
    float* out = (float*)d_out;

    char* ws = (char*)d_ws;
    size_t o = 0;
    auto alloc = [&](size_t bytes) -> char* {
        char* p = ws + o;
        o += (bytes + 255) & ~(size_t)255;
        return p;
    };
    __half*   h0      = (__half*)alloc((size_t)NNP * 32 * 2);
    __half*   x16     = (__half*)alloc((size_t)NNP * 128 * 2);
    __half*   hbuf    = (__half*)alloc((size_t)NNP * 128 * 2);
    float*    asd     = (float*)alloc((size_t)NNP * 8 * 4);
    float*    wb      = (float*)alloc((size_t)SLOTS * 4 * 4);    // region-addressed
    int*      offA    = (int*)alloc((size_t)NN * 4);
    int*      offE    = (int*)alloc((size_t)NN * 4);
    unsigned* e4      = (unsigned*)alloc((size_t)SLOTS * 4);
    int*      gcur    = (int*)alloc(256 * 4);
    float*    smallw  = (float*)alloc(4096);
    float*    lutbuf  = (float*)alloc((size_t)2 * LUTN * 4 * 4);
    __half*   w1h     = (__half*)alloc((size_t)128 * 40 * 2);
    // ebuf2 (9.6 MB) overlays hbuf (25.6 MB): written by k_hs (scat half),
    // last read by k_fine, strictly before hbuf's first write in k_aggz.
    uint2*    ebuf2   = (uint2*)hbuf;

    // 7 dispatches total.
    k_pre<<<17, 256, 0, stream>>>(We, be, Wedge1, atte1, Wedge2, atte2, Wf, bfv,
                                  W1, atts1, attd1, gamma,
                                  smallw, lutbuf, w1h, gcur);
    k_hs<<<NH0B + SCATB, 256, 0, stream>>>(pfeat, Wf, bfv, smallw, ei, ppos, wpos,
                                           gcur, ebuf2, h0, asd);
    k_fine<<<NBUCK, 1024, 0, stream>>>(gcur, ebuf2, lutbuf, asd, offA, offE, e4, wb);
    k_aggz<<<NN / 16, 256, 0, stream>>>(offA, offE, e4, wb, h0, w1h, b1, hbuf);
    k_xm<<<NNP / 64, 256, 0, stream>>>(hbuf, W2, atts2, attd2, x16, asd);
    k_agg2<<<N_WAT / 8, 256, 0, stream>>>(offA, offE, e4,
                                          lutbuf + (size_t)LUTN * 4, asd, x16, b2, hbuf);
    k_mlp<<<N_WAT / 64, 256, 0, stream>>>(hbuf, Wm1, bm1, Wm2, bm2, out);
}

// Round 8
// 280.482 us; speedup vs baseline: 1.3522x; 1.0078x over previous
//
#include <hip/hip_runtime.h>
#include <hip/hip_fp16.h>
#include <stdint.h>

#define N_PRO 60000
#define N_WAT 40000
#define NN    100000
#define NNP   100032            // padded to a multiple of 64 for tiles
#define NE    1000000
#define IN_DIM 21
#define HID    32
#define HEADS  4
#define HC     128
#define EDGE_K 32
#define LUTN   2048             // distance-LUT bins, bin = dist*256 (range [0,8))
#define NH0B  ((NNP * 32) / 256)       // h0 blocks
#define NBUCK 196                      // coarse buckets of 512 nodes (node>>9)
#define EPT   8                        // edges per thread in scat
#define SCATB ((NE / EPT + 255) / 256) // 489 blocks
#define FCAP  6144                     // per-bucket region capacity (edges)
#define SLOTS (NBUCK * FCAP)           // 1,204,224 region-addressed slots

typedef _Float16 half8 __attribute__((ext_vector_type(8)));
typedef float    f32x4 __attribute__((ext_vector_type(4)));

// ---------------------------------------------------------------------------
// K0 (k_pre, 17 blocks): block 16 = tiny fused weights (smallw) + W1->fp16
// pack (w1h) + gcur zero. Blocks 0..15 = distance LUT (recompute local U/aeb).
// smallw floats: [0..127]=U1, [128..131]=aeb1, [132..259]=U2, [260..263]=aeb2,
// [264..295]=h0w, [296..423]=va_s1, [424..551]=va_d1
// ---------------------------------------------------------------------------
__global__ __launch_bounds__(256) void k_pre(
    const float* We, const float* be,
    const float* Wedge1, const float* atte1,
    const float* Wedge2, const float* atte2,
    const float* Wf, const float* bfv,
    const float* W1, const float* atts1, const float* attd1,
    const float* gamma,
    float* smallw, float* lut, __half* w1h, int* gcur)
{
    __shared__ float V[2][128];
    __shared__ float aebs[4];
    int t = threadIdx.x;
    if (blockIdx.x == 16) {
        {
            int l = t >> 7, dh = t & 127, d = dh >> 2, h = dh & 3;
            const float* Wg = l ? Wedge2 : Wedge1;
            const float* ae = l ? atte2 : atte1;
            float s = 0.f;
            for (int c = 0; c < HID; c++)
                s += Wg[d * HC + h * HID + c] * ae[h * HID + c];
            V[l][dh] = s;
        }
        __syncthreads();
        {
            int l = t >> 7, kh = t & 127, k = kh >> 2, h = kh & 3;
            float s = 0.f;
            for (int d = 0; d < 32; d++)
                s += We[k * 32 + d] * V[l][d * 4 + h];
            smallw[(l ? 132 : 0) + kh] = s;
        }
        if (t < 8) {
            int l = t >> 2, h = t & 3;
            float s = 0.f;
            for (int d = 0; d < 32; d++)
                s += be[d] * V[l][d * 4 + h];
            smallw[(l ? 260 : 128) + h] = s;
        }
        if (t >= 32 && t < 64) {
            int c = t - 32;
            smallw[264 + c] = Wf[20 * 32 + c] + bfv[c];
        }
        {
            int side = t >> 7;
            int h = (t >> 5) & 3, c = t & 31;
            const float* av = side ? attd1 : atts1;
            float s = 0.f;
            for (int j = 0; j < 32; j++)
                s += W1[c * 128 + h * 32 + j] * av[h * 32 + j];
            smallw[(side ? 424 : 296) + (t & 127)] = s;
        }
        // W1 -> fp16, k_zm Wt layout [c*40 + k], 80B rows
        for (int i = t; i < 128 * 8; i += 256) {
            int c = i & 127, k4 = (i >> 7) * 4;
            float w0 = W1[(k4 + 0) * 128 + c];
            float w1v = W1[(k4 + 1) * 128 + c];
            float w2 = W1[(k4 + 2) * 128 + c];
            float w3 = W1[(k4 + 3) * 128 + c];
            __half2 p0 = __floats2half2_rn(w0, w1v);
            __half2 p1 = __floats2half2_rn(w2, w3);
            uint2 pk;
            pk.x = *(unsigned*)&p0;
            pk.y = *(unsigned*)&p1;
            *(uint2*)&w1h[c * 40 + k4] = pk;
        }
        gcur[t] = 0;
        return;
    }
    // LUT blocks: 256 entries each; layer uniform per block.
    int e = blockIdx.x * 256 + t;
    int layer = e >> 11, bin = e & (LUTN - 1);
    const float* Wg = layer ? Wedge2 : Wedge1;
    const float* ae = layer ? atte2 : atte1;
    if (t < 128) {
        int d = t >> 2, h = t & 3;
        float s = 0.f;
        for (int c = 0; c < 32; c++)
            s += Wg[d * HC + h * HID + c] * ae[h * HID + c];
        V[0][t] = s;
    }
    __syncthreads();
    if (t < 128) {
        int k = t >> 2, h = t & 3;
        float s = 0.f;
        for (int d = 0; d < 32; d++)
            s += We[k * 32 + d] * V[0][d * 4 + h];
        V[1][t] = s;
    }
    if (t >= 128 && t < 132) {
        int h = t - 128;
        float s = 0.f;
        for (int d = 0; d < 32; d++)
            s += be[d] * V[0][d * 4 + h];
        aebs[h] = s;
    }
    __syncthreads();
    const float* U = V[1];
    float dd = bin * (1.0f / 256.0f);
    float g = gamma[0];
    float a0 = aebs[0], a1 = aebs[1], a2 = aebs[2], a3 = aebs[3];
    const float step = 5.0f / 31.0f;
    #pragma unroll
    for (int k = 0; k < EDGE_K; k++) {
        float tt = dd - (float)k * step;
        float r = __expf(-g * tt * tt);
        a0 += r * U[k * 4 + 0];
        a1 += r * U[k * 4 + 1];
        a2 += r * U[k * 4 + 2];
        a3 += r * U[k * 4 + 3];
    }
    *(float4*)&lut[(size_t)e * 4] = make_float4(a0, a1, a2, a3);
}

// ---------------------------------------------------------------------------
// K2 (k_hs, MERGED, SCAT-FIRST): blocks < SCATB run the fixed-region bucket
// scatter (long, latency-bound — issued FIRST so they're resident while the
// h0 stream fills the rest of the machine). Blocks >= SCATB run h0 =
// feats@Wf+bf (fp16) + layer-1 logits asd. Round-7 had h0 first and the
// counters showed pure serialization (54.7us ~= t_h0 + t_scat).
// ---------------------------------------------------------------------------
__global__ __launch_bounds__(256) void k_hs(
    const float* __restrict__ pf, const float* __restrict__ Wf,
    const float* __restrict__ bfv, const float* __restrict__ smallw,
    const int* __restrict__ ei, const float* __restrict__ ppos,
    const float* __restrict__ wpos, int* __restrict__ gcur,
    uint2* __restrict__ ebuf2,
    __half* __restrict__ h0, float* __restrict__ asd)
{
    int t = threadIdx.x;
    if (blockIdx.x < SCATB) {
        // ---- scat half (issued first => co-resident with h0 stream) ----
        __shared__ int lh[256];
        __shared__ int lbase[256];
        lh[t] = 0;
        __syncthreads();
        int e0 = (blockIdx.x * 256 + t) * EPT;
        int bkt[EPT], rnk[EPT];
        unsigned rec0[EPT], rec1[EPT];
        #pragma unroll
        for (int j = 0; j < EPT; j++) bkt[j] = -1;
        if (e0 < NE) {
            int4 sa = *(const int4*)&ei[e0];
            int4 sb = *(const int4*)&ei[e0 + 4];
            int4 da = *(const int4*)&ei[NE + e0];
            int4 db = *(const int4*)&ei[NE + e0 + 4];
            int ss[8] = {sa.x, sa.y, sa.z, sa.w, sb.x, sb.y, sb.z, sb.w};
            int ds[8] = {da.x, da.y, da.z, da.w, db.x, db.y, db.z, db.w};
            #pragma unroll
            for (int j = 0; j < EPT; j++) {
                int s = ss[j], d = ds[j];
                if ((unsigned)d < (unsigned)NN) {
                    const float* ps = (s < N_PRO) ? &ppos[s * 3] : &wpos[(s - N_PRO) * 3];
                    const float* pd = (d < N_PRO) ? &ppos[d * 3] : &wpos[(d - N_PRO) * 3];
                    float dx = pd[0] - ps[0];
                    float dy = pd[1] - ps[1];
                    float dz = pd[2] - ps[2];
                    float dist = sqrtf(dx * dx + dy * dy + dz * dz);
                    unsigned code = (unsigned)fminf(dist * 4096.0f, 32767.0f);
                    bkt[j] = d >> 9;
                    rec0[j] = ((unsigned)d << 15) | code;
                    rec1[j] = (unsigned)s;
                    rnk[j] = atomicAdd(&lh[bkt[j]], 1);
                }
            }
        }
        __syncthreads();
        if (t < NBUCK) lbase[t] = lh[t] ? atomicAdd(&gcur[t], lh[t]) : 0;
        __syncthreads();
        #pragma unroll
        for (int j = 0; j < EPT; j++)
            if (bkt[j] >= 0) {
                int p = lbase[bkt[j]] + rnk[j];
                if (p < FCAP)   // 14-sigma overflow guard
                    ebuf2[(size_t)bkt[j] * FCAP + p] = make_uint2(rec0[j], rec1[j]);
            }
        return;
    }
    // ---- h0 half ----
    __shared__ float Wfs[IN_DIM * 32];
    __shared__ float bfs[32];
    __shared__ float h0w[32];
    __shared__ float vas[128], vad[128];
    for (int i = t; i < IN_DIM * 32; i += 256) Wfs[i] = Wf[i];
    if (t < 32) { bfs[t] = bfv[t]; h0w[t] = smallw[264 + t]; }
    if (t < 128) vas[t] = smallw[296 + t];
    else         vad[t - 128] = smallw[424 + (t - 128)];
    __syncthreads();
    int id = (blockIdx.x - SCATB) * 256 + t;
    int n = id >> 5, c = id & 31;
    if (n >= NNP) return;
    float v;
    if (n < N_PRO) {
        float s = bfs[c];
        for (int k = 0; k < IN_DIM; k++)
            s += pf[n * IN_DIM + k] * Wfs[k * 32 + c];
        v = s;
    } else {
        v = h0w[c];
    }
    h0[(size_t)n * 32 + c] = __float2half(v);
    float ps[4], pd[4];
    #pragma unroll
    for (int h = 0; h < 4; h++) {
        ps[h] = v * vas[h * 32 + c];
        pd[h] = v * vad[h * 32 + c];
    }
    #pragma unroll
    for (int m = 1; m < 32; m <<= 1) {
        #pragma unroll
        for (int h = 0; h < 4; h++) {
            ps[h] += __shfl_xor(ps[h], m, 64);
            pd[h] += __shfl_xor(pd[h], m, 64);
        }
    }
    if ((t & 31) == 0) {
        *(float4*)&asd[(size_t)n * 8]     = make_float4(ps[0], ps[1], ps[2], ps[3]);
        *(float4*)&asd[(size_t)n * 8 + 4] = make_float4(pd[0], pd[1], pd[2], pd[3]);
    }
}

// ---------------------------------------------------------------------------
// k_fine: one block per bucket, 1024 threads. nb from gcur (counts). LDS
// staging, fine-count, wave-shuffle scan, write GLOBAL offA/offE, then place
// e4 + exp'd layer-1 wb.
// ---------------------------------------------------------------------------
__global__ __launch_bounds__(1024) void k_fine(
    const int* __restrict__ gcur, const uint2* __restrict__ ebuf2,
    const float* __restrict__ lutg, const float* __restrict__ asd,
    int* __restrict__ offA, int* __restrict__ offE,
    unsigned* __restrict__ e4, float* __restrict__ wb)
{
    __shared__ uint2 eL[FCAP];          // 48 KB
    __shared__ int lcnt[512], lexc[512];
    __shared__ int wsum[8];
    int b = blockIdx.x, t = threadIdx.x;
    int beg = b * FCAP;
    int nb = gcur[b];
    if (nb > FCAP) nb = FCAP;
    for (int i = t; i < nb; i += 1024) eL[i] = ebuf2[beg + i];
    if (t < 512) lcnt[t] = 0;
    __syncthreads();
    for (int i = t; i < nb; i += 1024)
        atomicAdd(&lcnt[(eL[i].x >> 15) & 511], 1);
    __syncthreads();
    int c = 0;
    if (t < 512) {                       // waves 0..7 fully active
        c = lcnt[t];
        int lane = t & 63;
        int v = c;
        #pragma unroll
        for (int d = 1; d < 64; d <<= 1) {
            int x = __shfl_up(v, d, 64);
            if (lane >= d) v += x;
        }
        if (lane == 63) wsum[t >> 6] = v;
        lexc[t] = v - c;                 // wave-local exclusive prefix
    }
    __syncthreads();
    if (t < 8) {                         // exclusive scan of 8 wave sums
        int orig = wsum[t];
        int v = orig;
        #pragma unroll
        for (int d = 1; d < 8; d <<= 1) {
            int x = __shfl_up(v, d, 64);
            if (t >= d) v += x;
        }
        wsum[t] = v - orig;
    }
    __syncthreads();
    if (t < 512) {
        lexc[t] += wsum[t >> 6];
        int node = b * 512 + t;
        if (node < NN) {
            offA[node] = beg + lexc[t];
            offE[node] = beg + lexc[t] + c;
        }
        lcnt[t] = 0;                     // reuse as per-node cursor
    }
    __syncthreads();
    for (int i = t; i < nb; i += 1024) {
        uint2 u = eL[i];
        int ln = (int)((u.x >> 15) & 511u);
        int r = atomicAdd(&lcnt[ln], 1);
        int p = beg + lexc[ln] + r;
        unsigned code = u.x & 32767u;
        unsigned s = u.y;
        e4[p] = (s << 15) | code;
        int n = (b << 9) + ln;
        float f = fminf((float)code * 0.0625f, (float)(LUTN - 2));
        int i0 = (int)f;
        float fr = f - (float)i0;
        float4 A = *(const float4*)&lutg[(size_t)i0 * 4];
        float4 B = *(const float4*)&lutg[(size_t)(i0 + 1) * 4];
        float4 as4 = *(const float4*)&asd[(size_t)s * 8];
        float4 ad4 = *(const float4*)&asd[(size_t)n * 8 + 4];
        float v0 = as4.x + ad4.x + A.x + (B.x - A.x) * fr;
        float v1 = as4.y + ad4.y + A.y + (B.y - A.y) * fr;
        float v2 = as4.z + ad4.z + A.z + (B.z - A.z) * fr;
        float v3 = as4.w + ad4.w + A.w + (B.w - A.w) * fr;
        v0 = fmaxf(v0, 0.2f * v0);
        v1 = fmaxf(v1, 0.2f * v1);
        v2 = fmaxf(v2, 0.2f * v2);
        v3 = fmaxf(v3, 0.2f * v3);
        *(float4*)&wb[(size_t)p * 4] = make_float4(
            __expf(v0), __expf(v1), __expf(v2), __expf(v3));
    }
}

// ---------------------------------------------------------------------------
// K6 (MFMA): x = hbuf @ W2 (+ logits) via mfma_f32_16x16x32_f16.
// ---------------------------------------------------------------------------
__global__ __launch_bounds__(256) void k_xm(
    const __half* __restrict__ h, const float* __restrict__ Wg,
    const float* __restrict__ atts, const float* __restrict__ attd,
    __half* __restrict__ x16, float* __restrict__ asd)
{
    __shared__ __half Wt[128 * 136];
    __shared__ float attS[128], attD[128];
    int t = threadIdx.x;
    for (int i = t; i < 128 * 32; i += 256) {
        int c = i & 127, d = (i >> 7) * 4;
        float w0 = Wg[(d + 0) * 128 + c];
        float w1 = Wg[(d + 1) * 128 + c];
        float w2 = Wg[(d + 2) * 128 + c];
        float w3 = Wg[(d + 3) * 128 + c];
        __half2 p0 = __floats2half2_rn(w0, w1);
        __half2 p1 = __floats2half2_rn(w2, w3);
        uint2 pk;
        pk.x = *(unsigned*)&p0;
        pk.y = *(unsigned*)&p1;
        *(uint2*)&Wt[c * 136 + d] = pk;
    }
    if (t < 128) { attS[t] = atts[t]; attD[t] = attd[t]; }
    __syncthreads();
    int wv = t >> 6, lane = t & 63;
    int m16 = lane & 15, quad = lane >> 4;
    int n0 = blockIdx.x * 64 + wv * 16;
    f32x4 acc[8];
    #pragma unroll
    for (int ct = 0; ct < 8; ct++) acc[ct] = (f32x4){0.f, 0.f, 0.f, 0.f};
    #pragma unroll
    for (int ks = 0; ks < 4; ks++) {
        int d0 = ks * 32 + quad * 8;
        half8 bf = *(const half8*)&h[(size_t)(n0 + m16) * 128 + d0];
        #pragma unroll
        for (int ct = 0; ct < 8; ct++) {
            half8 af = *(const half8*)&Wt[(ct * 16 + m16) * 136 + d0];
            acc[ct] = __builtin_amdgcn_mfma_f32_16x16x32_f16(af, bf, acc[ct], 0, 0, 0);
        }
    }
    __half* xrow = &x16[(size_t)(n0 + m16) * 128 + quad * 4];
    float ps[4] = {0.f, 0.f, 0.f, 0.f}, pd[4] = {0.f, 0.f, 0.f, 0.f};
    #pragma unroll
    for (int ct = 0; ct < 8; ct++) {
        f32x4 a = acc[ct];
        __half2 h0p = __floats2half2_rn(a[0], a[1]);
        __half2 h1p = __floats2half2_rn(a[2], a[3]);
        uint2 pk;
        pk.x = *(unsigned*)&h0p;
        pk.y = *(unsigned*)&h1p;
        *(uint2*)&xrow[ct * 16] = pk;
        int cb = ct * 16 + quad * 4;
        int hh = ct >> 1;
        ps[hh] += a[0] * attS[cb] + a[1] * attS[cb + 1]
                + a[2] * attS[cb + 2] + a[3] * attS[cb + 3];
        pd[hh] += a[0] * attD[cb] + a[1] * attD[cb + 1]
                + a[2] * attD[cb + 2] + a[3] * attD[cb + 3];
    }
    #pragma unroll
    for (int hh = 0; hh < 4; hh++) {
        ps[hh] += __shfl_xor(ps[hh], 16, 64);
        ps[hh] += __shfl_xor(ps[hh], 32, 64);
        pd[hh] += __shfl_xor(pd[hh], 16, 64);
        pd[hh] += __shfl_xor(pd[hh], 32, 64);
    }
    if (lane < 16) {
        int n = n0 + m16;
        *(float4*)&asd[(size_t)n * 8]     = make_float4(ps[0], ps[1], ps[2], ps[3]);
        *(float4*)&asd[(size_t)n * 8 + 4] = make_float4(pd[0], pd[1], pd[2], pd[3]);
    }
}

// ---------------------------------------------------------------------------
// K8a (k_zm FUSED): layer-1 aggregation (16-lane group/node, unroll 4) THEN
// the blockdiag-W1 MFMA in the same block (zs LDS tile + k_zm epilogue).
// ---------------------------------------------------------------------------
__global__ __launch_bounds__(256) void k_aggz(
    const int* __restrict__ offA, const int* __restrict__ offE,
    const unsigned* __restrict__ e4, const float* __restrict__ wb,
    const __half* __restrict__ h016, const __half* __restrict__ w1h,
    const float* __restrict__ b1, __half* __restrict__ hbuf)
{
    __shared__ __half Wt[128 * 40];     // 10240 B, [c*40+k]
    __shared__ __half zs[16][136];      // 4352 B, padded rows
    int t = threadIdx.x;
    {
        uint4* dst = (uint4*)Wt;
        const uint4* src = (const uint4*)w1h;
        for (int i = t; i < 640; i += 256) dst[i] = src[i];
    }
    int wv = t >> 6, lane = t & 63;
    int g = lane >> 4, q = lane & 15;
    int n = blockIdx.x * 16 + wv * 4 + g;        // grid exact: NN/16
    int beg = offA[n], end = offE[n];
    const __half2* x2 = (const __half2*)h016;
    float a0x = 0.f, a0y = 0.f, a1x = 0.f, a1y = 0.f;
    float a2x = 0.f, a2y = 0.f, a3x = 0.f, a3y = 0.f;
    float l0 = 0.f, l1 = 0.f, l2 = 0.f, l3 = 0.f;
    int i = beg;
    for (; i + 3 < end; i += 4) {
        unsigned u0 = e4[i],     u1 = e4[i + 1];
        unsigned u2 = e4[i + 2], u3 = e4[i + 3];
        float4 w0 = *(const float4*)&wb[(size_t)i * 4];
        float4 w1 = *(const float4*)&wb[(size_t)(i + 1) * 4];
        float4 w2 = *(const float4*)&wb[(size_t)(i + 2) * 4];
        float4 w3 = *(const float4*)&wb[(size_t)(i + 3) * 4];
        float2 x0 = __half22float2(x2[(u0 >> 15) * 16u + q]);
        float2 x1 = __half22float2(x2[(u1 >> 15) * 16u + q]);
        float2 x2v = __half22float2(x2[(u2 >> 15) * 16u + q]);
        float2 x3 = __half22float2(x2[(u3 >> 15) * 16u + q]);
        a0x += w0.x * x0.x + w1.x * x1.x + w2.x * x2v.x + w3.x * x3.x;
        a0y += w0.x * x0.y + w1.x * x1.y + w2.x * x2v.y + w3.x * x3.y;
        a1x += w0.y * x0.x + w1.y * x1.x + w2.y * x2v.x + w3.y * x3.x;
        a1y += w0.y * x0.y + w1.y * x1.y + w2.y * x2v.y + w3.y * x3.y;
        a2x += w0.z * x0.x + w1.z * x1.x + w2.z * x2v.x + w3.z * x3.x;
        a2y += w0.z * x0.y + w1.z * x1.y + w2.z * x2v.y + w3.z * x3.y;
        a3x += w0.w * x0.x + w1.w * x1.x + w2.w * x2v.x + w3.w * x3.x;
        a3y += w0.w * x0.y + w1.w * x1.y + w2.w * x2v.y + w3.w * x3.y;
        l0 += (w0.x + w1.x) + (w2.x + w3.x);
        l1 += (w0.y + w1.y) + (w2.y + w3.y);
        l2 += (w0.z + w1.z) + (w2.z + w3.z);
        l3 += (w0.w + w1.w) + (w2.w + w3.w);
    }
    for (; i < end; i++) {
        unsigned u0 = e4[i];
        float4 w0 = *(const float4*)&wb[(size_t)i * 4];
        float2 x0 = __half22float2(x2[(u0 >> 15) * 16u + q]);
        a0x += w0.x * x0.x;  a0y += w0.x * x0.y;
        a1x += w0.y * x0.x;  a1y += w0.y * x0.y;
        a2x += w0.z * x0.x;  a2y += w0.z * x0.y;
        a3x += w0.w * x0.x;  a3y += w0.w * x0.y;
        l0 += w0.x; l1 += w0.y; l2 += w0.z; l3 += w0.w;
    }
    float i0v = 1.0f / (l0 + 1e-16f);
    float i1v = 1.0f / (l1 + 1e-16f);
    float i2v = 1.0f / (l2 + 1e-16f);
    float i3v = 1.0f / (l3 + 1e-16f);
    int nl = wv * 4 + g;
    *(__half2*)&zs[nl][     q * 2] = __floats2half2_rn(a0x * i0v, a0y * i0v);
    *(__half2*)&zs[nl][32 + q * 2] = __floats2half2_rn(a1x * i1v, a1y * i1v);
    *(__half2*)&zs[nl][64 + q * 2] = __floats2half2_rn(a2x * i2v, a2y * i2v);
    *(__half2*)&zs[nl][96 + q * 2] = __floats2half2_rn(a3x * i3v, a3y * i3v);
    __syncthreads();
    // MFMA: wave wv owns col-tiles {2wv, 2wv+1} (head wv) for all 16 rows.
    int m16 = lane & 15, quad = lane >> 4;
    half8 bf = *(const half8*)&zs[m16][wv * 32 + quad * 8];
    __half* orow = &hbuf[(size_t)(blockIdx.x * 16 + m16) * 128 + quad * 4];
    #pragma unroll
    for (int c2 = 0; c2 < 2; c2++) {
        int ct = wv * 2 + c2;
        half8 af = *(const half8*)&Wt[(ct * 16 + m16) * 40 + quad * 8];
        f32x4 acc = __builtin_amdgcn_mfma_f32_16x16x32_f16(
            af, bf, (f32x4){0.f, 0.f, 0.f, 0.f}, 0, 0, 0);
        int cb = ct * 16 + quad * 4;
        float4 bb = *(const float4*)&b1[cb];
        float r0 = acc[0] + bb.x;
        float r1 = acc[1] + bb.y;
        float r2 = acc[2] + bb.z;
        float r3 = acc[3] + bb.w;
        r0 = r0 > 0.f ? r0 : __expf(r0) - 1.0f;
        r1 = r1 > 0.f ? r1 : __expf(r1) - 1.0f;
        r2 = r2 > 0.f ? r2 : __expf(r2) - 1.0f;
        r3 = r3 > 0.f ? r3 : __expf(r3) - 1.0f;
        __half2 ha = __floats2half2_rn(r0, r1);
        __half2 hb = __floats2half2_rn(r2, r3);
        uint2 pk;
        pk.x = *(unsigned*)&ha;
        pk.y = *(unsigned*)&hb;
        *(uint2*)&orow[ct * 16] = pk;
    }
}

// ---------------------------------------------------------------------------
// K8b: layer-2 aggregation with INLINE weight computation, UNROLL 4.
// 32-lane group per node.
// ---------------------------------------------------------------------------
__global__ __launch_bounds__(256) void k_agg2(
    const int* __restrict__ offA, const int* __restrict__ offE,
    const unsigned* __restrict__ e4,
    const float* __restrict__ lutg, const float* __restrict__ asd,
    const __half* __restrict__ x16, const float* __restrict__ bias,
    __half* __restrict__ hout)
{
    int t = threadIdx.x;
    int wv = t >> 6, lane = t & 63;
    int g = lane >> 5, q = lane & 31;
    int n = N_PRO + blockIdx.x * 8 + wv * 2 + g;  // grid exact: N_WAT/8
    int h = q >> 3;
    int beg = offA[n], end = offE[n];
    float adh = asd[(size_t)n * 8 + 4 + h];
    float ax = 0.f, ay = 0.f, az = 0.f, aw = 0.f, ls = 0.f;
    int i = beg;
    for (; i + 3 < end; i += 4) {
        unsigned uu[4];
        float ww[4];
        float2 rr[4];
        #pragma unroll
        for (int j = 0; j < 4; j++) uu[j] = e4[i + j];
        #pragma unroll
        for (int j = 0; j < 4; j++) {
            unsigned s = uu[j] >> 15;
            float f = fminf((float)(uu[j] & 32767u) * 0.0625f, (float)(LUTN - 2));
            int i0 = (int)f;
            float fr = f - (float)i0;
            float A = lutg[i0 * 4 + h], B = lutg[(i0 + 1) * 4 + h];
            float as0 = asd[(size_t)s * 8 + h];
            rr[j] = *(const float2*)&x16[(size_t)s * 128 + q * 4];
            float v = as0 + adh + A + (B - A) * fr;
            v = fmaxf(v, 0.2f * v);
            ww[j] = __expf(v);
        }
        #pragma unroll
        for (int j = 0; j < 4; j++) {
            float2 fa = __half22float2(*(__half2*)&rr[j].x);
            float2 fb = __half22float2(*(__half2*)&rr[j].y);
            ax += ww[j] * fa.x;
            ay += ww[j] * fa.y;
            az += ww[j] * fb.x;
            aw += ww[j] * fb.y;
            ls += ww[j];
        }
    }
    for (; i < end; i++) {
        unsigned u0 = e4[i];
        unsigned s0 = u0 >> 15;
        float f0 = fminf((float)(u0 & 32767u) * 0.0625f, (float)(LUTN - 2));
        int i00 = (int)f0;
        float fr0 = f0 - (float)i00;
        float A0 = lutg[i00 * 4 + h], B0 = lutg[(i00 + 1) * 4 + h];
        float as0 = asd[(size_t)s0 * 8 + h];
        float2 r0 = *(const float2*)&x16[(size_t)s0 * 128 + q * 4];
        float v0 = as0 + adh + A0 + (B0 - A0) * fr0;
        v0 = fmaxf(v0, 0.2f * v0);
        float w0 = __expf(v0);
        float2 f00 = __half22float2(*(__half2*)&r0.x);
        float2 f01 = __half22float2(*(__half2*)&r0.y);
        ax += w0 * f00.x; ay += w0 * f00.y;
        az += w0 * f01.x; aw += w0 * f01.y;
        ls += w0;
    }
    float inv = 1.0f / (ls + 1e-16f);
    float4 bb = *(const float4*)&bias[q * 4];
    float o0 = ax * inv + bb.x;
    float o1 = ay * inv + bb.y;
    float o2 = az * inv + bb.z;
    float o3 = aw * inv + bb.w;
    o0 = o0 > 0.f ? o0 : __expf(o0) - 1.0f;
    o1 = o1 > 0.f ? o1 : __expf(o1) - 1.0f;
    o2 = o2 > 0.f ? o2 : __expf(o2) - 1.0f;
    o3 = o3 > 0.f ? o3 : __expf(o3) - 1.0f;
    __half2 ha = __floats2half2_rn(o0, o1);
    __half2 hb = __floats2half2_rn(o2, o3);
    uint2 pk;
    pk.x = *(unsigned*)&ha;
    pk.y = *(unsigned*)&hb;
    *(uint2*)&hout[(size_t)n * 128 + q * 4] = pk;
}

// ---------------------------------------------------------------------------
// K9 (MFMA): water MLP, k_xm-structure. 64 nodes/block, Wm1^T fp16 in LDS,
// epilogue bias+ReLU then 128->2 layer-2 via per-lane dots + shuffle-reduce.
// ---------------------------------------------------------------------------
__global__ __launch_bounds__(256) void k_mlp(
    const __half* __restrict__ hh, const float* __restrict__ Wm1,
    const float* __restrict__ bm1, const float* __restrict__ Wm2,
    const float* __restrict__ bm2, float* __restrict__ out)
{
    __shared__ __half Wt[128 * 136];
    __shared__ float b1s[128];
    __shared__ float w2s[256];
    int t = threadIdx.x;
    for (int i = t; i < 128 * 32; i += 256) {
        int c = i & 127, d = (i >> 7) * 4;
        float w0 = Wm1[(d + 0) * 128 + c];
        float w1 = Wm1[(d + 1) * 128 + c];
        float w2 = Wm1[(d + 2) * 128 + c];
        float w3 = Wm1[(d + 3) * 128 + c];
        __half2 p0 = __floats2half2_rn(w0, w1);
        __half2 p1 = __floats2half2_rn(w2, w3);
        uint2 pk;
        pk.x = *(unsigned*)&p0;
        pk.y = *(unsigned*)&p1;
        *(uint2*)&Wt[c * 136 + d] = pk;
    }
    if (t < 128) b1s[t] = bm1[t];
    w2s[t] = Wm2[t];                       // 256 floats = [128][2]
    __syncthreads();
    int wv = t >> 6, lane = t & 63;
    int m16 = lane & 15, quad = lane >> 4;
    int n0 = blockIdx.x * 64 + wv * 16;    // water-local node base
    f32x4 acc[8];
    #pragma unroll
    for (int ct = 0; ct < 8; ct++) acc[ct] = (f32x4){0.f, 0.f, 0.f, 0.f};
    #pragma unroll
    for (int ks = 0; ks < 4; ks++) {
        int d0 = ks * 32 + quad * 8;
        half8 bf = *(const half8*)&hh[(size_t)(N_PRO + n0 + m16) * 128 + d0];
        #pragma unroll
        for (int ct = 0; ct < 8; ct++) {
            half8 af = *(const half8*)&Wt[(ct * 16 + m16) * 136 + d0];
            acc[ct] = __builtin_amdgcn_mfma_f32_16x16x32_f16(af, bf, acc[ct], 0, 0, 0);
        }
    }
    float p0 = 0.f, p1 = 0.f;
    #pragma unroll
    for (int ct = 0; ct < 8; ct++) {
        int cb = ct * 16 + quad * 4;
        float4 bb = *(const float4*)&b1s[cb];
        float r0 = fmaxf(acc[ct][0] + bb.x, 0.f);
        float r1 = fmaxf(acc[ct][1] + bb.y, 0.f);
        float r2 = fmaxf(acc[ct][2] + bb.z, 0.f);
        float r3 = fmaxf(acc[ct][3] + bb.w, 0.f);
        p0 += r0 * w2s[(cb + 0) * 2] + r1 * w2s[(cb + 1) * 2]
            + r2 * w2s[(cb + 2) * 2] + r3 * w2s[(cb + 3) * 2];
        p1 += r0 * w2s[(cb + 0) * 2 + 1] + r1 * w2s[(cb + 1) * 2 + 1]
            + r2 * w2s[(cb + 2) * 2 + 1] + r3 * w2s[(cb + 3) * 2 + 1];
    }
    p0 += __shfl_xor(p0, 16, 64);
    p0 += __shfl_xor(p0, 32, 64);
    p1 += __shfl_xor(p1, 16, 64);
    p1 += __shfl_xor(p1, 32, 64);
    if (lane < 16) {
        int wn = n0 + m16;
        *(float2*)&out[(size_t)wn * 2] = make_float2(p0 + bm2[0], p1 + bm2[1]);
    }
}

// ---------------------------------------------------------------------------
extern "C" void kernel_launch(void* const* d_in, const int* in_sizes, int n_in,
                              void* d_out, int out_size, void* d_ws, size_t ws_size,
                              hipStream_t stream)
{
    const float* ppos   = (const float*)d_in[0];
    const float* wpos   = (const float*)d_in[1];
    const float* pfeat  = (const float*)d_in[2];
    const int*   ei     = (const int*)d_in[3];
    const float* gamma  = (const float*)d_in[4];
    const float* Wf     = (const float*)d_in[5];
    const float* bfv    = (const float*)d_in[6];
    const float* We     = (const float*)d_in[7];
    const float* be     = (const float*)d_in[8];
    const float* W1     = (const float*)d_in[9];
    const float* atts1  = (const float*)d_in[10];
    const float* attd1  = (const float*)d_in[11];
    const float* Wedge1 = (const float*)d_in[12];
    const float* atte1  = (const float*)d_in[13];
    const float* b1     = (const float*)d_in[14];
    const float* W2     = (const float*)d_in[15];
    const float* atts2  = (const float*)d_in[16];
    const float* attd2  = (const float*)d_in[17];
    const float* Wedge2 = (const float*)d_in[18];
    const float* atte2  = (const float*)d_in[19];
    const float* b2     = (const float*)d_in[20];
    const float* Wm1    = (const float*)d_in[21];
    const float* bm1    = (const float*)d_in[22];
    const float* Wm2    = (const float*)d_in[23];
    const float* bm2    = (const float*)d_in[24];
    float* out = (float*)d_out;

    char* ws = (char*)d_ws;
    size_t o = 0;
    auto alloc = [&](size_t bytes) -> char* {
        char* p = ws + o;
        o += (bytes + 255) & ~(size_t)255;
        return p;
    };
    __half*   h0      = (__half*)alloc((size_t)NNP * 32 * 2);
    __half*   x16     = (__half*)alloc((size_t)NNP * 128 * 2);
    __half*   hbuf    = (__half*)alloc((size_t)NNP * 128 * 2);
    float*    asd     = (float*)alloc((size_t)NNP * 8 * 4);
    float*    wb      = (float*)alloc((size_t)SLOTS * 4 * 4);    // region-addressed
    int*      offA    = (int*)alloc((size_t)NN * 4);
    int*      offE    = (int*)alloc((size_t)NN * 4);
    unsigned* e4      = (unsigned*)alloc((size_t)SLOTS * 4);
    int*      gcur    = (int*)alloc(256 * 4);
    float*    smallw  = (float*)alloc(4096);
    float*    lutbuf  = (float*)alloc((size_t)2 * LUTN * 4 * 4);
    __half*   w1h     = (__half*)alloc((size_t)128 * 40 * 2);
    // ebuf2 (9.6 MB) overlays hbuf (25.6 MB): written by k_hs (scat half),
    // last read by k_fine, strictly before hbuf's first write in k_aggz.
    uint2*    ebuf2   = (uint2*)hbuf;

    // 7 dispatches total.
    k_pre<<<17, 256, 0, stream>>>(We, be, Wedge1, atte1, Wedge2, atte2, Wf, bfv,
                                  W1, atts1, attd1, gamma,
                                  smallw, lutbuf, w1h, gcur);
    k_hs<<<NH0B + SCATB, 256, 0, stream>>>(pfeat, Wf, bfv, smallw, ei, ppos, wpos,
                                           gcur, ebuf2, h0, asd);
    k_fine<<<NBUCK, 1024, 0, stream>>>(gcur, ebuf2, lutbuf, asd, offA, offE, e4, wb);
    k_aggz<<<NN / 16, 256, 0, stream>>>(offA, offE, e4, wb, h0, w1h, b1, hbuf);
    k_xm<<<NNP / 64, 256, 0, stream>>>(hbuf, W2, atts2, attd2, x16, asd);
    k_agg2<<<N_WAT / 8, 256, 0, stream>>>(offA, offE, e4,
                                          lutbuf + (size_t)LUTN * 4, asd, x16, b2, hbuf);
    k_mlp<<<N_WAT / 64, 256, 0, stream>>>(hbuf, Wm1, bm1, Wm2, bm2, out);
}